// Round 1
// 11797.118 us; speedup vs baseline: 1.6379x; 1.6379x over previous
//
#include <hip/hip_runtime.h>

#define NC 128
#define KTOP 64
#define SMLSIZ 25
#define EPSF 5.9604645e-8f
#define SAFMINF 1.17549435e-38f
#define LDQ 129   // LDS leading dim for Qm: breaks 64-way bank conflicts on column-per-lane access

// out-tail scratch (floats). out = 16,777,216 floats; scratch in top ~5.4MB,
// dead before proj overwrites out.
#define TBASEF 15400960
#define F_A    0         // 262144 f (raw cov sums -> cov, eig input)
#define F_B    262144    // 262144 f (pristine cov for diag)
#define F_Q    524288    // 262144 f (eigvec writeback for diag)
#define F_Q2   786432    // 266240 f (global scratch in merges)
#define F_SM   1052672   // 262144 f (secular matrix, TRANSPOSED: [src*128+root])
#define F_VECS 1314816   // 18432 f (only d region [0..2047] used now)
#define F_IWSP 1333248   // unused (moved to LDS)

// ======================= f32 LAPACK helpers =======================

__device__ __forceinline__ float slapy2f(float x, float y) {
  float xa = fabsf(x), ya = fabsf(y);
  float w = fmaxf(xa, ya), z = fminf(xa, ya);
  if (z == 0.f) return w;
  float r = z / w;
  return w * sqrtf(1.f + r * r);
}

// LAPACK >=3.10 slartg convention (c >= 0, r carries sign of f)
__device__ __forceinline__ void slartgf(float f, float g, float* c, float* s, float* r) {
  if (g == 0.f) { *c = 1.f; *s = 0.f; *r = f; }
  else if (f == 0.f) { *c = 0.f; *s = (g >= 0.f) ? 1.f : -1.f; *r = fabsf(g); }
  else {
    float d_ = sqrtf(f * f + g * g);
    *c = fabsf(f) / d_;
    *r = (f >= 0.f) ? d_ : -d_;
    *s = g / (*r);
  }
}

__device__ void slaev2f(float a, float b, float c,
                        float* rt1, float* rt2, float* cs1, float* sn1) {
  float sm = a + c, df = a - c, adf = fabsf(df), tb = b + b, ab = fabsf(tb);
  float acmx, acmn;
  if (fabsf(a) > fabsf(c)) { acmx = a; acmn = c; } else { acmx = c; acmn = a; }
  float rt;
  if (adf > ab) { float t = ab / adf; rt = adf * sqrtf(1.f + t * t); }
  else if (adf < ab) { float t = adf / ab; rt = ab * sqrtf(1.f + t * t); }
  else rt = ab * sqrtf(2.f);
  int sgn1;
  if (sm < 0.f) { *rt1 = 0.5f * (sm - rt); sgn1 = -1; *rt2 = (acmx / (*rt1)) * acmn - (b / (*rt1)) * b; }
  else if (sm > 0.f) { *rt1 = 0.5f * (sm + rt); sgn1 = 1; *rt2 = (acmx / (*rt1)) * acmn - (b / (*rt1)) * b; }
  else { *rt1 = 0.5f * rt; *rt2 = -0.5f * rt; sgn1 = 1; }
  float cs; int sgn2;
  if (df >= 0.f) { cs = df + rt; sgn2 = 1; } else { cs = df - rt; sgn2 = -1; }
  float acs = fabsf(cs);
  if (acs > ab) {
    float ct = -tb / cs;
    *sn1 = 1.f / sqrtf(1.f + ct * ct);
    *cs1 = ct * (*sn1);
  } else {
    if (ab == 0.f) { *cs1 = 1.f; *sn1 = 0.f; }
    else { float tn = -cs / tb; *cs1 = 1.f / sqrtf(1.f + tn * tn); *sn1 = tn * (*cs1); }
  }
  if (sgn1 == sgn2) { float tn = *cs1; *cs1 = -(*sn1); *sn1 = tn; }
}

// Faithful serial ssteqr('I') for a block of size n (n <= 25), Z at zb (ldz).
// cw/sw: 32-float LDS slices (avoid runtime-indexed private arrays -> scratch).
__device__ void steqr_f32(float* d, float* e, int n, float* zb, int ldz,
                          float* cw, float* sw) {
  const float eps = EPSF;
  const float eps2 = eps * eps;
  const float safmin = SAFMINF;
  for (int j = 0; j < n; j++)
    for (int i = 0; i < n; i++) zb[j * ldz + i] = (i == j) ? 1.f : 0.f;
  if (n <= 1) return;
  int nmaxit = n * 30, jtot = 0;
  int l1 = 1;
  while (true) {
    if (l1 > n) break;
    if (l1 > 1) e[l1 - 2] = 0.f;
    int m;
    {
      int mm_;
      for (mm_ = l1; mm_ <= n - 1; mm_++) {
        float tst = fabsf(e[mm_ - 1]);
        if (tst == 0.f) break;
        if (tst <= (sqrtf(fabsf(d[mm_ - 1])) * sqrtf(fabsf(d[mm_]))) * eps) { e[mm_ - 1] = 0.f; break; }
      }
      m = mm_;
    }
    int l = l1, lsv = l, lend = m, lendsv = lend;
    l1 = m + 1;
    if (lend == l) continue;
    float anorm = 0.f;
    for (int i = l; i <= lend; i++) anorm = fmaxf(anorm, fabsf(d[i - 1]));
    for (int i = l; i <= lend - 1; i++) anorm = fmaxf(anorm, fabsf(e[i - 1]));
    if (anorm == 0.f) continue;
    if (fabsf(d[lend - 1]) < fabsf(d[l - 1])) { lend = lsv; l = lendsv; }
    if (lend > l) {
      // ---- QL ----
      while (true) {
        int m2;
        {
          int i;
          for (i = l; i <= lend - 1; i++) {
            float tst = fabsf(e[i - 1]); tst = tst * tst;
            if (tst <= (eps2 * fabsf(d[i - 1])) * fabsf(d[i]) + safmin) break;
          }
          m2 = i;
        }
        if (m2 < lend) e[m2 - 1] = 0.f;
        float p = d[l - 1];
        if (m2 == l) { d[l - 1] = p; l++; if (l <= lend) continue; else break; }
        if (m2 == l + 1) {
          float rt1, rt2, c_, s_;
          slaev2f(d[l - 1], e[l - 1], d[l], &rt1, &rt2, &c_, &s_);
          for (int i = 0; i < n; i++) {
            float t1 = zb[l * ldz + i];
            float t0 = zb[(l - 1) * ldz + i];
            zb[l * ldz + i] = c_ * t1 - s_ * t0;
            zb[(l - 1) * ldz + i] = s_ * t1 + c_ * t0;
          }
          d[l - 1] = rt1; d[l] = rt2; e[l - 1] = 0.f;
          l += 2; if (l <= lend) continue; else break;
        }
        if (jtot == nmaxit) break;
        jtot++;
        float g = (d[l] - p) / (2.f * e[l - 1]);
        float r = slapy2f(g, 1.f);
        g = d[m2 - 1] - p + e[l - 1] / (g + copysignf(r, g));
        float s_ = 1.f, c_ = 1.f; p = 0.f;
        for (int i = m2 - 1; i >= l; i--) {
          float f = s_ * e[i - 1], b2 = c_ * e[i - 1];
          float cc, ss, rr;
          slartgf(g, f, &cc, &ss, &rr);
          c_ = cc; s_ = ss;
          if (i != m2 - 1) e[i] = rr;
          g = d[i] - p;
          rr = (d[i - 1] - g) * s_ + 2.f * c_ * b2;
          p = s_ * rr;
          d[i] = g + p;
          g = c_ * rr - b2;
          cw[i - l] = c_; sw[i - l] = -s_;
        }
        int mm2 = m2 - l + 1;
        for (int jj = mm2 - 2; jj >= 0; jj--) {
          float ct_ = cw[jj], st_ = sw[jj];
          int colj = l - 1 + jj;
          for (int i = 0; i < n; i++) {
            float t1 = zb[(colj + 1) * ldz + i];
            float t0 = zb[colj * ldz + i];
            zb[(colj + 1) * ldz + i] = ct_ * t1 - st_ * t0;
            zb[colj * ldz + i] = st_ * t1 + ct_ * t0;
          }
        }
        d[l - 1] -= p; e[l - 1] = g;
      }
    } else {
      // ---- QR ----
      while (true) {
        int m2;
        {
          int i;
          for (i = l; i >= lend + 1; i--) {
            float tst = fabsf(e[i - 2]); tst = tst * tst;
            if (tst <= (eps2 * fabsf(d[i - 1])) * fabsf(d[i - 2]) + safmin) break;
          }
          m2 = i;
        }
        if (m2 > lend) e[m2 - 2] = 0.f;
        float p = d[l - 1];
        if (m2 == l) { d[l - 1] = p; l--; if (l >= lend) continue; else break; }
        if (m2 == l - 1) {
          float rt1, rt2, c_, s_;
          slaev2f(d[l - 2], e[l - 2], d[l - 1], &rt1, &rt2, &c_, &s_);
          for (int i = 0; i < n; i++) {
            float t1 = zb[(l - 1) * ldz + i];
            float t0 = zb[(l - 2) * ldz + i];
            zb[(l - 1) * ldz + i] = c_ * t1 - s_ * t0;
            zb[(l - 2) * ldz + i] = s_ * t1 + c_ * t0;
          }
          d[l - 2] = rt1; d[l - 1] = rt2; e[l - 2] = 0.f;
          l -= 2; if (l >= lend) continue; else break;
        }
        if (jtot == nmaxit) break;
        jtot++;
        float g = (d[l - 2] - p) / (2.f * e[l - 2]);
        float r = slapy2f(g, 1.f);
        g = d[m2 - 1] - p + e[l - 2] / (g + copysignf(r, g));
        float s_ = 1.f, c_ = 1.f; p = 0.f;
        for (int i = m2; i <= l - 1; i++) {
          float f = s_ * e[i - 1], b2 = c_ * e[i - 1];
          float cc, ss, rr;
          slartgf(g, f, &cc, &ss, &rr);
          c_ = cc; s_ = ss;
          if (i != m2) e[i - 2] = rr;
          g = d[i - 1] - p;
          rr = (d[i] - g) * s_ + 2.f * c_ * b2;
          p = s_ * rr;
          d[i - 1] = g + p;
          g = c_ * rr - b2;
          cw[i - m2] = c_; sw[i - m2] = s_;
        }
        int mm2 = l - m2 + 1;
        for (int jj = 0; jj <= mm2 - 2; jj++) {
          float ct_ = cw[jj], st_ = sw[jj];
          int colj = m2 - 1 + jj;
          for (int i = 0; i < n; i++) {
            float t1 = zb[(colj + 1) * ldz + i];
            float t0 = zb[colj * ldz + i];
            zb[(colj + 1) * ldz + i] = ct_ * t1 - st_ * t0;
            zb[colj * ldz + i] = st_ * t1 + ct_ * t0;
          }
        }
        d[l - 1] -= p; e[l - 2] = g;
      }
    }
  }
  for (int ii = 2; ii <= n; ii++) {
    int i = ii - 1, k = i;
    float p = d[i - 1];
    for (int j = ii; j <= n; j++) if (d[j - 1] < p) { k = j; p = d[j - 1]; }
    if (k != i) {
      d[k - 1] = d[i - 1]; d[i - 1] = p;
      for (int r = 0; r < n; r++) {
        float t5 = zb[(i - 1) * ldz + r];
        zb[(i - 1) * ldz + r] = zb[(k - 1) * ldz + r];
        zb[(k - 1) * ldz + r] = t5;
      }
    }
  }
}

// ======================= f32 D&C merge (slaed1/2/3 semantics) =======================
// Qm: LDS, leading dim LDQ. Sm: global, TRANSPOSED storage Sm[src*128+root]
// (same values/order as before, coalesced on the heavy passes).

__device__ void laed1_f32(float* d, float* Qm, float* Q2, float* Sm,
                          float* zv, float* dl, float* wv, float* wg, float* pvf,
                          float* dvf, int* srcx, int* dsrc, int* iq,
                          int off, int n, int n1, float rho_in,
                          int tid, int* shi, float* shdf,
                          double* sdl, double* spv, int* defcnt) {
  int n2 = n - n1;
  for (int t = tid; t < n1; t += 128) zv[t] = Qm[(off + t) * LDQ + off + n1 - 1];
  for (int t = tid; t < n2; t += 128) zv[n1 + t] = Qm[(off + n1 + t) * LDQ + off + n1];
  __syncthreads();
  if (tid == 0) {
    float rho = rho_in;
    if (rho < 0.f) for (int t = n1; t < n; t++) zv[t] = -zv[t];
    float tsc = 1.0f / sqrtf(2.0f);
    for (int t = 0; t < n; t++) zv[t] *= tsc;
    rho = fabsf(2.0f * rho);
    {
      int i = 0, j = n1, p = 0;
      while (i < n1 && j < n) {
        if (d[off + i] <= d[off + j]) srcx[p++] = i++; else srcx[p++] = j++;
      }
      while (i < n1) srcx[p++] = i++;
      while (j < n) srcx[p++] = j++;
    }
    int imax = 0, jmax = 0;
    for (int t = 1; t < n; t++) if (fabsf(zv[t]) > fabsf(zv[imax])) imax = t;
    for (int t = 1; t < n; t++) if (fabsf(d[off + t]) > fabsf(d[off + jmax])) jmax = t;
    float tol = 8.0f * EPSF * fmaxf(fabsf(d[off + jmax]), fabsf(zv[imax]));
    int k = 0, nd = 0;
    if (rho * fabsf(zv[imax]) <= tol) {
      for (int t = 0; t < n; t++) { dsrc[nd] = srcx[t]; dvf[nd] = d[off + srcx[t]]; nd++; }
    } else {
      int pj = -1;
      for (int jj = 0; jj < n; jj++) {
        int nj = srcx[jj];
        if (rho * fabsf(zv[nj]) <= tol) {
          dsrc[nd] = nj; dvf[nd] = d[off + nj]; nd++;
        } else if (pj < 0) {
          pj = nj;
        } else {
          float s_ = zv[pj], c_ = zv[nj];
          float tau_ = slapy2f(c_, s_);
          float t3 = d[off + nj] - d[off + pj];
          c_ /= tau_; s_ = -s_ / tau_;
          if (fabsf(t3 * c_ * s_) <= tol) {
            zv[nj] = tau_; zv[pj] = 0.f;
            for (int r = 0; r < n; r++) {
              float x_ = Qm[(off + pj) * LDQ + off + r];
              float y_ = Qm[(off + nj) * LDQ + off + r];
              Qm[(off + pj) * LDQ + off + r] = c_ * x_ + s_ * y_;
              Qm[(off + nj) * LDQ + off + r] = c_ * y_ - s_ * x_;
            }
            float dp = d[off + pj], dn = d[off + nj];
            d[off + nj] = dp * s_ * s_ + dn * c_ * c_;
            d[off + pj] = dp * c_ * c_ + dn * s_ * s_;
            dsrc[nd] = pj; dvf[nd] = d[off + pj]; nd++;
            pj = nj;
          } else {
            dl[k] = d[off + pj]; wv[k] = zv[pj]; srcx[k] = pj; k++;
            pj = nj;
          }
        }
      }
      if (pj >= 0) { dl[k] = d[off + pj]; wv[k] = zv[pj]; srcx[k] = pj; k++; }
    }
    shi[132] = k; shi[133] = nd; shdf[1] = rho;
    if (nd > 0) atomicAdd(defcnt, nd);
  }
  __syncthreads();
  int k = shi[132], nd = shi[133];
  float rho = shdf[1];
  if (k > 0) {
    if (k == 1) {
      if (tid == 0) {
        zv[0] = dl[0] + rho * (wv[0] * wv[0]);
        for (int r = 0; r < n; r++) Q2[r] = Qm[(off + srcx[0]) * LDQ + off + r];
      }
      __syncthreads();
    } else {
      for (int t = tid; t < k; t += 128) {
        sdl[t] = (double)dl[t];
        spv[t] = (double)rho * (double)wv[t] * (double)wv[t];
      }
      __syncthreads();
      // secular roots in f64, shifted frame: lambda_j = dl_j + eta
      if (tid < k) {
        int j = tid;
        double lo = 0.0, hi;
        if (j == k - 1) {
          double sw2 = 0.0;
          for (int t = 0; t < k; t++) sw2 += spv[t];
          hi = sw2;
          for (int g2 = 0; g2 < 8; g2++) {
            double f = 1.0;
            for (int t = 0; t < k; t++) f += spv[t] / ((sdl[t] - sdl[j]) - hi);
            if (f >= 0.0) break;
            hi *= 2.0;
          }
        } else hi = sdl[j + 1] - sdl[j];
        double gap = hi;
        for (int it = 0; it < 110; it++) {
          double mid = 0.5 * (lo + hi);
          if (!(mid > lo && mid < hi)) break;
          double f = 1.0;
          for (int t = 0; t < k; t++) f += spv[t] / ((sdl[t] - sdl[j]) - mid);
          if (f < 0.0) lo = mid; else hi = mid;
        }
        double eta = 0.5 * (lo + hi);
        if (eta <= 0.0) eta = gap * 1e-30;
        if (j < k - 1 && eta >= gap) eta = gap * (1.0 - 1e-15);
        d[off + j] = (float)(sdl[j] + eta);
        for (int t = 0; t < k; t++)
          Sm[t * 128 + j] = (float)((sdl[t] - sdl[j]) - eta);
      }
      __syncthreads();
      // Gu-Eisenstat reweighting (f32, as slaed3)
      if (tid < k) {
        int i = tid;
        float acc = Sm[i * 128 + i];
        for (int j = 0; j < k; j++) {
          if (j == i) continue;
          acc *= Sm[i * 128 + j] / (dl[i] - dl[j]);
        }
        wg[i] = copysignf(sqrtf(fmaxf(-acc, 0.f)), wv[i]);
      }
      __syncthreads();
      // secular vectors, positive normalization, direct gather
      if (tid < k) {
        int j = tid;
        float nrm2 = 0.f;
        for (int i = 0; i < k; i++) {
          float u = wg[i] / Sm[i * 128 + j];
          Sm[i * 128 + j] = u;
          nrm2 += u * u;
        }
        float nrm = sqrtf(nrm2);
        for (int i = 0; i < k; i++) Sm[i * 128 + j] /= nrm;
        for (int r = 0; r < n; r++) {
          float acc = 0.f;
          for (int i = 0; i < k; i++)
            acc += Qm[(off + srcx[i]) * LDQ + off + r] * Sm[i * 128 + j];
          Q2[j * 128 + r] = acc;
        }
      }
      __syncthreads();
      if (tid < k) zv[tid] = d[off + tid];
      __syncthreads();
    }
  }
  for (int t2 = tid; t2 < nd; t2 += 128)
    for (int r = 0; r < n; r++) Q2[(k + t2) * 128 + r] = Qm[(off + dsrc[t2]) * LDQ + off + r];
  for (int j = tid; j < n; j += 128) pvf[j] = (j < k) ? zv[j] : dvf[j - k];
  __syncthreads();
  // ascending physical sort (stable: secular wins ties, encounter order after)
  if (tid == 0) {
    for (int i = 0; i < n; i++) iq[i] = i;
    for (int i = 0; i < n - 1; i++) {
      int kb = i;
      for (int j = i + 1; j < n; j++) if (pvf[iq[j]] < pvf[iq[kb]]) kb = j;
      if (kb != i) { int tt = iq[i]; iq[i] = iq[kb]; iq[kb] = tt; }
    }
  }
  __syncthreads();
  for (int j = tid; j < n; j += 128) {
    int s2 = iq[j];
    d[off + j] = pvf[s2];
    for (int r = 0; r < n; r++) Qm[(off + j) * LDQ + off + r] = Q2[s2 * 128 + r];
  }
  __syncthreads();
}

__device__ void laed0_f32(float* d, float* e, float* Qm, float* Q2, float* Sm,
                          float* zv, float* dl, float* wv, float* wg, float* pvf,
                          float* dvf, int* srcx, int* dsrc, int* iq, int* iwps,
                          float* sscr,
                          int goff, int m, int tid, int* shi, float* shdf,
                          double* sdl, double* spv, int* defcnt) {
  if (tid == 0) {
    iwps[0] = m; int sp = 1;
    while (iwps[sp - 1] > SMLSIZ) {
      for (int j = sp - 1; j >= 0; j--) { iwps[2 * j + 1] = (iwps[j] + 1) / 2; iwps[2 * j] = iwps[j] / 2; }
      sp *= 2;
    }
    for (int j = 1; j < sp; j++) iwps[j] += iwps[j - 1];
    shi[134] = sp;
    for (int i = 0; i < sp - 1; i++) {
      int bnd = goff + iwps[i];
      d[bnd - 1] -= fabsf(e[bnd - 1]);
      d[bnd] -= fabsf(e[bnd - 1]);
    }
  }
  __syncthreads();
  int subpbs = shi[134];
  // leaves: faithful serial ssteqr per sub-block. Spread workers across BOTH
  // waves (lanes 0..3 of each) to halve divergence serialization: leaf
  // lw = (lane)*2 + wave.
  {
    int lane = tid & 63, w = tid >> 6;
    int lw = lane * 2 + w;
    if (lane < 4 && lw < subpbs) {
      int boff = goff + (lw == 0 ? 0 : iwps[lw - 1]);
      int bm = iwps[lw] - (lw == 0 ? 0 : iwps[lw - 1]);
      steqr_f32(d + boff, e + boff, bm, Qm + boff * LDQ + boff, LDQ,
                sscr + lw * 64, sscr + lw * 64 + 32);
    }
  }
  __syncthreads();
  int cur = subpbs;
  while (cur > 1) {
    for (int p = 0; p < cur; p += 2) {
      int off2 = goff + (p == 0 ? 0 : iwps[p - 1]);
      int msz = iwps[p + 1] - (p == 0 ? 0 : iwps[p - 1]);
      int msd2 = (p == 0) ? iwps[0] : (msz / 2);
      float rho = e[off2 + msd2 - 1];
      laed1_f32(d, Qm, Q2, Sm, zv, dl, wv, wg, pvf, dvf, srcx, dsrc, iq,
                off2, msz, msd2, rho, tid, shi, shdf, sdl, spv, defcnt);
    }
    __syncthreads();
    if (tid == 0) for (int t = 0; 2 * t + 1 < cur; t++) iwps[t] = iwps[2 * t + 1];
    __syncthreads();
    cur /= 2;
  }
}

// ======================= eig kernel: ssyevd emulation per batch =======================
// All hot matrices/vectors in LDS (~143KB/block, 1 block/CU, 16 blocks total):
//   A (64KB, ld 128), Qm (66KB, ld 129), 12 small work vectors, steqr scratch.
// Q2/Sm stay global (don't fit). Qm and d written back to global for diag.

__global__ __launch_bounds__(128) void eig_f32_kernel(const float* __restrict__ covA,
                                                      float* __restrict__ Qw,
                                                      float* Q2w, float* Sw, float* vecs,
                                                      float* Vw, int* defcnt) {
  int b = blockIdx.x, tid = threadIdx.x;
  const float* Ag = covA + (size_t)b * 16384;
  float* Qg = Qw + (size_t)b * 16384;
  float* Q2 = Q2w + (size_t)b * 16640;
  float* Sm = Sw + (size_t)b * 16384;

  __shared__ float As[16384];
  __shared__ float Qs[128 * LDQ];
  __shared__ float sh_d[128], sh_e[128], sh_tau[128], sh_zv[128], sh_dl[128];
  __shared__ float sh_wv[128], sh_wg[128], sh_pvf[128], sh_dvf[128];
  __shared__ int sh_iq[128], sh_srcx[128], sh_dsrc[128];
  __shared__ int iwps[64];
  __shared__ float sscr[512];   // 8 leaf workers x (cw[32]+sw[32])
  __shared__ float redf[128];
  __shared__ float shdf[8];
  __shared__ int shi[280];
  __shared__ double sdl[128];
  __shared__ double spv[128];

  float* A = As;
  float* Qm = Qs;
  float* d = sh_d; float* e = sh_e; float* tauv = sh_tau; float* zv = sh_zv;
  float* dl = sh_dl; float* wv = sh_wv; float* wg = sh_wg; float* pvf = sh_pvf;
  float* dvf = sh_dvf;
  int* iq = sh_iq; int* srcx = sh_srcx; int* dsrc = sh_dsrc;

  // stage cov into LDS
  for (int idx = tid; idx < 16384; idx += 128) As[idx] = Ag[idx];
  __syncthreads();

  // ---------- Phase 1: ssytd2 (UPLO='L') ----------
  for (int i1 = 1; i1 <= NC - 1; i1++) {
    int ii = i1 - 1;
    int mlen = NC - i1;
    float alpha = A[ii * 128 + ii + 1];
    float ps = 0.f;
    for (int t = tid; t < mlen - 1; t += 128) {
      float v = A[ii * 128 + ii + 2 + t];
      ps += v * v;
    }
    redf[tid] = ps;
    __syncthreads();
    for (int sft = 64; sft > 0; sft >>= 1) {
      if (tid < sft) redf[tid] += redf[tid + sft];
      __syncthreads();
    }
    float xnorm = sqrtf(redf[0]);
    __syncthreads();
    float taui, ei;
    if (xnorm == 0.f) { taui = 0.f; ei = alpha; }
    else {
      float beta = -copysignf(slapy2f(alpha, xnorm), alpha);
      taui = (beta - alpha) / beta;
      float scl = 1.f / (alpha - beta);
      ei = beta;
      for (int t = tid; t < mlen - 1; t += 128) A[ii * 128 + ii + 2 + t] *= scl;
    }
    if (tid == 0) { e[ii] = ei; tauv[ii] = taui; A[ii * 128 + ii + 1] = 1.f; }
    __syncthreads();
    if (taui != 0.f) {
      for (int r = tid; r < mlen; r += 128) {
        float acc = 0.f;
        int row = ii + 1 + r;
        for (int s = 0; s < mlen; s++) acc += A[(ii + 1 + s) * 128 + row] * A[ii * 128 + ii + 1 + s];
        pvf[r] = taui * acc;
      }
      __syncthreads();
      float pd = 0.f;
      for (int t = tid; t < mlen; t += 128) pd += pvf[t] * A[ii * 128 + ii + 1 + t];
      redf[tid] = pd;
      __syncthreads();
      for (int sft = 64; sft > 0; sft >>= 1) {
        if (tid < sft) redf[tid] += redf[tid + sft];
        __syncthreads();
      }
      float alpha2 = -0.5f * taui * redf[0];
      __syncthreads();
      for (int t = tid; t < mlen; t += 128) pvf[t] += alpha2 * A[ii * 128 + ii + 1 + t];
      __syncthreads();
      // rank-2 update, row-owned (no runtime div/mod; identical per-element expr)
      if (tid < mlen) {
        int r = tid;
        float vr = A[ii * 128 + ii + 1 + r], pr = pvf[r];
        for (int c2 = 0; c2 < mlen; c2++) {
          A[(ii + 1 + c2) * 128 + (ii + 1 + r)] -= vr * pvf[c2] + pr * A[ii * 128 + ii + 1 + c2];
        }
      }
      __syncthreads();
    }
    if (tid == 0) A[ii * 128 + ii + 1] = ei;
    __syncthreads();
  }
  for (int t = tid; t < NC; t += 128) d[t] = A[t * 128 + t];
  __syncthreads();

  // ---------- Phase 2: sstedc('I') ----------
  for (int idx = tid; idx < 16384; idx += 128) {
    int c = idx >> 7, r = idx & 127;
    Qs[c * LDQ + r] = (c == r) ? 1.f : 0.f;
  }
  __syncthreads();
  if (tid == 0) {
    int ns = 0, start = 0;
    while (start < NC) {
      int fin = start;
      while (fin < NC - 1) {
        float tiny = EPSF * sqrtf(fabsf(d[fin])) * sqrtf(fabsf(d[fin + 1]));
        if (fabsf(e[fin]) > tiny) fin++;
        else break;
      }
      shi[2 + 2 * ns] = start; shi[3 + 2 * ns] = fin - start + 1; ns++;
      start = fin + 1;
    }
    shi[0] = ns;
  }
  __syncthreads();
  int nsplit = shi[0];
  for (int sb = 0; sb < nsplit; sb++) {
    int goff = shi[2 + 2 * sb], m = shi[3 + 2 * sb];
    if (m == 1) continue;
    if (m <= SMLSIZ) {
      if (tid == 0) steqr_f32(d + goff, e + goff, m, Qm + goff * LDQ + goff, LDQ, sscr, sscr + 32);
      __syncthreads();
    } else {
      if (tid == 0) {
        float mx = 0.f;
        for (int i = 0; i < m; i++) mx = fmaxf(mx, fabsf(d[goff + i]));
        for (int i = 0; i < m - 1; i++) mx = fmaxf(mx, fabsf(e[goff + i]));
        shdf[0] = mx;
      }
      __syncthreads();
      float onrm = shdf[0];
      if (onrm != 0.f) {
        float mul = 1.f / onrm;
        for (int t = tid; t < m; t += 128) d[goff + t] *= mul;
        for (int t = tid; t < m - 1; t += 128) e[goff + t] *= mul;
        __syncthreads();
        laed0_f32(d, e, Qm, Q2, Sm, zv, dl, wv, wg, pvf, dvf, srcx, dsrc, iq,
                  iwps, sscr, goff, m, tid, shi, shdf, sdl, spv, defcnt);
        for (int t = tid; t < m; t += 128) d[goff + t] *= onrm;
        __syncthreads();
      }
    }
  }
  if (tid == 0) {
    for (int i = 0; i < NC; i++) shi[140 + i] = i;
    for (int ii2 = 2; ii2 <= NC; ii2++) {
      int i = ii2 - 1, kk2 = i;
      float p = d[i - 1];
      for (int j = ii2; j <= NC; j++) if (d[j - 1] < p) { kk2 = j; p = d[j - 1]; }
      if (kk2 != i) {
        d[kk2 - 1] = d[i - 1]; d[i - 1] = p;
        int tmp = shi[140 + i - 1]; shi[140 + i - 1] = shi[140 + kk2 - 1]; shi[140 + kk2 - 1] = tmp;
      }
    }
  }
  __syncthreads();
  {
    int j = tid;
    int src = shi[140 + j];
    for (int r = 0; r < NC; r++) Q2[j * 128 + r] = Qm[src * LDQ + r];
  }
  __syncthreads();
  {
    int j = tid;
    for (int r = 0; r < NC; r++) Qm[j * LDQ + r] = Q2[j * 128 + r];
  }
  __syncthreads();

  // ---------- Phase 3: sormtr('L','L','N') ----------
  for (int j1 = NC - 1; j1 >= 1; j1--) {
    int jj = j1 - 1;
    float tj = tauv[jj];
    if (tj != 0.f) {
      int col = tid;
      float s = Qm[col * LDQ + jj + 1];
      for (int r = jj + 2; r < NC; r++) s += A[jj * 128 + r] * Qm[col * LDQ + r];
      s *= tj;
      Qm[col * LDQ + jj + 1] -= s;
      for (int r = jj + 2; r < NC; r++) Qm[col * LDQ + r] -= s * A[jj * 128 + r];
    }
  }
  __syncthreads();

  // ---------- Phase 4: extract top-64 descending + writeback for diag ----------
  for (int idx = tid; idx < NC * KTOP; idx += 128) {
    int c2 = idx / KTOP, kk = idx % KTOP;
    Vw[(size_t)b * (NC * KTOP) + idx] = Qm[(127 - kk) * LDQ + c2];
  }
  for (int idx = tid; idx < 16384; idx += 128) {
    int c = idx >> 7, r = idx & 127;
    Qg[idx] = Qs[c * LDQ + r];
  }
  vecs[b * 128 + tid] = d[tid];
}

// ======================= diagnostics =======================

__global__ void zeroi_kernel(int* p) { p[0] = 0; p[1] = 0; }

__global__ __launch_bounds__(128) void diag_kernel(const float* __restrict__ covB,
                                                   const float* __restrict__ Qw,
                                                   const float* __restrict__ vecs,
                                                   const float* __restrict__ Vw, int* dcode) {
  int b = blockIdx.x, tid = threadIdx.x;
  const float* C = covB + (size_t)b * 16384;
  const float* Qm = Qw + (size_t)b * 16384;
  const float* d = vecs + b * 128;
  int flags = 0;
  double rmax = 0.0;
  for (int k = 64; k < 128; k++) {
    double lam = (double)d[k];
    double acc = 0.0;
    for (int j = 0; j < 128; j++) acc += (double)C[j * 128 + tid] * (double)Qm[k * 128 + j];
    acc -= lam * (double)Qm[k * 128 + tid];
    rmax = fmax(rmax, fabs(acc));
  }
  if (rmax > 1e-3) flags |= 1;
  double omax = 0.0;
  for (int p = tid; p < 64 * 64; p += 128) {
    int i = 64 + p / 64, j = 64 + p % 64;
    if (j < i) continue;
    double s = 0.0;
    for (int r = 0; r < 128; r++) s += (double)Qm[i * 128 + r] * (double)Qm[j * 128 + r];
    if (i == j) s -= 1.0;
    omax = fmax(omax, fabs(s));
  }
  if (omax > 1e-3) flags |= 2;
  if (tid < 127 && d[tid + 1] < d[tid] - 1e-5f) flags |= 4;
  for (int idx = tid; idx < 8192; idx += 128) {
    int c2 = idx / 64, kk = idx % 64;
    if (Vw[(size_t)b * 8192 + idx] != Qm[(127 - kk) * 128 + c2]) flags |= 8;
  }
  if (tid == 0) {
    for (int k = 64; k < 128; k++) if (!(d[k] > 0.2f && d[k] < 5.0f)) flags |= 16;
    float s = 0.f;
    for (int c = 0; c < 128; c++) { float v = Vw[(size_t)b * 8192 + c * 64]; s += v * v; }
    if (fabsf(s - 1.f) > 1e-2f) flags |= 32;
  }
  if (flags) atomicOr(dcode, flags);
}

__global__ void emit_kernel(const int* dcode, float* out) {
  int f = dcode[0];
  if (f) {
    int code = 1000;
    if (f & 1) code += 400;
    if (f & 2) code += 200;
    if (f & 4) code += 100;
    if (f & 8) code += 40;
    if (f & 16) code += 20;
    if (f & 32) code += 10;
    int nd = dcode[1]; if (nd > 9) nd = 9;
    code += nd;
    out[0] = (float)code;
  }
}

// ======================= numpy-f32-mirror mean / cov =======================

__global__ __launch_bounds__(128) void mean_np_kernel(const float* __restrict__ x,
                                                      float* __restrict__ mean32) {
  int b = blockIdx.x, c = threadIdx.x;
  const float* xb = x + (size_t)b * 2097152;
  float s = 0.0f;
  for (int n = 0; n < 16384; n++) s = __fadd_rn(s, xb[n * 128 + c]);
  mean32[b * 128 + c] = s / 16384.0f;
}

__global__ __launch_bounds__(256) void covnp_kernel(const float* __restrict__ x,
                                                    const float* __restrict__ mean32,
                                                    float* __restrict__ S) {
  int b = blockIdx.x;
  int ti = (blockIdx.y & 3) * 32, tj = (blockIdx.y >> 2) * 32;
  __shared__ float XI[32 * 64], XJ[32 * 64];
  int tid = threadIdx.x;
  int ci = 2 * (tid & 15), dj = 2 * (tid >> 4);
  float a00 = 0.f, a01 = 0.f, a10 = 0.f, a11 = 0.f;
  const float* xb = x + (size_t)b * 2097152;
  const float* mb = mean32 + b * 128;
  for (int n0 = 0; n0 < 16384; n0 += 64) {
    __syncthreads();
    for (int l = tid; l < 2048; l += 256) {
      int n = l >> 5, cc = l & 31;
      XI[cc * 64 + n] = __fsub_rn(xb[(n0 + n) * 128 + ti + cc], mb[ti + cc]);
      XJ[cc * 64 + n] = __fsub_rn(xb[(n0 + n) * 128 + tj + cc], mb[tj + cc]);
    }
    __syncthreads();
    const float* pi0 = &XI[ci * 64];
    const float* pi1 = pi0 + 64;
    const float* pj0 = &XJ[dj * 64];
    const float* pj1 = pj0 + 64;
    for (int n = 0; n < 64; n++) {
      float ai0 = pi0[n], ai1 = pi1[n], bj0 = pj0[n], bj1 = pj1[n];
      a00 = __fadd_rn(a00, __fmul_rn(ai0, bj0));
      a01 = __fadd_rn(a01, __fmul_rn(ai0, bj1));
      a10 = __fadd_rn(a10, __fmul_rn(ai1, bj0));
      a11 = __fadd_rn(a11, __fmul_rn(ai1, bj1));
    }
  }
  float* Sb = S + (size_t)b * 16384;
  int C = ti + ci, D = tj + dj;
  Sb[C * 128 + D] = a00;
  Sb[C * 128 + D + 1] = a01;
  Sb[(C + 1) * 128 + D] = a10;
  Sb[(C + 1) * 128 + D + 1] = a11;
}

__global__ void covfin_kernel(float* __restrict__ A, float* __restrict__ B) {
  int i = blockIdx.x * 256 + threadIdx.x;
  if (i < 262144) {
    float v = A[i] / 16383.0f;
    A[i] = v;
    B[i] = v;
  }
}

// ======================= projection =======================

__global__ __launch_bounds__(256) void proj_kernel(const float* __restrict__ x, const float* __restrict__ V,
                                                   const float* __restrict__ mean32, float* __restrict__ out) {
  __shared__ float Vs[128 * 64];
  __shared__ float Xs[64 * 128];
  __shared__ float ms[128];
  int b = blockIdx.x, t = blockIdx.y, tid = threadIdx.x;
  const float* xb = x + (size_t)b * 2097152 + (size_t)t * 64 * 128;
  const float* vb = V + (size_t)b * 8192;
  if (tid < 128) ms[tid] = mean32[b * 128 + tid];
  __syncthreads();
  for (int i = tid; i < 2048; i += 256) ((float4*)Vs)[i] = ((const float4*)vb)[i];
  for (int i = tid; i < 2048; i += 256) {
    float4 xv = ((const float4*)xb)[i];
    int cv = (i & 31) * 4;
    xv.x -= ms[cv]; xv.y -= ms[cv + 1]; xv.z -= ms[cv + 2]; xv.w -= ms[cv + 3];
    ((float4*)Xs)[i] = xv;
  }
  __syncthreads();
  int kk = tid & 63, w = tid >> 6;
  float acc[16];
#pragma unroll
  for (int r = 0; r < 16; r++) acc[r] = 0.f;
  for (int c4 = 0; c4 < 32; c4++) {
    float v0 = Vs[(c4 * 4 + 0) * 64 + kk];
    float v1 = Vs[(c4 * 4 + 1) * 64 + kk];
    float v2 = Vs[(c4 * 4 + 2) * 64 + kk];
    float v3 = Vs[(c4 * 4 + 3) * 64 + kk];
#pragma unroll
    for (int r = 0; r < 16; r++) {
      const float4 xv = ((const float4*)Xs)[(w * 16 + r) * 32 + c4];
      acc[r] += xv.x * v0 + xv.y * v1 + xv.z * v2 + xv.w * v3;
    }
  }
  float* ob = out + (size_t)b * 1048576 + (size_t)t * 4096;
#pragma unroll
  for (int r = 0; r < 16; r++) ob[(w * 16 + r) * 64 + kk] = acc[r];
}

// ======================= launch =======================

extern "C" void kernel_launch(void* const* d_in, const int* in_sizes, int n_in,
                              void* d_out, int out_size, void* d_ws, size_t ws_size,
                              hipStream_t stream) {
  (void)in_sizes; (void)n_in; (void)out_size; (void)ws_size;
  const float* x = (const float*)d_in[0];
  float* out = (float*)d_out;
  float* T = out + TBASEF;
  float* Af   = T + F_A;
  float* Bf   = T + F_B;
  float* Qf   = T + F_Q;
  float* Q2f  = T + F_Q2;
  float* Smf  = T + F_SM;
  float* vecsf = T + F_VECS;
  float* Vw = (float*)d_ws;
  float* mean32 = Vw + 131072;
  int* dcode = (int*)(mean32 + 2048);

  zeroi_kernel<<<dim3(1), dim3(1), 0, stream>>>(dcode);
  mean_np_kernel<<<dim3(16), dim3(128), 0, stream>>>(x, mean32);
  covnp_kernel<<<dim3(16, 16), dim3(256), 0, stream>>>(x, mean32, Af);
  covfin_kernel<<<dim3(1024), dim3(256), 0, stream>>>(Af, Bf);
  eig_f32_kernel<<<dim3(16), dim3(128), 0, stream>>>(Af, Qf, Q2f, Smf, vecsf, Vw, dcode + 1);
  diag_kernel<<<dim3(16), dim3(128), 0, stream>>>(Bf, Qf, vecsf, Vw, dcode);
  proj_kernel<<<dim3(16, 256), dim3(256), 0, stream>>>(x, Vw, mean32, out);
  emit_kernel<<<dim3(1), dim3(1), 0, stream>>>(dcode, out);
}

// Round 2
// 8256.483 us; speedup vs baseline: 2.3403x; 1.4288x over previous
//
#include <hip/hip_runtime.h>

#define NC 128
#define KTOP 64
#define SMLSIZ 25
#define EPSF 5.9604645e-8f
#define SAFMINF 1.17549435e-38f
#define LDQ 129   // LDS leading dim for Qm: breaks 64-way bank conflicts on column-per-lane access
#define THREADS 512

// out-tail scratch (floats). out = 16,777,216 floats; scratch in top ~5.4MB,
// dead before proj overwrites out.
#define TBASEF 15400960
#define F_A    0         // 262144 f (raw cov sums -> cov, eig input)
#define F_B    262144    // 262144 f (pristine cov for diag)
#define F_Q    524288    // 262144 f (eigvec writeback for diag)
#define F_Q2   786432    // 266240 f (global scratch in merges)
#define F_SM   1052672   // 262144 f (secular matrix, TRANSPOSED: [src*128+root])
#define F_VECS 1314816   // 18432 f (only d region [0..2047] used now)

// ======================= f32 LAPACK helpers =======================

__device__ __forceinline__ float slapy2f(float x, float y) {
  float xa = fabsf(x), ya = fabsf(y);
  float w = fmaxf(xa, ya), z = fminf(xa, ya);
  if (z == 0.f) return w;
  float r = z / w;
  return w * sqrtf(1.f + r * r);
}

// LAPACK >=3.10 slartg convention (c >= 0, r carries sign of f)
__device__ __forceinline__ void slartgf(float f, float g, float* c, float* s, float* r) {
  if (g == 0.f) { *c = 1.f; *s = 0.f; *r = f; }
  else if (f == 0.f) { *c = 0.f; *s = (g >= 0.f) ? 1.f : -1.f; *r = fabsf(g); }
  else {
    float d_ = sqrtf(f * f + g * g);
    *c = fabsf(f) / d_;
    *r = (f >= 0.f) ? d_ : -d_;
    *s = g / (*r);
  }
}

__device__ void slaev2f(float a, float b, float c,
                        float* rt1, float* rt2, float* cs1, float* sn1) {
  float sm = a + c, df = a - c, adf = fabsf(df), tb = b + b, ab = fabsf(tb);
  float acmx, acmn;
  if (fabsf(a) > fabsf(c)) { acmx = a; acmn = c; } else { acmx = c; acmn = a; }
  float rt;
  if (adf > ab) { float t = ab / adf; rt = adf * sqrtf(1.f + t * t); }
  else if (adf < ab) { float t = adf / ab; rt = ab * sqrtf(1.f + t * t); }
  else rt = ab * sqrtf(2.f);
  int sgn1;
  if (sm < 0.f) { *rt1 = 0.5f * (sm - rt); sgn1 = -1; *rt2 = (acmx / (*rt1)) * acmn - (b / (*rt1)) * b; }
  else if (sm > 0.f) { *rt1 = 0.5f * (sm + rt); sgn1 = 1; *rt2 = (acmx / (*rt1)) * acmn - (b / (*rt1)) * b; }
  else { *rt1 = 0.5f * rt; *rt2 = -0.5f * rt; sgn1 = 1; }
  float cs; int sgn2;
  if (df >= 0.f) { cs = df + rt; sgn2 = 1; } else { cs = df - rt; sgn2 = -1; }
  float acs = fabsf(cs);
  if (acs > ab) {
    float ct = -tb / cs;
    *sn1 = 1.f / sqrtf(1.f + ct * ct);
    *cs1 = ct * (*sn1);
  } else {
    if (ab == 0.f) { *cs1 = 1.f; *sn1 = 0.f; }
    else { float tn = -cs / tb; *cs1 = 1.f / sqrtf(1.f + tn * tn); *sn1 = tn * (*cs1); }
  }
  if (sgn1 == sgn2) { float tn = *cs1; *cs1 = -(*sn1); *sn1 = tn; }
}

// Faithful serial ssteqr('I') for a block of size n (n <= 25), Z at zb (ldz).
// cw/sw: 32-float LDS slices (avoid runtime-indexed private arrays -> scratch).
__device__ void steqr_f32(float* d, float* e, int n, float* zb, int ldz,
                          float* cw, float* sw) {
  const float eps = EPSF;
  const float eps2 = eps * eps;
  const float safmin = SAFMINF;
  for (int j = 0; j < n; j++)
    for (int i = 0; i < n; i++) zb[j * ldz + i] = (i == j) ? 1.f : 0.f;
  if (n <= 1) return;
  int nmaxit = n * 30, jtot = 0;
  int l1 = 1;
  while (true) {
    if (l1 > n) break;
    if (l1 > 1) e[l1 - 2] = 0.f;
    int m;
    {
      int mm_;
      for (mm_ = l1; mm_ <= n - 1; mm_++) {
        float tst = fabsf(e[mm_ - 1]);
        if (tst == 0.f) break;
        if (tst <= (sqrtf(fabsf(d[mm_ - 1])) * sqrtf(fabsf(d[mm_]))) * eps) { e[mm_ - 1] = 0.f; break; }
      }
      m = mm_;
    }
    int l = l1, lsv = l, lend = m, lendsv = lend;
    l1 = m + 1;
    if (lend == l) continue;
    float anorm = 0.f;
    for (int i = l; i <= lend; i++) anorm = fmaxf(anorm, fabsf(d[i - 1]));
    for (int i = l; i <= lend - 1; i++) anorm = fmaxf(anorm, fabsf(e[i - 1]));
    if (anorm == 0.f) continue;
    if (fabsf(d[lend - 1]) < fabsf(d[l - 1])) { lend = lsv; l = lendsv; }
    if (lend > l) {
      // ---- QL ----
      while (true) {
        int m2;
        {
          int i;
          for (i = l; i <= lend - 1; i++) {
            float tst = fabsf(e[i - 1]); tst = tst * tst;
            if (tst <= (eps2 * fabsf(d[i - 1])) * fabsf(d[i]) + safmin) break;
          }
          m2 = i;
        }
        if (m2 < lend) e[m2 - 1] = 0.f;
        float p = d[l - 1];
        if (m2 == l) { d[l - 1] = p; l++; if (l <= lend) continue; else break; }
        if (m2 == l + 1) {
          float rt1, rt2, c_, s_;
          slaev2f(d[l - 1], e[l - 1], d[l], &rt1, &rt2, &c_, &s_);
          for (int i = 0; i < n; i++) {
            float t1 = zb[l * ldz + i];
            float t0 = zb[(l - 1) * ldz + i];
            zb[l * ldz + i] = c_ * t1 - s_ * t0;
            zb[(l - 1) * ldz + i] = s_ * t1 + c_ * t0;
          }
          d[l - 1] = rt1; d[l] = rt2; e[l - 1] = 0.f;
          l += 2; if (l <= lend) continue; else break;
        }
        if (jtot == nmaxit) break;
        jtot++;
        float g = (d[l] - p) / (2.f * e[l - 1]);
        float r = slapy2f(g, 1.f);
        g = d[m2 - 1] - p + e[l - 1] / (g + copysignf(r, g));
        float s_ = 1.f, c_ = 1.f; p = 0.f;
        for (int i = m2 - 1; i >= l; i--) {
          float f = s_ * e[i - 1], b2 = c_ * e[i - 1];
          float cc, ss, rr;
          slartgf(g, f, &cc, &ss, &rr);
          c_ = cc; s_ = ss;
          if (i != m2 - 1) e[i] = rr;
          g = d[i] - p;
          rr = (d[i - 1] - g) * s_ + 2.f * c_ * b2;
          p = s_ * rr;
          d[i] = g + p;
          g = c_ * rr - b2;
          cw[i - l] = c_; sw[i - l] = -s_;
        }
        int mm2 = m2 - l + 1;
        for (int jj = mm2 - 2; jj >= 0; jj--) {
          float ct_ = cw[jj], st_ = sw[jj];
          int colj = l - 1 + jj;
          for (int i = 0; i < n; i++) {
            float t1 = zb[(colj + 1) * ldz + i];
            float t0 = zb[colj * ldz + i];
            zb[(colj + 1) * ldz + i] = ct_ * t1 - st_ * t0;
            zb[colj * ldz + i] = st_ * t1 + ct_ * t0;
          }
        }
        d[l - 1] -= p; e[l - 1] = g;
      }
    } else {
      // ---- QR ----
      while (true) {
        int m2;
        {
          int i;
          for (i = l; i >= lend + 1; i--) {
            float tst = fabsf(e[i - 2]); tst = tst * tst;
            if (tst <= (eps2 * fabsf(d[i - 1])) * fabsf(d[i - 2]) + safmin) break;
          }
          m2 = i;
        }
        if (m2 > lend) e[m2 - 2] = 0.f;
        float p = d[l - 1];
        if (m2 == l) { d[l - 1] = p; l--; if (l >= lend) continue; else break; }
        if (m2 == l - 1) {
          float rt1, rt2, c_, s_;
          slaev2f(d[l - 2], e[l - 2], d[l - 1], &rt1, &rt2, &c_, &s_);
          for (int i = 0; i < n; i++) {
            float t1 = zb[(l - 1) * ldz + i];
            float t0 = zb[(l - 2) * ldz + i];
            zb[(l - 1) * ldz + i] = c_ * t1 - s_ * t0;
            zb[(l - 2) * ldz + i] = s_ * t1 + c_ * t0;
          }
          d[l - 2] = rt1; d[l - 1] = rt2; e[l - 2] = 0.f;
          l -= 2; if (l >= lend) continue; else break;
        }
        if (jtot == nmaxit) break;
        jtot++;
        float g = (d[l - 2] - p) / (2.f * e[l - 2]);
        float r = slapy2f(g, 1.f);
        g = d[m2 - 1] - p + e[l - 2] / (g + copysignf(r, g));
        float s_ = 1.f, c_ = 1.f; p = 0.f;
        for (int i = m2; i <= l - 1; i++) {
          float f = s_ * e[i - 1], b2 = c_ * e[i - 1];
          float cc, ss, rr;
          slartgf(g, f, &cc, &ss, &rr);
          c_ = cc; s_ = ss;
          if (i != m2) e[i - 2] = rr;
          g = d[i - 1] - p;
          rr = (d[i] - g) * s_ + 2.f * c_ * b2;
          p = s_ * rr;
          d[i - 1] = g + p;
          g = c_ * rr - b2;
          cw[i - m2] = c_; sw[i - m2] = s_;
        }
        int mm2 = l - m2 + 1;
        for (int jj = 0; jj <= mm2 - 2; jj++) {
          float ct_ = cw[jj], st_ = sw[jj];
          int colj = m2 - 1 + jj;
          for (int i = 0; i < n; i++) {
            float t1 = zb[(colj + 1) * ldz + i];
            float t0 = zb[colj * ldz + i];
            zb[(colj + 1) * ldz + i] = ct_ * t1 - st_ * t0;
            zb[colj * ldz + i] = st_ * t1 + ct_ * t0;
          }
        }
        d[l - 1] -= p; e[l - 2] = g;
      }
    }
  }
  for (int ii = 2; ii <= n; ii++) {
    int i = ii - 1, k = i;
    float p = d[i - 1];
    for (int j = ii; j <= n; j++) if (d[j - 1] < p) { k = j; p = d[j - 1]; }
    if (k != i) {
      d[k - 1] = d[i - 1]; d[i - 1] = p;
      for (int r = 0; r < n; r++) {
        float t5 = zb[(i - 1) * ldz + r];
        zb[(i - 1) * ldz + r] = zb[(k - 1) * ldz + r];
        zb[(k - 1) * ldz + r] = t5;
      }
    }
  }
}

// ======================= f32 D&C merge (slaed1/2/3 semantics) =======================
// Qm: LDS, leading dim LDQ. Sm: global, TRANSPOSED storage Sm[src*128+root].

__device__ void laed1_f32(float* d, float* Qm, float* Q2, float* Sm,
                          float* zv, float* dl, float* wv, float* wg, float* pvf,
                          float* dvf, int* srcx, int* dsrc, int* iq,
                          int off, int n, int n1, float rho_in,
                          int tid, int* shi, float* shdf,
                          double* sdl, double* spv, int* defcnt) {
  int n2 = n - n1;
  for (int t = tid; t < n1; t += THREADS) zv[t] = Qm[(off + t) * LDQ + off + n1 - 1];
  for (int t = tid; t < n2; t += THREADS) zv[n1 + t] = Qm[(off + n1 + t) * LDQ + off + n1];
  __syncthreads();
  if (tid == 0) {
    float rho = rho_in;
    if (rho < 0.f) for (int t = n1; t < n; t++) zv[t] = -zv[t];
    float tsc = 1.0f / sqrtf(2.0f);
    for (int t = 0; t < n; t++) zv[t] *= tsc;
    rho = fabsf(2.0f * rho);
    {
      int i = 0, j = n1, p = 0;
      while (i < n1 && j < n) {
        if (d[off + i] <= d[off + j]) srcx[p++] = i++; else srcx[p++] = j++;
      }
      while (i < n1) srcx[p++] = i++;
      while (j < n) srcx[p++] = j++;
    }
    int imax = 0, jmax = 0;
    for (int t = 1; t < n; t++) if (fabsf(zv[t]) > fabsf(zv[imax])) imax = t;
    for (int t = 1; t < n; t++) if (fabsf(d[off + t]) > fabsf(d[off + jmax])) jmax = t;
    float tol = 8.0f * EPSF * fmaxf(fabsf(d[off + jmax]), fabsf(zv[imax]));
    int k = 0, nd = 0;
    if (rho * fabsf(zv[imax]) <= tol) {
      for (int t = 0; t < n; t++) { dsrc[nd] = srcx[t]; dvf[nd] = d[off + srcx[t]]; nd++; }
    } else {
      int pj = -1;
      for (int jj = 0; jj < n; jj++) {
        int nj = srcx[jj];
        if (rho * fabsf(zv[nj]) <= tol) {
          dsrc[nd] = nj; dvf[nd] = d[off + nj]; nd++;
        } else if (pj < 0) {
          pj = nj;
        } else {
          float s_ = zv[pj], c_ = zv[nj];
          float tau_ = slapy2f(c_, s_);
          float t3 = d[off + nj] - d[off + pj];
          c_ /= tau_; s_ = -s_ / tau_;
          if (fabsf(t3 * c_ * s_) <= tol) {
            zv[nj] = tau_; zv[pj] = 0.f;
            for (int r = 0; r < n; r++) {
              float x_ = Qm[(off + pj) * LDQ + off + r];
              float y_ = Qm[(off + nj) * LDQ + off + r];
              Qm[(off + pj) * LDQ + off + r] = c_ * x_ + s_ * y_;
              Qm[(off + nj) * LDQ + off + r] = c_ * y_ - s_ * x_;
            }
            float dp = d[off + pj], dn = d[off + nj];
            d[off + nj] = dp * s_ * s_ + dn * c_ * c_;
            d[off + pj] = dp * c_ * c_ + dn * s_ * s_;
            dsrc[nd] = pj; dvf[nd] = d[off + pj]; nd++;
            pj = nj;
          } else {
            dl[k] = d[off + pj]; wv[k] = zv[pj]; srcx[k] = pj; k++;
            pj = nj;
          }
        }
      }
      if (pj >= 0) { dl[k] = d[off + pj]; wv[k] = zv[pj]; srcx[k] = pj; k++; }
    }
    shi[132] = k; shi[133] = nd; shdf[1] = rho;
    if (nd > 0) atomicAdd(defcnt, nd);
  }
  __syncthreads();
  int k = shi[132], nd = shi[133];
  float rho = shdf[1];
  if (k > 0) {
    if (k == 1) {
      if (tid == 0) {
        zv[0] = dl[0] + rho * (wv[0] * wv[0]);
        for (int r = 0; r < n; r++) Q2[r] = Qm[(off + srcx[0]) * LDQ + off + r];
      }
      __syncthreads();
    } else {
      for (int t = tid; t < k; t += THREADS) {
        sdl[t] = (double)dl[t];
        spv[t] = (double)rho * (double)wv[t] * (double)wv[t];
      }
      __syncthreads();
      // secular roots in f64, shifted frame: lambda_j = dl_j + eta
      if (tid < k) {
        int j = tid;
        double lo = 0.0, hi;
        if (j == k - 1) {
          double sw2 = 0.0;
          for (int t = 0; t < k; t++) sw2 += spv[t];
          hi = sw2;
          for (int g2 = 0; g2 < 8; g2++) {
            double f = 1.0;
            for (int t = 0; t < k; t++) f += spv[t] / ((sdl[t] - sdl[j]) - hi);
            if (f >= 0.0) break;
            hi *= 2.0;
          }
        } else hi = sdl[j + 1] - sdl[j];
        double gap = hi;
        for (int it = 0; it < 110; it++) {
          double mid = 0.5 * (lo + hi);
          if (!(mid > lo && mid < hi)) break;
          double f = 1.0;
          for (int t = 0; t < k; t++) f += spv[t] / ((sdl[t] - sdl[j]) - mid);
          if (f < 0.0) lo = mid; else hi = mid;
        }
        double eta = 0.5 * (lo + hi);
        if (eta <= 0.0) eta = gap * 1e-30;
        if (j < k - 1 && eta >= gap) eta = gap * (1.0 - 1e-15);
        d[off + j] = (float)(sdl[j] + eta);
        for (int t = 0; t < k; t++)
          Sm[t * 128 + j] = (float)((sdl[t] - sdl[j]) - eta);
      }
      __syncthreads();
      // Gu-Eisenstat reweighting (f32, as slaed3)
      if (tid < k) {
        int i = tid;
        float acc = Sm[i * 128 + i];
        for (int j = 0; j < k; j++) {
          if (j == i) continue;
          acc *= Sm[i * 128 + j] / (dl[i] - dl[j]);
        }
        wg[i] = copysignf(sqrtf(fmaxf(-acc, 0.f)), wv[i]);
      }
      __syncthreads();
      // secular vectors + positive normalization (thread j, exact order)
      if (tid < k) {
        int j = tid;
        float nrm2 = 0.f;
        for (int i = 0; i < k; i++) {
          float u = wg[i] / Sm[i * 128 + j];
          Sm[i * 128 + j] = u;
          nrm2 += u * u;
        }
        float nrm = sqrtf(nrm2);
        for (int i = 0; i < k; i++) Sm[i * 128 + j] /= nrm;
      }
      __syncthreads();
      // gather Q2[j][r] = sum_i Qm[off+srcx[i]][off+r] * Smn[i][j]:
      // r-chunked across 4 thread-groups, 8-wide r-tiling reusing each Sm load.
      // Per-output accumulation stays i-ascending -> bit-identical.
      {
        int j = tid & 127, g = tid >> 7;
        if (j < k) {
          int chunk = (n + 3) >> 2;
          int rbeg = g * chunk, rend = rbeg + chunk;
          if (rend > n) rend = n;
          int r0 = rbeg;
          for (; r0 + 8 <= rend; r0 += 8) {
            float a0 = 0.f, a1 = 0.f, a2 = 0.f, a3 = 0.f;
            float a4 = 0.f, a5 = 0.f, a6 = 0.f, a7 = 0.f;
            for (int i = 0; i < k; i++) {
              float s = Sm[i * 128 + j];
              const float* q = &Qm[(off + srcx[i]) * LDQ + off + r0];
              a0 += q[0] * s; a1 += q[1] * s; a2 += q[2] * s; a3 += q[3] * s;
              a4 += q[4] * s; a5 += q[5] * s; a6 += q[6] * s; a7 += q[7] * s;
            }
            float* o = &Q2[j * 128 + r0];
            o[0] = a0; o[1] = a1; o[2] = a2; o[3] = a3;
            o[4] = a4; o[5] = a5; o[6] = a6; o[7] = a7;
          }
          for (; r0 < rend; r0++) {
            float a = 0.f;
            for (int i = 0; i < k; i++)
              a += Qm[(off + srcx[i]) * LDQ + off + r0] * Sm[i * 128 + j];
            Q2[j * 128 + r0] = a;
          }
        }
      }
      __syncthreads();
      if (tid < k) zv[tid] = d[off + tid];
      __syncthreads();
    }
  }
  for (int t2 = tid; t2 < nd; t2 += THREADS)
    for (int r = 0; r < n; r++) Q2[(k + t2) * 128 + r] = Qm[(off + dsrc[t2]) * LDQ + off + r];
  for (int j = tid; j < n; j += THREADS) pvf[j] = (j < k) ? zv[j] : dvf[j - k];
  __syncthreads();
  // ascending physical sort with swaps. Dense key mirror ks==wg keeps the
  // invariant ks[j]==pvf[iq[j]] -> identical compare/swap decisions, but
  // sequential-address loads (pipelineable) instead of chained indirection.
  if (tid == 0) {
    float* ks = wg;  // wg is dead here
    for (int i = 0; i < n; i++) { iq[i] = i; ks[i] = pvf[i]; }
    for (int i = 0; i < n - 1; i++) {
      int kb = i;
      float vkb = ks[i];
      for (int j = i + 1; j < n; j++) {
        float vj = ks[j];
        if (vj < vkb) { kb = j; vkb = vj; }
      }
      if (kb != i) {
        int tt = iq[i]; iq[i] = iq[kb]; iq[kb] = tt;
        float tf = ks[i]; ks[i] = ks[kb]; ks[kb] = tf;
      }
    }
  }
  __syncthreads();
  // permuted writeback, r-chunked over 4 groups (elementwise, exact)
  {
    int j = tid & 127, g = tid >> 7;
    if (j < n) {
      int s2 = iq[j];
      if (g == 0) d[off + j] = pvf[s2];
      int chunk = (n + 3) >> 2;
      int rbeg = g * chunk, rend = rbeg + chunk;
      if (rend > n) rend = n;
      for (int r = rbeg; r < rend; r++) Qm[(off + j) * LDQ + off + r] = Q2[s2 * 128 + r];
    }
  }
  __syncthreads();
}

__device__ void laed0_f32(float* d, float* e, float* Qm, float* Q2, float* Sm,
                          float* zv, float* dl, float* wv, float* wg, float* pvf,
                          float* dvf, int* srcx, int* dsrc, int* iq, int* iwps,
                          float* sscr,
                          int goff, int m, int tid, int* shi, float* shdf,
                          double* sdl, double* spv, int* defcnt) {
  if (tid == 0) {
    iwps[0] = m; int sp = 1;
    while (iwps[sp - 1] > SMLSIZ) {
      for (int j = sp - 1; j >= 0; j--) { iwps[2 * j + 1] = (iwps[j] + 1) / 2; iwps[2 * j] = iwps[j] / 2; }
      sp *= 2;
    }
    for (int j = 1; j < sp; j++) iwps[j] += iwps[j - 1];
    shi[134] = sp;
    for (int i = 0; i < sp - 1; i++) {
      int bnd = goff + iwps[i];
      d[bnd - 1] -= fabsf(e[bnd - 1]);
      d[bnd] -= fabsf(e[bnd - 1]);
    }
  }
  __syncthreads();
  int subpbs = shi[134];
  // leaves: faithful serial ssteqr per sub-block — ONE leaf per wave
  // (8 waves @ 512 threads) so divergent leaf solvers don't serialize.
  {
    int lw = tid >> 6;
    if ((tid & 63) == 0 && lw < subpbs) {
      int boff = goff + (lw == 0 ? 0 : iwps[lw - 1]);
      int bm = iwps[lw] - (lw == 0 ? 0 : iwps[lw - 1]);
      steqr_f32(d + boff, e + boff, bm, Qm + boff * LDQ + boff, LDQ,
                sscr + lw * 64, sscr + lw * 64 + 32);
    }
  }
  __syncthreads();
  int cur = subpbs;
  while (cur > 1) {
    for (int p = 0; p < cur; p += 2) {
      int off2 = goff + (p == 0 ? 0 : iwps[p - 1]);
      int msz = iwps[p + 1] - (p == 0 ? 0 : iwps[p - 1]);
      int msd2 = (p == 0) ? iwps[0] : (msz / 2);
      float rho = e[off2 + msd2 - 1];
      laed1_f32(d, Qm, Q2, Sm, zv, dl, wv, wg, pvf, dvf, srcx, dsrc, iq,
                off2, msz, msd2, rho, tid, shi, shdf, sdl, spv, defcnt);
    }
    __syncthreads();
    if (tid == 0) for (int t = 0; 2 * t + 1 < cur; t++) iwps[t] = iwps[2 * t + 1];
    __syncthreads();
    cur /= 2;
  }
}

// ======================= eig kernel: ssyevd emulation per batch =======================
// Hot state in LDS (~145KB/block, 1 block/CU, 16 blocks). 512 threads = 8 waves:
// leaf steqr gets a wave each; elementwise/gather passes get 4x thread groups.
// All FP values bit-identical to the 128-thread version (reduction trees only
// append +0.f terms; per-output sums keep i-order; sorts keep decisions).

__global__ __launch_bounds__(THREADS) void eig_f32_kernel(const float* __restrict__ covA,
                                                          float* __restrict__ Qw,
                                                          float* Q2w, float* Sw, float* vecs,
                                                          float* Vw, int* defcnt) {
  int b = blockIdx.x, tid = threadIdx.x;
  const float* Ag = covA + (size_t)b * 16384;
  float* Qg = Qw + (size_t)b * 16384;
  float* Q2 = Q2w + (size_t)b * 16640;
  float* Sm = Sw + (size_t)b * 16384;

  __shared__ float As[16384];
  __shared__ float Qs[128 * LDQ];
  __shared__ float sh_d[128], sh_e[128], sh_tau[128], sh_zv[128], sh_dl[128];
  __shared__ float sh_wv[128], sh_wg[128], sh_pvf[128], sh_dvf[128];
  __shared__ int sh_iq[128], sh_srcx[128], sh_dsrc[128];
  __shared__ int iwps[64];
  __shared__ float sscr[512];   // 8 leaf workers x (cw[32]+sw[32])
  __shared__ float redf[THREADS];
  __shared__ float shdf[8];
  __shared__ int shi[280];
  __shared__ double sdl[128];
  __shared__ double spv[128];

  float* A = As;
  float* Qm = Qs;
  float* d = sh_d; float* e = sh_e; float* tauv = sh_tau; float* zv = sh_zv;
  float* dl = sh_dl; float* wv = sh_wv; float* wg = sh_wg; float* pvf = sh_pvf;
  float* dvf = sh_dvf;
  int* iq = sh_iq; int* srcx = sh_srcx; int* dsrc = sh_dsrc;

  // stage cov into LDS
  for (int idx = tid; idx < 16384; idx += THREADS) As[idx] = Ag[idx];
  __syncthreads();

  // ---------- Phase 1: ssytd2 (UPLO='L') ----------
  // NOTE: per-thread partial-sum loops keep stride 128; since mlen<128 each
  // thread<128 holds exactly one element and threads>=128 hold ps=0, so the
  // extended tree only adds +0.f (bit-exact).
  for (int i1 = 1; i1 <= NC - 1; i1++) {
    int ii = i1 - 1;
    int mlen = NC - i1;
    float alpha = A[ii * 128 + ii + 1];
    float ps = 0.f;
    for (int t = tid; t < mlen - 1; t += 128) {
      float v = A[ii * 128 + ii + 2 + t];
      ps += v * v;
    }
    redf[tid] = ps;
    __syncthreads();
    for (int sft = THREADS / 2; sft > 0; sft >>= 1) {
      if (tid < sft) redf[tid] += redf[tid + sft];
      __syncthreads();
    }
    float xnorm = sqrtf(redf[0]);
    __syncthreads();
    float taui, ei;
    if (xnorm == 0.f) { taui = 0.f; ei = alpha; }
    else {
      float beta = -copysignf(slapy2f(alpha, xnorm), alpha);
      taui = (beta - alpha) / beta;
      float scl = 1.f / (alpha - beta);
      ei = beta;
      for (int t = tid; t < mlen - 1; t += 128) A[ii * 128 + ii + 2 + t] *= scl;
    }
    if (tid == 0) { e[ii] = ei; tauv[ii] = taui; A[ii * 128 + ii + 1] = 1.f; }
    __syncthreads();
    if (taui != 0.f) {
      for (int r = tid; r < mlen; r += 128) {
        float acc = 0.f;
        int row = ii + 1 + r;
        for (int s = 0; s < mlen; s++) acc += A[(ii + 1 + s) * 128 + row] * A[ii * 128 + ii + 1 + s];
        pvf[r] = taui * acc;
      }
      __syncthreads();
      float pd = 0.f;
      for (int t = tid; t < mlen; t += 128) pd += pvf[t] * A[ii * 128 + ii + 1 + t];
      redf[tid] = pd;
      __syncthreads();
      for (int sft = THREADS / 2; sft > 0; sft >>= 1) {
        if (tid < sft) redf[tid] += redf[tid + sft];
        __syncthreads();
      }
      float alpha2 = -0.5f * taui * redf[0];
      __syncthreads();
      for (int t = tid; t < mlen; t += 128) pvf[t] += alpha2 * A[ii * 128 + ii + 1 + t];
      __syncthreads();
      // rank-2 update: (r, c2-chunk) across 4 thread groups; per-element
      // expression identical, disjoint writes, reads only untouched col ii.
      if ((tid & 127) < mlen) {
        int r = tid & 127, g = tid >> 7;
        int chunk = (mlen + 3) >> 2;
        int cb = g * chunk, ce = cb + chunk;
        if (ce > mlen) ce = mlen;
        float vr = A[ii * 128 + ii + 1 + r], pr = pvf[r];
        for (int c2 = cb; c2 < ce; c2++) {
          A[(ii + 1 + c2) * 128 + (ii + 1 + r)] -=
              vr * pvf[c2] + pr * A[ii * 128 + ii + 1 + c2];
        }
      }
      __syncthreads();
    }
    if (tid == 0) A[ii * 128 + ii + 1] = ei;
    __syncthreads();
  }
  for (int t = tid; t < NC; t += 128) d[t] = A[t * 128 + t];
  __syncthreads();

  // ---------- Phase 2: sstedc('I') ----------
  for (int idx = tid; idx < 16384; idx += THREADS) {
    int c = idx >> 7, r = idx & 127;
    Qs[c * LDQ + r] = (c == r) ? 1.f : 0.f;
  }
  __syncthreads();
  if (tid == 0) {
    int ns = 0, start = 0;
    while (start < NC) {
      int fin = start;
      while (fin < NC - 1) {
        float tiny = EPSF * sqrtf(fabsf(d[fin])) * sqrtf(fabsf(d[fin + 1]));
        if (fabsf(e[fin]) > tiny) fin++;
        else break;
      }
      shi[2 + 2 * ns] = start; shi[3 + 2 * ns] = fin - start + 1; ns++;
      start = fin + 1;
    }
    shi[0] = ns;
  }
  __syncthreads();
  int nsplit = shi[0];
  for (int sb = 0; sb < nsplit; sb++) {
    int goff = shi[2 + 2 * sb], m = shi[3 + 2 * sb];
    if (m == 1) continue;
    if (m <= SMLSIZ) {
      if (tid == 0) steqr_f32(d + goff, e + goff, m, Qm + goff * LDQ + goff, LDQ, sscr, sscr + 32);
      __syncthreads();
    } else {
      if (tid == 0) {
        float mx = 0.f;
        for (int i = 0; i < m; i++) mx = fmaxf(mx, fabsf(d[goff + i]));
        for (int i = 0; i < m - 1; i++) mx = fmaxf(mx, fabsf(e[goff + i]));
        shdf[0] = mx;
      }
      __syncthreads();
      float onrm = shdf[0];
      if (onrm != 0.f) {
        float mul = 1.f / onrm;
        for (int t = tid; t < m; t += 128) d[goff + t] *= mul;
        for (int t = tid; t < m - 1; t += 128) e[goff + t] *= mul;
        __syncthreads();
        laed0_f32(d, e, Qm, Q2, Sm, zv, dl, wv, wg, pvf, dvf, srcx, dsrc, iq,
                  iwps, sscr, goff, m, tid, shi, shdf, sdl, spv, defcnt);
        for (int t = tid; t < m; t += 128) d[goff + t] *= onrm;
        __syncthreads();
      }
    }
  }
  if (tid == 0) {
    for (int i = 0; i < NC; i++) shi[140 + i] = i;
    for (int ii2 = 2; ii2 <= NC; ii2++) {
      int i = ii2 - 1, kk2 = i;
      float p = d[i - 1];
      for (int j = ii2; j <= NC; j++) if (d[j - 1] < p) { kk2 = j; p = d[j - 1]; }
      if (kk2 != i) {
        d[kk2 - 1] = d[i - 1]; d[i - 1] = p;
        int tmp = shi[140 + i - 1]; shi[140 + i - 1] = shi[140 + kk2 - 1]; shi[140 + kk2 - 1] = tmp;
      }
    }
  }
  __syncthreads();
  // eigen-permutation via Q2, r-chunked over 4 groups (elementwise copies)
  {
    int j = tid & 127, g = tid >> 7;
    int chunk = 32;
    int rbeg = g * chunk, rend = rbeg + chunk;
    int src = shi[140 + j];
    for (int r = rbeg; r < rend; r++) Q2[j * 128 + r] = Qm[src * LDQ + r];
  }
  __syncthreads();
  {
    int j = tid & 127, g = tid >> 7;
    int chunk = 32;
    int rbeg = g * chunk, rend = rbeg + chunk;
    for (int r = rbeg; r < rend; r++) Qm[j * LDQ + r] = Q2[j * 128 + r];
  }
  __syncthreads();

  // ---------- Phase 3: sormtr('L','L','N') ----------
  for (int j1 = NC - 1; j1 >= 1; j1--) {
    int jj = j1 - 1;
    float tj = tauv[jj];
    if (tj != 0.f) {
      if (tid < NC) {
        int col = tid;
        float s = Qm[col * LDQ + jj + 1];
        for (int r = jj + 2; r < NC; r++) s += A[jj * 128 + r] * Qm[col * LDQ + r];
        s *= tj;
        Qm[col * LDQ + jj + 1] -= s;
        for (int r = jj + 2; r < NC; r++) Qm[col * LDQ + r] -= s * A[jj * 128 + r];
      }
    }
  }
  __syncthreads();

  // ---------- Phase 4: extract top-64 descending + writeback for diag ----------
  for (int idx = tid; idx < NC * KTOP; idx += THREADS) {
    int c2 = idx / KTOP, kk = idx % KTOP;
    Vw[(size_t)b * (NC * KTOP) + idx] = Qm[(127 - kk) * LDQ + c2];
  }
  for (int idx = tid; idx < 16384; idx += THREADS) {
    int c = idx >> 7, r = idx & 127;
    Qg[idx] = Qs[c * LDQ + r];
  }
  if (tid < 128) vecs[b * 128 + tid] = d[tid];
}

// ======================= diagnostics =======================

__global__ void zeroi_kernel(int* p) { p[0] = 0; p[1] = 0; }

__global__ __launch_bounds__(128) void diag_kernel(const float* __restrict__ covB,
                                                   const float* __restrict__ Qw,
                                                   const float* __restrict__ vecs,
                                                   const float* __restrict__ Vw, int* dcode) {
  int b = blockIdx.x, tid = threadIdx.x;
  const float* C = covB + (size_t)b * 16384;
  const float* Qm = Qw + (size_t)b * 16384;
  const float* d = vecs + b * 128;
  int flags = 0;
  double rmax = 0.0;
  for (int k = 64; k < 128; k++) {
    double lam = (double)d[k];
    double acc = 0.0;
    for (int j = 0; j < 128; j++) acc += (double)C[j * 128 + tid] * (double)Qm[k * 128 + j];
    acc -= lam * (double)Qm[k * 128 + tid];
    rmax = fmax(rmax, fabs(acc));
  }
  if (rmax > 1e-3) flags |= 1;
  double omax = 0.0;
  for (int p = tid; p < 64 * 64; p += 128) {
    int i = 64 + p / 64, j = 64 + p % 64;
    if (j < i) continue;
    double s = 0.0;
    for (int r = 0; r < 128; r++) s += (double)Qm[i * 128 + r] * (double)Qm[j * 128 + r];
    if (i == j) s -= 1.0;
    omax = fmax(omax, fabs(s));
  }
  if (omax > 1e-3) flags |= 2;
  if (tid < 127 && d[tid + 1] < d[tid] - 1e-5f) flags |= 4;
  for (int idx = tid; idx < 8192; idx += 128) {
    int c2 = idx / 64, kk = idx % 64;
    if (Vw[(size_t)b * 8192 + idx] != Qm[(127 - kk) * 128 + c2]) flags |= 8;
  }
  if (tid == 0) {
    for (int k = 64; k < 128; k++) if (!(d[k] > 0.2f && d[k] < 5.0f)) flags |= 16;
    float s = 0.f;
    for (int c = 0; c < 128; c++) { float v = Vw[(size_t)b * 8192 + c * 64]; s += v * v; }
    if (fabsf(s - 1.f) > 1e-2f) flags |= 32;
  }
  if (flags) atomicOr(dcode, flags);
}

__global__ void emit_kernel(const int* dcode, float* out) {
  int f = dcode[0];
  if (f) {
    int code = 1000;
    if (f & 1) code += 400;
    if (f & 2) code += 200;
    if (f & 4) code += 100;
    if (f & 8) code += 40;
    if (f & 16) code += 20;
    if (f & 32) code += 10;
    int nd = dcode[1]; if (nd > 9) nd = 9;
    code += nd;
    out[0] = (float)code;
  }
}

// ======================= numpy-f32-mirror mean / cov =======================

__global__ __launch_bounds__(128) void mean_np_kernel(const float* __restrict__ x,
                                                      float* __restrict__ mean32) {
  int b = blockIdx.x, c = threadIdx.x;
  const float* xb = x + (size_t)b * 2097152;
  float s = 0.0f;
  for (int n = 0; n < 16384; n++) s = __fadd_rn(s, xb[n * 128 + c]);
  mean32[b * 128 + c] = s / 16384.0f;
}

__global__ __launch_bounds__(256) void covnp_kernel(const float* __restrict__ x,
                                                    const float* __restrict__ mean32,
                                                    float* __restrict__ S) {
  int b = blockIdx.x;
  int ti = (blockIdx.y & 3) * 32, tj = (blockIdx.y >> 2) * 32;
  __shared__ float XI[32 * 64], XJ[32 * 64];
  int tid = threadIdx.x;
  int ci = 2 * (tid & 15), dj = 2 * (tid >> 4);
  float a00 = 0.f, a01 = 0.f, a10 = 0.f, a11 = 0.f;
  const float* xb = x + (size_t)b * 2097152;
  const float* mb = mean32 + b * 128;
  for (int n0 = 0; n0 < 16384; n0 += 64) {
    __syncthreads();
    for (int l = tid; l < 2048; l += 256) {
      int n = l >> 5, cc = l & 31;
      XI[cc * 64 + n] = __fsub_rn(xb[(n0 + n) * 128 + ti + cc], mb[ti + cc]);
      XJ[cc * 64 + n] = __fsub_rn(xb[(n0 + n) * 128 + tj + cc], mb[tj + cc]);
    }
    __syncthreads();
    const float* pi0 = &XI[ci * 64];
    const float* pi1 = pi0 + 64;
    const float* pj0 = &XJ[dj * 64];
    const float* pj1 = pj0 + 64;
    for (int n = 0; n < 64; n++) {
      float ai0 = pi0[n], ai1 = pi1[n], bj0 = pj0[n], bj1 = pj1[n];
      a00 = __fadd_rn(a00, __fmul_rn(ai0, bj0));
      a01 = __fadd_rn(a01, __fmul_rn(ai0, bj1));
      a10 = __fadd_rn(a10, __fmul_rn(ai1, bj0));
      a11 = __fadd_rn(a11, __fmul_rn(ai1, bj1));
    }
  }
  float* Sb = S + (size_t)b * 16384;
  int C = ti + ci, D = tj + dj;
  Sb[C * 128 + D] = a00;
  Sb[C * 128 + D + 1] = a01;
  Sb[(C + 1) * 128 + D] = a10;
  Sb[(C + 1) * 128 + D + 1] = a11;
}

__global__ void covfin_kernel(float* __restrict__ A, float* __restrict__ B) {
  int i = blockIdx.x * 256 + threadIdx.x;
  if (i < 262144) {
    float v = A[i] / 16383.0f;
    A[i] = v;
    B[i] = v;
  }
}

// ======================= projection =======================

__global__ __launch_bounds__(256) void proj_kernel(const float* __restrict__ x, const float* __restrict__ V,
                                                   const float* __restrict__ mean32, float* __restrict__ out) {
  __shared__ float Vs[128 * 64];
  __shared__ float Xs[64 * 128];
  __shared__ float ms[128];
  int b = blockIdx.x, t = blockIdx.y, tid = threadIdx.x;
  const float* xb = x + (size_t)b * 2097152 + (size_t)t * 64 * 128;
  const float* vb = V + (size_t)b * 8192;
  if (tid < 128) ms[tid] = mean32[b * 128 + tid];
  __syncthreads();
  for (int i = tid; i < 2048; i += 256) ((float4*)Vs)[i] = ((const float4*)vb)[i];
  for (int i = tid; i < 2048; i += 256) {
    float4 xv = ((const float4*)xb)[i];
    int cv = (i & 31) * 4;
    xv.x -= ms[cv]; xv.y -= ms[cv + 1]; xv.z -= ms[cv + 2]; xv.w -= ms[cv + 3];
    ((float4*)Xs)[i] = xv;
  }
  __syncthreads();
  int kk = tid & 63, w = tid >> 6;
  float acc[16];
#pragma unroll
  for (int r = 0; r < 16; r++) acc[r] = 0.f;
  for (int c4 = 0; c4 < 32; c4++) {
    float v0 = Vs[(c4 * 4 + 0) * 64 + kk];
    float v1 = Vs[(c4 * 4 + 1) * 64 + kk];
    float v2 = Vs[(c4 * 4 + 2) * 64 + kk];
    float v3 = Vs[(c4 * 4 + 3) * 64 + kk];
#pragma unroll
    for (int r = 0; r < 16; r++) {
      const float4 xv = ((const float4*)Xs)[(w * 16 + r) * 32 + c4];
      acc[r] += xv.x * v0 + xv.y * v1 + xv.z * v2 + xv.w * v3;
    }
  }
  float* ob = out + (size_t)b * 1048576 + (size_t)t * 4096;
#pragma unroll
  for (int r = 0; r < 16; r++) ob[(w * 16 + r) * 64 + kk] = acc[r];
}

// ======================= launch =======================

extern "C" void kernel_launch(void* const* d_in, const int* in_sizes, int n_in,
                              void* d_out, int out_size, void* d_ws, size_t ws_size,
                              hipStream_t stream) {
  (void)in_sizes; (void)n_in; (void)out_size; (void)ws_size;
  const float* x = (const float*)d_in[0];
  float* out = (float*)d_out;
  float* T = out + TBASEF;
  float* Af   = T + F_A;
  float* Bf   = T + F_B;
  float* Qf   = T + F_Q;
  float* Q2f  = T + F_Q2;
  float* Smf  = T + F_SM;
  float* vecsf = T + F_VECS;
  float* Vw = (float*)d_ws;
  float* mean32 = Vw + 131072;
  int* dcode = (int*)(mean32 + 2048);

  zeroi_kernel<<<dim3(1), dim3(1), 0, stream>>>(dcode);
  mean_np_kernel<<<dim3(16), dim3(128), 0, stream>>>(x, mean32);
  covnp_kernel<<<dim3(16, 16), dim3(256), 0, stream>>>(x, mean32, Af);
  covfin_kernel<<<dim3(1024), dim3(256), 0, stream>>>(Af, Bf);
  eig_f32_kernel<<<dim3(16), dim3(THREADS), 0, stream>>>(Af, Qf, Q2f, Smf, vecsf, Vw, dcode + 1);
  diag_kernel<<<dim3(16), dim3(128), 0, stream>>>(Bf, Qf, vecsf, Vw, dcode);
  proj_kernel<<<dim3(16, 256), dim3(256), 0, stream>>>(x, Vw, mean32, out);
  emit_kernel<<<dim3(1), dim3(1), 0, stream>>>(dcode, out);
}

// Round 3
// 6497.466 us; speedup vs baseline: 2.9739x; 1.2707x over previous
//
#include <hip/hip_runtime.h>

#define NC 128
#define KTOP 64
#define SMLSIZ 25
#define EPSF 5.9604645e-8f
#define SAFMINF 1.17549435e-38f
#define LDQ 129   // LDS leading dim for Qm: breaks 64-way bank conflicts on column-per-lane access
#define THREADS 512

// out-tail scratch (floats). out = 16,777,216 floats; scratch in top ~5.4MB,
// dead before proj overwrites out.
#define TBASEF 15400960
#define F_A    0         // 262144 f (raw cov sums -> cov, eig input)
#define F_B    262144    // 262144 f (pristine cov for diag)
#define F_Q    524288    // 262144 f (eigvec writeback for diag)
#define F_Q2   786432    // 266240 f (global scratch in merges, sliced by off*128)
#define F_SM   1052672   // 262144 f (secular matrix, TRANSPOSED + off-sliced)
#define F_VECS 1314816   // 18432 f (only d region [0..2047] used now)

// ======================= f32 LAPACK helpers =======================

__device__ __forceinline__ float slapy2f(float x, float y) {
  float xa = fabsf(x), ya = fabsf(y);
  float w = fmaxf(xa, ya), z = fminf(xa, ya);
  if (z == 0.f) return w;
  float r = z / w;
  return w * sqrtf(1.f + r * r);
}

// LAPACK >=3.10 slartg convention (c >= 0, r carries sign of f)
__device__ __forceinline__ void slartgf(float f, float g, float* c, float* s, float* r) {
  if (g == 0.f) { *c = 1.f; *s = 0.f; *r = f; }
  else if (f == 0.f) { *c = 0.f; *s = (g >= 0.f) ? 1.f : -1.f; *r = fabsf(g); }
  else {
    float d_ = sqrtf(f * f + g * g);
    *c = fabsf(f) / d_;
    *r = (f >= 0.f) ? d_ : -d_;
    *s = g / (*r);
  }
}

__device__ void slaev2f(float a, float b, float c,
                        float* rt1, float* rt2, float* cs1, float* sn1) {
  float sm = a + c, df = a - c, adf = fabsf(df), tb = b + b, ab = fabsf(tb);
  float acmx, acmn;
  if (fabsf(a) > fabsf(c)) { acmx = a; acmn = c; } else { acmx = c; acmn = a; }
  float rt;
  if (adf > ab) { float t = ab / adf; rt = adf * sqrtf(1.f + t * t); }
  else if (adf < ab) { float t = adf / ab; rt = ab * sqrtf(1.f + t * t); }
  else rt = ab * sqrtf(2.f);
  int sgn1;
  if (sm < 0.f) { *rt1 = 0.5f * (sm - rt); sgn1 = -1; *rt2 = (acmx / (*rt1)) * acmn - (b / (*rt1)) * b; }
  else if (sm > 0.f) { *rt1 = 0.5f * (sm + rt); sgn1 = 1; *rt2 = (acmx / (*rt1)) * acmn - (b / (*rt1)) * b; }
  else { *rt1 = 0.5f * rt; *rt2 = -0.5f * rt; sgn1 = 1; }
  float cs; int sgn2;
  if (df >= 0.f) { cs = df + rt; sgn2 = 1; } else { cs = df - rt; sgn2 = -1; }
  float acs = fabsf(cs);
  if (acs > ab) {
    float ct = -tb / cs;
    *sn1 = 1.f / sqrtf(1.f + ct * ct);
    *cs1 = ct * (*sn1);
  } else {
    if (ab == 0.f) { *cs1 = 1.f; *sn1 = 0.f; }
    else { float tn = -cs / tb; *cs1 = 1.f / sqrtf(1.f + tn * tn); *sn1 = tn * (*cs1); }
  }
  if (sgn1 == sgn2) { float tn = *cs1; *cs1 = -(*sn1); *sn1 = tn; }
}

// Faithful serial ssteqr('I'), WAVE-PARALLEL: all 64 lanes of one wave call
// this together. Scalar chain computed redundantly (uniform LDS reads -> same
// values in every lane); scalar LDS writes lane0-guarded; O(n^2) Z loops
// lane-strided. Same instruction ordering/values as the serial version.
__device__ void steqr_f32(float* d, float* e, int n, float* zb, int ldz,
                          float* cw, float* sw, int lane) {
  const float eps = EPSF;
  const float eps2 = eps * eps;
  const float safmin = SAFMINF;
  for (int j = 0; j < n; j++)
    for (int i = lane; i < n; i += 64) zb[j * ldz + i] = (i == j) ? 1.f : 0.f;
  if (n <= 1) return;
  int nmaxit = n * 30, jtot = 0;
  int l1 = 1;
  while (true) {
    if (l1 > n) break;
    if (l1 > 1) { if (lane == 0) e[l1 - 2] = 0.f; }
    int m;
    {
      int mm_;
      for (mm_ = l1; mm_ <= n - 1; mm_++) {
        float tst = fabsf(e[mm_ - 1]);
        if (tst == 0.f) break;
        if (tst <= (sqrtf(fabsf(d[mm_ - 1])) * sqrtf(fabsf(d[mm_]))) * eps) {
          if (lane == 0) e[mm_ - 1] = 0.f;
          break;
        }
      }
      m = mm_;
    }
    int l = l1, lsv = l, lend = m, lendsv = lend;
    l1 = m + 1;
    if (lend == l) continue;
    float anorm = 0.f;
    for (int i = l; i <= lend; i++) anorm = fmaxf(anorm, fabsf(d[i - 1]));
    for (int i = l; i <= lend - 1; i++) anorm = fmaxf(anorm, fabsf(e[i - 1]));
    if (anorm == 0.f) continue;
    if (fabsf(d[lend - 1]) < fabsf(d[l - 1])) { lend = lsv; l = lendsv; }
    if (lend > l) {
      // ---- QL ----
      while (true) {
        int m2;
        {
          int i;
          for (i = l; i <= lend - 1; i++) {
            float tst = fabsf(e[i - 1]); tst = tst * tst;
            if (tst <= (eps2 * fabsf(d[i - 1])) * fabsf(d[i]) + safmin) break;
          }
          m2 = i;
        }
        if (m2 < lend) { if (lane == 0) e[m2 - 1] = 0.f; }
        float p = d[l - 1];
        if (m2 == l) { if (lane == 0) d[l - 1] = p; l++; if (l <= lend) continue; else break; }
        if (m2 == l + 1) {
          float rt1, rt2, c_, s_;
          slaev2f(d[l - 1], e[l - 1], d[l], &rt1, &rt2, &c_, &s_);
          for (int i = lane; i < n; i += 64) {
            float t1 = zb[l * ldz + i];
            float t0 = zb[(l - 1) * ldz + i];
            zb[l * ldz + i] = c_ * t1 - s_ * t0;
            zb[(l - 1) * ldz + i] = s_ * t1 + c_ * t0;
          }
          if (lane == 0) { d[l - 1] = rt1; d[l] = rt2; e[l - 1] = 0.f; }
          l += 2; if (l <= lend) continue; else break;
        }
        if (jtot == nmaxit) break;
        jtot++;
        float g = (d[l] - p) / (2.f * e[l - 1]);
        float r = slapy2f(g, 1.f);
        g = d[m2 - 1] - p + e[l - 1] / (g + copysignf(r, g));
        float s_ = 1.f, c_ = 1.f; p = 0.f;
        for (int i = m2 - 1; i >= l; i--) {
          float f = s_ * e[i - 1], b2 = c_ * e[i - 1];
          float cc, ss, rr;
          slartgf(g, f, &cc, &ss, &rr);
          c_ = cc; s_ = ss;
          if (i != m2 - 1) { if (lane == 0) e[i] = rr; }
          g = d[i] - p;
          rr = (d[i - 1] - g) * s_ + 2.f * c_ * b2;
          p = s_ * rr;
          if (lane == 0) d[i] = g + p;
          g = c_ * rr - b2;
          if (lane == 0) { cw[i - l] = c_; sw[i - l] = -s_; }
        }
        int mm2 = m2 - l + 1;
        for (int jj = mm2 - 2; jj >= 0; jj--) {
          float ct_ = cw[jj], st_ = sw[jj];
          int colj = l - 1 + jj;
          for (int i = lane; i < n; i += 64) {
            float t1 = zb[(colj + 1) * ldz + i];
            float t0 = zb[colj * ldz + i];
            zb[(colj + 1) * ldz + i] = ct_ * t1 - st_ * t0;
            zb[colj * ldz + i] = st_ * t1 + ct_ * t0;
          }
        }
        if (lane == 0) { d[l - 1] -= p; e[l - 1] = g; }
      }
    } else {
      // ---- QR ----
      while (true) {
        int m2;
        {
          int i;
          for (i = l; i >= lend + 1; i--) {
            float tst = fabsf(e[i - 2]); tst = tst * tst;
            if (tst <= (eps2 * fabsf(d[i - 1])) * fabsf(d[i - 2]) + safmin) break;
          }
          m2 = i;
        }
        if (m2 > lend) { if (lane == 0) e[m2 - 2] = 0.f; }
        float p = d[l - 1];
        if (m2 == l) { if (lane == 0) d[l - 1] = p; l--; if (l >= lend) continue; else break; }
        if (m2 == l - 1) {
          float rt1, rt2, c_, s_;
          slaev2f(d[l - 2], e[l - 2], d[l - 1], &rt1, &rt2, &c_, &s_);
          for (int i = lane; i < n; i += 64) {
            float t1 = zb[(l - 1) * ldz + i];
            float t0 = zb[(l - 2) * ldz + i];
            zb[(l - 1) * ldz + i] = c_ * t1 - s_ * t0;
            zb[(l - 2) * ldz + i] = s_ * t1 + c_ * t0;
          }
          if (lane == 0) { d[l - 2] = rt1; d[l - 1] = rt2; e[l - 2] = 0.f; }
          l -= 2; if (l >= lend) continue; else break;
        }
        if (jtot == nmaxit) break;
        jtot++;
        float g = (d[l - 2] - p) / (2.f * e[l - 2]);
        float r = slapy2f(g, 1.f);
        g = d[m2 - 1] - p + e[l - 2] / (g + copysignf(r, g));
        float s_ = 1.f, c_ = 1.f; p = 0.f;
        for (int i = m2; i <= l - 1; i++) {
          float f = s_ * e[i - 1], b2 = c_ * e[i - 1];
          float cc, ss, rr;
          slartgf(g, f, &cc, &ss, &rr);
          c_ = cc; s_ = ss;
          if (i != m2) { if (lane == 0) e[i - 2] = rr; }
          g = d[i - 1] - p;
          rr = (d[i] - g) * s_ + 2.f * c_ * b2;
          p = s_ * rr;
          if (lane == 0) d[i - 1] = g + p;
          g = c_ * rr - b2;
          if (lane == 0) { cw[i - m2] = c_; sw[i - m2] = s_; }
        }
        int mm2 = l - m2 + 1;
        for (int jj = 0; jj <= mm2 - 2; jj++) {
          float ct_ = cw[jj], st_ = sw[jj];
          int colj = m2 - 1 + jj;
          for (int i = lane; i < n; i += 64) {
            float t1 = zb[(colj + 1) * ldz + i];
            float t0 = zb[colj * ldz + i];
            zb[(colj + 1) * ldz + i] = ct_ * t1 - st_ * t0;
            zb[colj * ldz + i] = st_ * t1 + ct_ * t0;
          }
        }
        if (lane == 0) { d[l - 1] -= p; e[l - 2] = g; }
      }
    }
  }
  for (int ii = 2; ii <= n; ii++) {
    int i = ii - 1, k = i;
    float p = d[i - 1];
    for (int j = ii; j <= n; j++) if (d[j - 1] < p) { k = j; p = d[j - 1]; }
    if (k != i) {
      if (lane == 0) { d[k - 1] = d[i - 1]; d[i - 1] = p; }
      for (int r = lane; r < n; r += 64) {
        float t5 = zb[(i - 1) * ldz + r];
        zb[(i - 1) * ldz + r] = zb[(k - 1) * ldz + r];
        zb[(k - 1) * ldz + r] = t5;
      }
    }
  }
}

// ======================= f32 D&C merge, MULTI-GROUP (slaed1/2/3 semantics) ===
// G independent same-level merges execute concurrently in G thread-groups.
// All per-merge state sliced disjointly by `off`; every __syncthreads is
// group-uniform (hit by all 512 threads). Per-merge arithmetic identical
// (same slices, same orders) to the sequential version -> bit-identical.

__device__ void laed1_multi(float* d, float* e, float* Qm, float* Q2b, float* Smb,
                            float* zv, float* dl, float* wv, float* wg, float* pvf,
                            float* dvf, int* srcx, int* dsrc, int* iq,
                            int goff, const int* iwps, int p0, int G,
                            int tid, int* shi, float* shdf,
                            double* sdl, double* spv, int* defcnt) {
  int Tg = THREADS / G;
  int g = tid / Tg, gtid = tid - g * Tg;
  int pg = 2 * (p0 + g);
  int prev = (pg == 0) ? 0 : iwps[pg - 1];
  int off = goff + prev;
  int n = iwps[pg + 1] - prev;
  int n1 = (pg == 0) ? iwps[0] : (n / 2);
  int n2 = n - n1;
  float rho_in = e[off + n1 - 1];
  float* dg = d + off;
  float* zvg = zv + off;  float* dlg = dl + off;  float* wvg = wv + off;
  float* wgg = wg + off;  float* pvfg = pvf + off; float* dvfg = dvf + off;
  int* srcxg = srcx + off; int* dsrcg = dsrc + off; int* iqg = iq + off;
  double* sdlg = sdl + off; double* spvg = spv + off;
  float* Q2g = Q2b + (size_t)off * 128;
  float* Smg = Smb + (size_t)off * 128 + off;

  for (int t = gtid; t < n1; t += Tg) zvg[t] = Qm[(off + t) * LDQ + off + n1 - 1];
  for (int t = gtid; t < n2; t += Tg) zvg[n1 + t] = Qm[(off + n1 + t) * LDQ + off + n1];
  __syncthreads();                                   // B1
  if (gtid == 0) {
    float rho = rho_in;
    if (rho < 0.f) for (int t = n1; t < n; t++) zvg[t] = -zvg[t];
    float tsc = 1.0f / sqrtf(2.0f);
    for (int t = 0; t < n; t++) zvg[t] *= tsc;
    rho = fabsf(2.0f * rho);
    {
      int i = 0, j = n1, p = 0;
      while (i < n1 && j < n) {
        if (dg[i] <= dg[j]) srcxg[p++] = i++; else srcxg[p++] = j++;
      }
      while (i < n1) srcxg[p++] = i++;
      while (j < n) srcxg[p++] = j++;
    }
    int imax = 0, jmax = 0;
    for (int t = 1; t < n; t++) if (fabsf(zvg[t]) > fabsf(zvg[imax])) imax = t;
    for (int t = 1; t < n; t++) if (fabsf(dg[t]) > fabsf(dg[jmax])) jmax = t;
    float tol = 8.0f * EPSF * fmaxf(fabsf(dg[jmax]), fabsf(zvg[imax]));
    int k = 0, nd = 0;
    if (rho * fabsf(zvg[imax]) <= tol) {
      for (int t = 0; t < n; t++) { dsrcg[nd] = srcxg[t]; dvfg[nd] = dg[srcxg[t]]; nd++; }
    } else {
      int pj = -1;
      for (int jj = 0; jj < n; jj++) {
        int nj = srcxg[jj];
        if (rho * fabsf(zvg[nj]) <= tol) {
          dsrcg[nd] = nj; dvfg[nd] = dg[nj]; nd++;
        } else if (pj < 0) {
          pj = nj;
        } else {
          float s_ = zvg[pj], c_ = zvg[nj];
          float tau_ = slapy2f(c_, s_);
          float t3 = dg[nj] - dg[pj];
          c_ /= tau_; s_ = -s_ / tau_;
          if (fabsf(t3 * c_ * s_) <= tol) {
            zvg[nj] = tau_; zvg[pj] = 0.f;
            for (int r = 0; r < n; r++) {
              float x_ = Qm[(off + pj) * LDQ + off + r];
              float y_ = Qm[(off + nj) * LDQ + off + r];
              Qm[(off + pj) * LDQ + off + r] = c_ * x_ + s_ * y_;
              Qm[(off + nj) * LDQ + off + r] = c_ * y_ - s_ * x_;
            }
            float dp = dg[pj], dn = dg[nj];
            dg[nj] = dp * s_ * s_ + dn * c_ * c_;
            dg[pj] = dp * c_ * c_ + dn * s_ * s_;
            dsrcg[nd] = pj; dvfg[nd] = dg[pj]; nd++;
            pj = nj;
          } else {
            dlg[k] = dg[pj]; wvg[k] = zvg[pj]; srcxg[k] = pj; k++;
            pj = nj;
          }
        }
      }
      if (pj >= 0) { dlg[k] = dg[pj]; wvg[k] = zvg[pj]; srcxg[k] = pj; k++; }
    }
    shi[200 + g] = k; shi[208 + g] = nd; shdf[8 + g] = rho;
    if (nd > 0) atomicAdd(defcnt, nd);
  }
  __syncthreads();                                   // B2
  int k = shi[200 + g], nd = shi[208 + g];
  float rho = shdf[8 + g];
  if (k > 1) {
    for (int t = gtid; t < k; t += Tg) {
      sdlg[t] = (double)dlg[t];
      spvg[t] = (double)rho * (double)wvg[t] * (double)wvg[t];
    }
  }
  __syncthreads();                                   // B3
  // secular roots in f64, shifted frame: lambda_j = dl_j + eta
  if (k > 1 && gtid < k) {
    int j = gtid;
    double lo = 0.0, hi;
    if (j == k - 1) {
      double sw2 = 0.0;
      for (int t = 0; t < k; t++) sw2 += spvg[t];
      hi = sw2;
      for (int g2 = 0; g2 < 8; g2++) {
        double f = 1.0;
        for (int t = 0; t < k; t++) f += spvg[t] / ((sdlg[t] - sdlg[j]) - hi);
        if (f >= 0.0) break;
        hi *= 2.0;
      }
    } else hi = sdlg[j + 1] - sdlg[j];
    double gap = hi;
    for (int it = 0; it < 110; it++) {
      double mid = 0.5 * (lo + hi);
      if (!(mid > lo && mid < hi)) break;
      double f = 1.0;
      for (int t = 0; t < k; t++) f += spvg[t] / ((sdlg[t] - sdlg[j]) - mid);
      if (f < 0.0) lo = mid; else hi = mid;
    }
    double eta = 0.5 * (lo + hi);
    if (eta <= 0.0) eta = gap * 1e-30;
    if (j < k - 1 && eta >= gap) eta = gap * (1.0 - 1e-15);
    dg[j] = (float)(sdlg[j] + eta);
    for (int t = 0; t < k; t++)
      Smg[t * 128 + j] = (float)((sdlg[t] - sdlg[j]) - eta);
  }
  __syncthreads();                                   // B4
  // Gu-Eisenstat reweighting (f32, as slaed3)
  if (k > 1 && gtid < k) {
    int i = gtid;
    float acc = Smg[i * 128 + i];
    for (int j = 0; j < k; j++) {
      if (j == i) continue;
      acc *= Smg[i * 128 + j] / (dlg[i] - dlg[j]);
    }
    wgg[i] = copysignf(sqrtf(fmaxf(-acc, 0.f)), wvg[i]);
  }
  __syncthreads();                                   // B5
  // secular vectors + positive normalization (thread j, exact order)
  if (k > 1 && gtid < k) {
    int j = gtid;
    float nrm2 = 0.f;
    for (int i = 0; i < k; i++) {
      float u = wgg[i] / Smg[i * 128 + j];
      Smg[i * 128 + j] = u;
      nrm2 += u * u;
    }
    float nrm = sqrtf(nrm2);
    for (int i = 0; i < k; i++) Smg[i * 128 + j] /= nrm;
  }
  __syncthreads();                                   // B6
  if (k > 1) {
    // gather Q2g[j][r] = sum_i Qm[off+srcxg[i]][off+r] * Smg[i][j]
    // r-chunked across RG sub-groups, 8-wide r-tiling; i-ascending -> exact.
    int j = gtid & 127, rg = gtid >> 7;
    int RG = Tg >> 7; if (RG < 1) RG = 1;
    if (j < k) {
      int chunk = (n + RG - 1) / RG;
      int rbeg = rg * chunk, rend = rbeg + chunk;
      if (rend > n) rend = n;
      int r0 = rbeg;
      for (; r0 + 8 <= rend; r0 += 8) {
        float a0 = 0.f, a1 = 0.f, a2 = 0.f, a3 = 0.f;
        float a4 = 0.f, a5 = 0.f, a6 = 0.f, a7 = 0.f;
        for (int i = 0; i < k; i++) {
          float s = Smg[i * 128 + j];
          const float* q = &Qm[(off + srcxg[i]) * LDQ + off + r0];
          a0 += q[0] * s; a1 += q[1] * s; a2 += q[2] * s; a3 += q[3] * s;
          a4 += q[4] * s; a5 += q[5] * s; a6 += q[6] * s; a7 += q[7] * s;
        }
        float* o = &Q2g[j * 128 + r0];
        o[0] = a0; o[1] = a1; o[2] = a2; o[3] = a3;
        o[4] = a4; o[5] = a5; o[6] = a6; o[7] = a7;
      }
      for (; r0 < rend; r0++) {
        float a = 0.f;
        for (int i = 0; i < k; i++)
          a += Qm[(off + srcxg[i]) * LDQ + off + r0] * Smg[i * 128 + j];
        Q2g[j * 128 + r0] = a;
      }
    }
  } else if (k == 1 && gtid == 0) {
    zvg[0] = dlg[0] + rho * (wvg[0] * wvg[0]);
    for (int r = 0; r < n; r++) Q2g[r] = Qm[(off + srcxg[0]) * LDQ + off + r];
  }
  __syncthreads();                                   // B7
  if (k > 1 && gtid < k) zvg[gtid] = dg[gtid];
  __syncthreads();                                   // B8
  for (int t2 = gtid; t2 < nd; t2 += Tg)
    for (int r = 0; r < n; r++) Q2g[(k + t2) * 128 + r] = Qm[(off + dsrcg[t2]) * LDQ + off + r];
  for (int j = gtid; j < n; j += Tg) pvfg[j] = (j < k) ? zvg[j] : dvfg[j - k];
  __syncthreads();                                   // B9
  // ascending physical sort: dense key mirror (ks[j]==pvfg[iqg[j]] invariant)
  // -> identical compare/swap decisions, pipelined linear scans.
  if (gtid == 0) {
    float* ks = wgg;  // dead here
    for (int i = 0; i < n; i++) { iqg[i] = i; ks[i] = pvfg[i]; }
    for (int i = 0; i < n - 1; i++) {
      int kb = i;
      float vkb = ks[i];
      for (int j = i + 1; j < n; j++) {
        float vj = ks[j];
        if (vj < vkb) { kb = j; vkb = vj; }
      }
      if (kb != i) {
        int tt = iqg[i]; iqg[i] = iqg[kb]; iqg[kb] = tt;
        float tf = ks[i]; ks[i] = ks[kb]; ks[kb] = tf;
      }
    }
  }
  __syncthreads();                                   // B10
  // permuted writeback, r-chunked (elementwise, exact)
  {
    int j = gtid & 127, rg = gtid >> 7;
    int RG = Tg >> 7; if (RG < 1) RG = 1;
    if (j < n) {
      int s2 = iqg[j];
      if (rg == 0) dg[j] = pvfg[s2];
      int chunk = (n + RG - 1) / RG;
      int rbeg = rg * chunk, rend = rbeg + chunk;
      if (rend > n) rend = n;
      for (int r = rbeg; r < rend; r++) Qm[(off + j) * LDQ + off + r] = Q2g[s2 * 128 + r];
    }
  }
  __syncthreads();                                   // B11
}

__device__ void laed0_f32(float* d, float* e, float* Qm, float* Q2, float* Sm,
                          float* zv, float* dl, float* wv, float* wg, float* pvf,
                          float* dvf, int* srcx, int* dsrc, int* iq, int* iwps,
                          float* sscr,
                          int goff, int m, int tid, int* shi, float* shdf,
                          double* sdl, double* spv, int* defcnt) {
  if (tid == 0) {
    iwps[0] = m; int sp = 1;
    while (iwps[sp - 1] > SMLSIZ) {
      for (int j = sp - 1; j >= 0; j--) { iwps[2 * j + 1] = (iwps[j] + 1) / 2; iwps[2 * j] = iwps[j] / 2; }
      sp *= 2;
    }
    for (int j = 1; j < sp; j++) iwps[j] += iwps[j - 1];
    shi[134] = sp;
    for (int i = 0; i < sp - 1; i++) {
      int bnd = goff + iwps[i];
      d[bnd - 1] -= fabsf(e[bnd - 1]);
      d[bnd] -= fabsf(e[bnd - 1]);
    }
  }
  __syncthreads();
  int subpbs = shi[134];
  // leaves: wave-parallel steqr, one leaf per wave (8 waves @ 512 threads)
  {
    int lw = tid >> 6;
    if (lw < subpbs) {
      int boff = goff + (lw == 0 ? 0 : iwps[lw - 1]);
      int bm = iwps[lw] - (lw == 0 ? 0 : iwps[lw - 1]);
      steqr_f32(d + boff, e + boff, bm, Qm + boff * LDQ + boff, LDQ,
                sscr + lw * 64, sscr + lw * 64 + 32, tid & 63);
    }
  }
  __syncthreads();
  int cur = subpbs;
  while (cur > 1) {
    int nm = cur >> 1;
    for (int p0 = 0; p0 < nm; ) {
      int G = (nm - p0 >= 4) ? 4 : ((nm - p0 >= 2) ? 2 : 1);
      laed1_multi(d, e, Qm, Q2, Sm, zv, dl, wv, wg, pvf, dvf, srcx, dsrc, iq,
                  goff, iwps, p0, G, tid, shi, shdf, sdl, spv, defcnt);
      p0 += G;
    }
    if (tid == 0) for (int t = 0; 2 * t + 1 < cur; t++) iwps[t] = iwps[2 * t + 1];
    __syncthreads();
    cur >>= 1;
  }
}

// ======================= eig kernel: ssyevd emulation per batch =======================
// Hot state in LDS (~140KB/block, 1 block/CU, 16 blocks). 512 threads = 8 waves.
// Same-level D&C merges run concurrently in thread-groups; Phase-1 reductions
// use in-wave shfl butterflies (lane0 value == sequential tree, bit-exact).

__global__ __launch_bounds__(THREADS) void eig_f32_kernel(const float* __restrict__ covA,
                                                          float* __restrict__ Qw,
                                                          float* Q2w, float* Sw, float* vecs,
                                                          float* Vw, int* defcnt) {
  int b = blockIdx.x, tid = threadIdx.x;
  const float* Ag = covA + (size_t)b * 16384;
  float* Qg = Qw + (size_t)b * 16384;
  float* Q2 = Q2w + (size_t)b * 16640;
  float* Sm = Sw + (size_t)b * 16384;

  __shared__ float As[16384];
  __shared__ float Qs[128 * LDQ];
  __shared__ float sh_d[128], sh_e[128], sh_tau[128], sh_zv[128], sh_dl[128];
  __shared__ float sh_wv[128], sh_wg[128], sh_pvf[128], sh_dvf[128];
  __shared__ int sh_iq[128], sh_srcx[128], sh_dsrc[128];
  __shared__ int iwps[64];
  __shared__ float sscr[512];   // 8 leaf workers x (cw[32]+sw[32])
  __shared__ float redf[128];
  __shared__ float shdf[16];
  __shared__ int shi[280];
  __shared__ double sdl[128];
  __shared__ double spv[128];

  float* A = As;
  float* Qm = Qs;
  float* d = sh_d; float* e = sh_e; float* tauv = sh_tau; float* zv = sh_zv;
  float* dl = sh_dl; float* wv = sh_wv; float* wg = sh_wg; float* pvf = sh_pvf;
  float* dvf = sh_dvf;
  int* iq = sh_iq; int* srcx = sh_srcx; int* dsrc = sh_dsrc;

  // stage cov into LDS
  for (int idx = tid; idx < 16384; idx += THREADS) As[idx] = Ag[idx];
  __syncthreads();

  // ---------- Phase 1: ssytd2 (UPLO='L') ----------
  // Householder head element is IMPLICIT 1 (no A write/restore; nothing reads
  // that slot afterward). Reductions: 128-wide pair-add + wave butterfly;
  // lane0 result bit-identical to the sequential tree.
  for (int i1 = 1; i1 <= NC - 1; i1++) {
    int ii = i1 - 1;
    int mlen = NC - i1;
    float ps = 0.f;
    if (tid < 128) {
      for (int t = tid; t < mlen - 1; t += 128) {
        float v = A[ii * 128 + ii + 2 + t];
        ps += v * v;
      }
      redf[tid] = ps;
    }
    __syncthreads();                               // B1
    if (tid < 64) {
      float a = redf[tid] + redf[tid + 64];
      a += __shfl_xor(a, 32); a += __shfl_xor(a, 16); a += __shfl_xor(a, 8);
      a += __shfl_xor(a, 4);  a += __shfl_xor(a, 2);  a += __shfl_xor(a, 1);
      if (tid == 0) {
        float xnorm = sqrtf(a);
        float alpha = A[ii * 128 + ii + 1];
        float taui, ei, scl;
        if (xnorm == 0.f) { taui = 0.f; ei = alpha; scl = 0.f; }
        else {
          float beta = -copysignf(slapy2f(alpha, xnorm), alpha);
          taui = (beta - alpha) / beta;
          scl = 1.f / (alpha - beta);
          ei = beta;
        }
        e[ii] = ei; tauv[ii] = taui; shdf[2] = scl;
      }
    }
    __syncthreads();                               // B2
    float taui = tauv[ii];
    if (taui != 0.f) {
      float scl = shdf[2];
      for (int t = tid; t < mlen - 1; t += 128) A[ii * 128 + ii + 2 + t] *= scl;
      __syncthreads();                             // B3
      for (int r = tid; r < mlen; r += 128) {
        float acc = 0.f;
        int row = ii + 1 + r;
        acc += A[(ii + 1) * 128 + row];            // s=0 term, v0 == 1
        for (int s = 1; s < mlen; s++) acc += A[(ii + 1 + s) * 128 + row] * A[ii * 128 + ii + 1 + s];
        pvf[r] = taui * acc;
      }
      __syncthreads();                             // B4
      if (tid < 128) {
        float pd = 0.f;
        for (int t = tid; t < mlen; t += 128) {
          float vt = (t == 0) ? 1.f : A[ii * 128 + ii + 1 + t];
          pd += pvf[t] * vt;
        }
        redf[tid] = pd;
      }
      __syncthreads();                             // B5
      if (tid < 64) {
        float a = redf[tid] + redf[tid + 64];
        a += __shfl_xor(a, 32); a += __shfl_xor(a, 16); a += __shfl_xor(a, 8);
        a += __shfl_xor(a, 4);  a += __shfl_xor(a, 2);  a += __shfl_xor(a, 1);
        if (tid == 0) shdf[3] = -0.5f * taui * a;
      }
      __syncthreads();                             // B6
      float alpha2 = shdf[3];
      for (int t = tid; t < mlen; t += 128) {
        float vt = (t == 0) ? 1.f : A[ii * 128 + ii + 1 + t];
        pvf[t] += alpha2 * vt;
      }
      __syncthreads();                             // B7
      // rank-2 update: (r, c2-chunk) across 4 thread groups
      if ((tid & 127) < mlen) {
        int r = tid & 127, g = tid >> 7;
        int chunk = (mlen + 3) >> 2;
        int cb = g * chunk, ce = cb + chunk;
        if (ce > mlen) ce = mlen;
        float vr = (r == 0) ? 1.f : A[ii * 128 + ii + 1 + r];
        float pr = pvf[r];
        for (int c2 = cb; c2 < ce; c2++) {
          float vc = (c2 == 0) ? 1.f : A[ii * 128 + ii + 1 + c2];
          A[(ii + 1 + c2) * 128 + (ii + 1 + r)] -= vr * pvf[c2] + pr * vc;
        }
      }
      __syncthreads();                             // B8
    }
  }
  for (int t = tid; t < NC; t += 128) d[t] = A[t * 128 + t];
  __syncthreads();

  // ---------- Phase 2: sstedc('I') ----------
  for (int idx = tid; idx < 16384; idx += THREADS) {
    int c = idx >> 7, r = idx & 127;
    Qs[c * LDQ + r] = (c == r) ? 1.f : 0.f;
  }
  __syncthreads();
  if (tid == 0) {
    int ns = 0, start = 0;
    while (start < NC) {
      int fin = start;
      while (fin < NC - 1) {
        float tiny = EPSF * sqrtf(fabsf(d[fin])) * sqrtf(fabsf(d[fin + 1]));
        if (fabsf(e[fin]) > tiny) fin++;
        else break;
      }
      shi[2 + 2 * ns] = start; shi[3 + 2 * ns] = fin - start + 1; ns++;
      start = fin + 1;
    }
    shi[0] = ns;
  }
  __syncthreads();
  int nsplit = shi[0];
  for (int sb = 0; sb < nsplit; sb++) {
    int goff = shi[2 + 2 * sb], m = shi[3 + 2 * sb];
    if (m == 1) continue;
    if (m <= SMLSIZ) {
      if (tid < 64) steqr_f32(d + goff, e + goff, m, Qm + goff * LDQ + goff, LDQ,
                              sscr, sscr + 32, tid);
      __syncthreads();
    } else {
      if (tid == 0) {
        float mx = 0.f;
        for (int i = 0; i < m; i++) mx = fmaxf(mx, fabsf(d[goff + i]));
        for (int i = 0; i < m - 1; i++) mx = fmaxf(mx, fabsf(e[goff + i]));
        shdf[0] = mx;
      }
      __syncthreads();
      float onrm = shdf[0];
      if (onrm != 0.f) {
        float mul = 1.f / onrm;
        for (int t = tid; t < m; t += 128) d[goff + t] *= mul;
        for (int t = tid; t < m - 1; t += 128) e[goff + t] *= mul;
        __syncthreads();
        laed0_f32(d, e, Qm, Q2, Sm, zv, dl, wv, wg, pvf, dvf, srcx, dsrc, iq,
                  iwps, sscr, goff, m, tid, shi, shdf, sdl, spv, defcnt);
        for (int t = tid; t < m; t += 128) d[goff + t] *= onrm;
        __syncthreads();
      }
    }
  }
  if (tid == 0) {
    for (int i = 0; i < NC; i++) shi[140 + i] = i;
    for (int ii2 = 2; ii2 <= NC; ii2++) {
      int i = ii2 - 1, kk2 = i;
      float p = d[i - 1];
      for (int j = ii2; j <= NC; j++) if (d[j - 1] < p) { kk2 = j; p = d[j - 1]; }
      if (kk2 != i) {
        d[kk2 - 1] = d[i - 1]; d[i - 1] = p;
        int tmp = shi[140 + i - 1]; shi[140 + i - 1] = shi[140 + kk2 - 1]; shi[140 + kk2 - 1] = tmp;
      }
    }
  }
  __syncthreads();
  // eigen-permutation via Q2, r-chunked over 4 groups (elementwise copies)
  {
    int j = tid & 127, g = tid >> 7;
    int rbeg = g * 32, rend = rbeg + 32;
    int src = shi[140 + j];
    for (int r = rbeg; r < rend; r++) Q2[j * 128 + r] = Qm[src * LDQ + r];
  }
  __syncthreads();
  {
    int j = tid & 127, g = tid >> 7;
    int rbeg = g * 32, rend = rbeg + 32;
    for (int r = rbeg; r < rend; r++) Qm[j * LDQ + r] = Q2[j * 128 + r];
  }
  __syncthreads();

  // ---------- Phase 3: sormtr('L','L','N') ----------
  for (int j1 = NC - 1; j1 >= 1; j1--) {
    int jj = j1 - 1;
    float tj = tauv[jj];
    if (tj != 0.f) {
      if (tid < NC) {
        int col = tid;
        float s = Qm[col * LDQ + jj + 1];
        for (int r = jj + 2; r < NC; r++) s += A[jj * 128 + r] * Qm[col * LDQ + r];
        s *= tj;
        Qm[col * LDQ + jj + 1] -= s;
        for (int r = jj + 2; r < NC; r++) Qm[col * LDQ + r] -= s * A[jj * 128 + r];
      }
    }
  }
  __syncthreads();

  // ---------- Phase 4: extract top-64 descending + writeback for diag ----------
  for (int idx = tid; idx < NC * KTOP; idx += THREADS) {
    int c2 = idx / KTOP, kk = idx % KTOP;
    Vw[(size_t)b * (NC * KTOP) + idx] = Qm[(127 - kk) * LDQ + c2];
  }
  for (int idx = tid; idx < 16384; idx += THREADS) {
    int c = idx >> 7, r = idx & 127;
    Qg[idx] = Qs[c * LDQ + r];
  }
  if (tid < 128) vecs[b * 128 + tid] = d[tid];
}

// ======================= diagnostics =======================

__global__ void zeroi_kernel(int* p) { p[0] = 0; p[1] = 0; }

__global__ __launch_bounds__(128) void diag_kernel(const float* __restrict__ covB,
                                                   const float* __restrict__ Qw,
                                                   const float* __restrict__ vecs,
                                                   const float* __restrict__ Vw, int* dcode) {
  int b = blockIdx.x, tid = threadIdx.x;
  const float* C = covB + (size_t)b * 16384;
  const float* Qm = Qw + (size_t)b * 16384;
  const float* d = vecs + b * 128;
  int flags = 0;
  double rmax = 0.0;
  for (int k = 64; k < 128; k++) {
    double lam = (double)d[k];
    double acc = 0.0;
    for (int j = 0; j < 128; j++) acc += (double)C[j * 128 + tid] * (double)Qm[k * 128 + j];
    acc -= lam * (double)Qm[k * 128 + tid];
    rmax = fmax(rmax, fabs(acc));
  }
  if (rmax > 1e-3) flags |= 1;
  double omax = 0.0;
  for (int p = tid; p < 64 * 64; p += 128) {
    int i = 64 + p / 64, j = 64 + p % 64;
    if (j < i) continue;
    double s = 0.0;
    for (int r = 0; r < 128; r++) s += (double)Qm[i * 128 + r] * (double)Qm[j * 128 + r];
    if (i == j) s -= 1.0;
    omax = fmax(omax, fabs(s));
  }
  if (omax > 1e-3) flags |= 2;
  if (tid < 127 && d[tid + 1] < d[tid] - 1e-5f) flags |= 4;
  for (int idx = tid; idx < 8192; idx += 128) {
    int c2 = idx / 64, kk = idx % 64;
    if (Vw[(size_t)b * 8192 + idx] != Qm[(127 - kk) * 128 + c2]) flags |= 8;
  }
  if (tid == 0) {
    for (int k = 64; k < 128; k++) if (!(d[k] > 0.2f && d[k] < 5.0f)) flags |= 16;
    float s = 0.f;
    for (int c = 0; c < 128; c++) { float v = Vw[(size_t)b * 8192 + c * 64]; s += v * v; }
    if (fabsf(s - 1.f) > 1e-2f) flags |= 32;
  }
  if (flags) atomicOr(dcode, flags);
}

__global__ void emit_kernel(const int* dcode, float* out) {
  int f = dcode[0];
  if (f) {
    int code = 1000;
    if (f & 1) code += 400;
    if (f & 2) code += 200;
    if (f & 4) code += 100;
    if (f & 8) code += 40;
    if (f & 16) code += 20;
    if (f & 32) code += 10;
    int nd = dcode[1]; if (nd > 9) nd = 9;
    code += nd;
    out[0] = (float)code;
  }
}

// ======================= numpy-f32-mirror mean / cov =======================

__global__ __launch_bounds__(128) void mean_np_kernel(const float* __restrict__ x,
                                                      float* __restrict__ mean32) {
  int b = blockIdx.x, c = threadIdx.x;
  const float* xb = x + (size_t)b * 2097152;
  float s = 0.0f;
  for (int n = 0; n < 16384; n++) s = __fadd_rn(s, xb[n * 128 + c]);
  mean32[b * 128 + c] = s / 16384.0f;
}

__global__ __launch_bounds__(256) void covnp_kernel(const float* __restrict__ x,
                                                    const float* __restrict__ mean32,
                                                    float* __restrict__ S) {
  int b = blockIdx.x;
  int ti = (blockIdx.y & 3) * 32, tj = (blockIdx.y >> 2) * 32;
  __shared__ float XI[32 * 64], XJ[32 * 64];
  int tid = threadIdx.x;
  int ci = 2 * (tid & 15), dj = 2 * (tid >> 4);
  float a00 = 0.f, a01 = 0.f, a10 = 0.f, a11 = 0.f;
  const float* xb = x + (size_t)b * 2097152;
  const float* mb = mean32 + b * 128;
  for (int n0 = 0; n0 < 16384; n0 += 64) {
    __syncthreads();
    for (int l = tid; l < 2048; l += 256) {
      int n = l >> 5, cc = l & 31;
      XI[cc * 64 + n] = __fsub_rn(xb[(n0 + n) * 128 + ti + cc], mb[ti + cc]);
      XJ[cc * 64 + n] = __fsub_rn(xb[(n0 + n) * 128 + tj + cc], mb[tj + cc]);
    }
    __syncthreads();
    const float* pi0 = &XI[ci * 64];
    const float* pi1 = pi0 + 64;
    const float* pj0 = &XJ[dj * 64];
    const float* pj1 = pj0 + 64;
    for (int n = 0; n < 64; n++) {
      float ai0 = pi0[n], ai1 = pi1[n], bj0 = pj0[n], bj1 = pj1[n];
      a00 = __fadd_rn(a00, __fmul_rn(ai0, bj0));
      a01 = __fadd_rn(a01, __fmul_rn(ai0, bj1));
      a10 = __fadd_rn(a10, __fmul_rn(ai1, bj0));
      a11 = __fadd_rn(a11, __fmul_rn(ai1, bj1));
    }
  }
  float* Sb = S + (size_t)b * 16384;
  int C = ti + ci, D = tj + dj;
  Sb[C * 128 + D] = a00;
  Sb[C * 128 + D + 1] = a01;
  Sb[(C + 1) * 128 + D] = a10;
  Sb[(C + 1) * 128 + D + 1] = a11;
}

__global__ void covfin_kernel(float* __restrict__ A, float* __restrict__ B) {
  int i = blockIdx.x * 256 + threadIdx.x;
  if (i < 262144) {
    float v = A[i] / 16383.0f;
    A[i] = v;
    B[i] = v;
  }
}

// ======================= projection =======================

__global__ __launch_bounds__(256) void proj_kernel(const float* __restrict__ x, const float* __restrict__ V,
                                                   const float* __restrict__ mean32, float* __restrict__ out) {
  __shared__ float Vs[128 * 64];
  __shared__ float Xs[64 * 128];
  __shared__ float ms[128];
  int b = blockIdx.x, t = blockIdx.y, tid = threadIdx.x;
  const float* xb = x + (size_t)b * 2097152 + (size_t)t * 64 * 128;
  const float* vb = V + (size_t)b * 8192;
  if (tid < 128) ms[tid] = mean32[b * 128 + tid];
  __syncthreads();
  for (int i = tid; i < 2048; i += 256) ((float4*)Vs)[i] = ((const float4*)vb)[i];
  for (int i = tid; i < 2048; i += 256) {
    float4 xv = ((const float4*)xb)[i];
    int cv = (i & 31) * 4;
    xv.x -= ms[cv]; xv.y -= ms[cv + 1]; xv.z -= ms[cv + 2]; xv.w -= ms[cv + 3];
    ((float4*)Xs)[i] = xv;
  }
  __syncthreads();
  int kk = tid & 63, w = tid >> 6;
  float acc[16];
#pragma unroll
  for (int r = 0; r < 16; r++) acc[r] = 0.f;
  for (int c4 = 0; c4 < 32; c4++) {
    float v0 = Vs[(c4 * 4 + 0) * 64 + kk];
    float v1 = Vs[(c4 * 4 + 1) * 64 + kk];
    float v2 = Vs[(c4 * 4 + 2) * 64 + kk];
    float v3 = Vs[(c4 * 4 + 3) * 64 + kk];
#pragma unroll
    for (int r = 0; r < 16; r++) {
      const float4 xv = ((const float4*)Xs)[(w * 16 + r) * 32 + c4];
      acc[r] += xv.x * v0 + xv.y * v1 + xv.z * v2 + xv.w * v3;
    }
  }
  float* ob = out + (size_t)b * 1048576 + (size_t)t * 4096;
#pragma unroll
  for (int r = 0; r < 16; r++) ob[(w * 16 + r) * 64 + kk] = acc[r];
}

// ======================= launch =======================

extern "C" void kernel_launch(void* const* d_in, const int* in_sizes, int n_in,
                              void* d_out, int out_size, void* d_ws, size_t ws_size,
                              hipStream_t stream) {
  (void)in_sizes; (void)n_in; (void)out_size; (void)ws_size;
  const float* x = (const float*)d_in[0];
  float* out = (float*)d_out;
  float* T = out + TBASEF;
  float* Af   = T + F_A;
  float* Bf   = T + F_B;
  float* Qf   = T + F_Q;
  float* Q2f  = T + F_Q2;
  float* Smf  = T + F_SM;
  float* vecsf = T + F_VECS;
  float* Vw = (float*)d_ws;
  float* mean32 = Vw + 131072;
  int* dcode = (int*)(mean32 + 2048);

  zeroi_kernel<<<dim3(1), dim3(1), 0, stream>>>(dcode);
  mean_np_kernel<<<dim3(16), dim3(128), 0, stream>>>(x, mean32);
  covnp_kernel<<<dim3(16, 16), dim3(256), 0, stream>>>(x, mean32, Af);
  covfin_kernel<<<dim3(1024), dim3(256), 0, stream>>>(Af, Bf);
  eig_f32_kernel<<<dim3(16), dim3(THREADS), 0, stream>>>(Af, Qf, Q2f, Smf, vecsf, Vw, dcode + 1);
  diag_kernel<<<dim3(16), dim3(128), 0, stream>>>(Bf, Qf, vecsf, Vw, dcode);
  proj_kernel<<<dim3(16, 256), dim3(256), 0, stream>>>(x, Vw, mean32, out);
  emit_kernel<<<dim3(1), dim3(1), 0, stream>>>(dcode, out);
}

// Round 4
// 5546.685 us; speedup vs baseline: 3.4837x; 1.1714x over previous
//
#include <hip/hip_runtime.h>

#define NC 128
#define KTOP 64
#define SMLSIZ 25
#define EPSF 5.9604645e-8f
#define SAFMINF 1.17549435e-38f
#define LDQ 129   // LDS leading dim for Qm: breaks 64-way bank conflicts on column-per-lane access
#define THREADS 512

// out-tail scratch (floats). out = 16,777,216 floats; scratch in top ~5.4MB,
// dead before proj overwrites out.
#define TBASEF 15400960
#define F_A    0         // 262144 f (covnp raw sums -> transformed Householder A)
#define F_B    262144    // 262144 f (finalized cov: eig input + diag)
#define F_Q    524288    // 262144 f (eigvec handoff P2->P3 + diag)
#define F_Q2   786432    // 266240 f (global scratch in merges, sliced by off*128)
#define F_SM   1052672   // 262144 f (secular matrix, TRANSPOSED + off-sliced)
#define F_VECS 1314816   // 18432 f (d / e / tau regions)

// ======================= f32 LAPACK helpers =======================

__device__ __forceinline__ float slapy2f(float x, float y) {
  float xa = fabsf(x), ya = fabsf(y);
  float w = fmaxf(xa, ya), z = fminf(xa, ya);
  if (z == 0.f) return w;
  float r = z / w;
  return w * sqrtf(1.f + r * r);
}

// LAPACK >=3.10 slartg convention (c >= 0, r carries sign of f)
__device__ __forceinline__ void slartgf(float f, float g, float* c, float* s, float* r) {
  if (g == 0.f) { *c = 1.f; *s = 0.f; *r = f; }
  else if (f == 0.f) { *c = 0.f; *s = (g >= 0.f) ? 1.f : -1.f; *r = fabsf(g); }
  else {
    float d_ = sqrtf(f * f + g * g);
    *c = fabsf(f) / d_;
    *r = (f >= 0.f) ? d_ : -d_;
    *s = g / (*r);
  }
}

__device__ void slaev2f(float a, float b, float c,
                        float* rt1, float* rt2, float* cs1, float* sn1) {
  float sm = a + c, df = a - c, adf = fabsf(df), tb = b + b, ab = fabsf(tb);
  float acmx, acmn;
  if (fabsf(a) > fabsf(c)) { acmx = a; acmn = c; } else { acmx = c; acmn = a; }
  float rt;
  if (adf > ab) { float t = ab / adf; rt = adf * sqrtf(1.f + t * t); }
  else if (adf < ab) { float t = adf / ab; rt = ab * sqrtf(1.f + t * t); }
  else rt = ab * sqrtf(2.f);
  int sgn1;
  if (sm < 0.f) { *rt1 = 0.5f * (sm - rt); sgn1 = -1; *rt2 = (acmx / (*rt1)) * acmn - (b / (*rt1)) * b; }
  else if (sm > 0.f) { *rt1 = 0.5f * (sm + rt); sgn1 = 1; *rt2 = (acmx / (*rt1)) * acmn - (b / (*rt1)) * b; }
  else { *rt1 = 0.5f * rt; *rt2 = -0.5f * rt; sgn1 = 1; }
  float cs; int sgn2;
  if (df >= 0.f) { cs = df + rt; sgn2 = 1; } else { cs = df - rt; sgn2 = -1; }
  float acs = fabsf(cs);
  if (acs > ab) {
    float ct = -tb / cs;
    *sn1 = 1.f / sqrtf(1.f + ct * ct);
    *cs1 = ct * (*sn1);
  } else {
    if (ab == 0.f) { *cs1 = 1.f; *sn1 = 0.f; }
    else { float tn = -cs / tb; *cs1 = 1.f / sqrtf(1.f + tn * tn); *sn1 = tn * (*cs1); }
  }
  if (sgn1 == sgn2) { float tn = *cs1; *cs1 = -(*sn1); *sn1 = tn; }
}

// Faithful serial ssteqr('I'), WAVE-PARALLEL: all 64 lanes of one wave call
// this together. Scalar chain computed redundantly (uniform LDS reads -> same
// values in every lane); scalar LDS writes lane0-guarded; O(n^2) Z loops
// lane-strided. Same instruction ordering/values as the serial version.
__device__ void steqr_f32(float* d, float* e, int n, float* zb, int ldz,
                          float* cw, float* sw, int lane) {
  const float eps = EPSF;
  const float eps2 = eps * eps;
  const float safmin = SAFMINF;
  for (int j = 0; j < n; j++)
    for (int i = lane; i < n; i += 64) zb[j * ldz + i] = (i == j) ? 1.f : 0.f;
  if (n <= 1) return;
  int nmaxit = n * 30, jtot = 0;
  int l1 = 1;
  while (true) {
    if (l1 > n) break;
    if (l1 > 1) { if (lane == 0) e[l1 - 2] = 0.f; }
    int m;
    {
      int mm_;
      for (mm_ = l1; mm_ <= n - 1; mm_++) {
        float tst = fabsf(e[mm_ - 1]);
        if (tst == 0.f) break;
        if (tst <= (sqrtf(fabsf(d[mm_ - 1])) * sqrtf(fabsf(d[mm_]))) * eps) {
          if (lane == 0) e[mm_ - 1] = 0.f;
          break;
        }
      }
      m = mm_;
    }
    int l = l1, lsv = l, lend = m, lendsv = lend;
    l1 = m + 1;
    if (lend == l) continue;
    float anorm = 0.f;
    for (int i = l; i <= lend; i++) anorm = fmaxf(anorm, fabsf(d[i - 1]));
    for (int i = l; i <= lend - 1; i++) anorm = fmaxf(anorm, fabsf(e[i - 1]));
    if (anorm == 0.f) continue;
    if (fabsf(d[lend - 1]) < fabsf(d[l - 1])) { lend = lsv; l = lendsv; }
    if (lend > l) {
      // ---- QL ----
      while (true) {
        int m2;
        {
          int i;
          for (i = l; i <= lend - 1; i++) {
            float tst = fabsf(e[i - 1]); tst = tst * tst;
            if (tst <= (eps2 * fabsf(d[i - 1])) * fabsf(d[i]) + safmin) break;
          }
          m2 = i;
        }
        if (m2 < lend) { if (lane == 0) e[m2 - 1] = 0.f; }
        float p = d[l - 1];
        if (m2 == l) { if (lane == 0) d[l - 1] = p; l++; if (l <= lend) continue; else break; }
        if (m2 == l + 1) {
          float rt1, rt2, c_, s_;
          slaev2f(d[l - 1], e[l - 1], d[l], &rt1, &rt2, &c_, &s_);
          for (int i = lane; i < n; i += 64) {
            float t1 = zb[l * ldz + i];
            float t0 = zb[(l - 1) * ldz + i];
            zb[l * ldz + i] = c_ * t1 - s_ * t0;
            zb[(l - 1) * ldz + i] = s_ * t1 + c_ * t0;
          }
          if (lane == 0) { d[l - 1] = rt1; d[l] = rt2; e[l - 1] = 0.f; }
          l += 2; if (l <= lend) continue; else break;
        }
        if (jtot == nmaxit) break;
        jtot++;
        float g = (d[l] - p) / (2.f * e[l - 1]);
        float r = slapy2f(g, 1.f);
        g = d[m2 - 1] - p + e[l - 1] / (g + copysignf(r, g));
        float s_ = 1.f, c_ = 1.f; p = 0.f;
        for (int i = m2 - 1; i >= l; i--) {
          float f = s_ * e[i - 1], b2 = c_ * e[i - 1];
          float cc, ss, rr;
          slartgf(g, f, &cc, &ss, &rr);
          c_ = cc; s_ = ss;
          if (i != m2 - 1) { if (lane == 0) e[i] = rr; }
          g = d[i] - p;
          rr = (d[i - 1] - g) * s_ + 2.f * c_ * b2;
          p = s_ * rr;
          if (lane == 0) d[i] = g + p;
          g = c_ * rr - b2;
          if (lane == 0) { cw[i - l] = c_; sw[i - l] = -s_; }
        }
        int mm2 = m2 - l + 1;
        for (int jj = mm2 - 2; jj >= 0; jj--) {
          float ct_ = cw[jj], st_ = sw[jj];
          int colj = l - 1 + jj;
          for (int i = lane; i < n; i += 64) {
            float t1 = zb[(colj + 1) * ldz + i];
            float t0 = zb[colj * ldz + i];
            zb[(colj + 1) * ldz + i] = ct_ * t1 - st_ * t0;
            zb[colj * ldz + i] = st_ * t1 + ct_ * t0;
          }
        }
        if (lane == 0) { d[l - 1] -= p; e[l - 1] = g; }
      }
    } else {
      // ---- QR ----
      while (true) {
        int m2;
        {
          int i;
          for (i = l; i >= lend + 1; i--) {
            float tst = fabsf(e[i - 2]); tst = tst * tst;
            if (tst <= (eps2 * fabsf(d[i - 1])) * fabsf(d[i - 2]) + safmin) break;
          }
          m2 = i;
        }
        if (m2 > lend) { if (lane == 0) e[m2 - 2] = 0.f; }
        float p = d[l - 1];
        if (m2 == l) { if (lane == 0) d[l - 1] = p; l--; if (l >= lend) continue; else break; }
        if (m2 == l - 1) {
          float rt1, rt2, c_, s_;
          slaev2f(d[l - 2], e[l - 2], d[l - 1], &rt1, &rt2, &c_, &s_);
          for (int i = lane; i < n; i += 64) {
            float t1 = zb[(l - 1) * ldz + i];
            float t0 = zb[(l - 2) * ldz + i];
            zb[(l - 1) * ldz + i] = c_ * t1 - s_ * t0;
            zb[(l - 2) * ldz + i] = s_ * t1 + c_ * t0;
          }
          if (lane == 0) { d[l - 2] = rt1; d[l - 1] = rt2; e[l - 2] = 0.f; }
          l -= 2; if (l >= lend) continue; else break;
        }
        if (jtot == nmaxit) break;
        jtot++;
        float g = (d[l - 2] - p) / (2.f * e[l - 2]);
        float r = slapy2f(g, 1.f);
        g = d[m2 - 1] - p + e[l - 2] / (g + copysignf(r, g));
        float s_ = 1.f, c_ = 1.f; p = 0.f;
        for (int i = m2; i <= l - 1; i++) {
          float f = s_ * e[i - 1], b2 = c_ * e[i - 1];
          float cc, ss, rr;
          slartgf(g, f, &cc, &ss, &rr);
          c_ = cc; s_ = ss;
          if (i != m2) { if (lane == 0) e[i - 2] = rr; }
          g = d[i - 1] - p;
          rr = (d[i] - g) * s_ + 2.f * c_ * b2;
          p = s_ * rr;
          if (lane == 0) d[i - 1] = g + p;
          g = c_ * rr - b2;
          if (lane == 0) { cw[i - m2] = c_; sw[i - m2] = s_; }
        }
        int mm2 = l - m2 + 1;
        for (int jj = 0; jj <= mm2 - 2; jj++) {
          float ct_ = cw[jj], st_ = sw[jj];
          int colj = m2 - 1 + jj;
          for (int i = lane; i < n; i += 64) {
            float t1 = zb[(colj + 1) * ldz + i];
            float t0 = zb[colj * ldz + i];
            zb[(colj + 1) * ldz + i] = ct_ * t1 - st_ * t0;
            zb[colj * ldz + i] = st_ * t1 + ct_ * t0;
          }
        }
        if (lane == 0) { d[l - 1] -= p; e[l - 2] = g; }
      }
    }
  }
  for (int ii = 2; ii <= n; ii++) {
    int i = ii - 1, k = i;
    float p = d[i - 1];
    for (int j = ii; j <= n; j++) if (d[j - 1] < p) { k = j; p = d[j - 1]; }
    if (k != i) {
      if (lane == 0) { d[k - 1] = d[i - 1]; d[i - 1] = p; }
      for (int r = lane; r < n; r += 64) {
        float t5 = zb[(i - 1) * ldz + r];
        zb[(i - 1) * ldz + r] = zb[(k - 1) * ldz + r];
        zb[(k - 1) * ldz + r] = t5;
      }
    }
  }
}

// ======================= f32 D&C merge, MULTI-GROUP (slaed1/2/3 semantics) ===

__device__ void laed1_multi(float* d, float* e, float* Qm, float* Q2b, float* Smb,
                            float* zv, float* dl, float* wv, float* wg, float* pvf,
                            float* dvf, int* srcx, int* dsrc, int* iq,
                            int goff, const int* iwps, int p0, int G,
                            int tid, int* shi, float* shdf,
                            double* sdl, double* spv, int* defcnt) {
  int Tg = THREADS / G;
  int g = tid / Tg, gtid = tid - g * Tg;
  int pg = 2 * (p0 + g);
  int prev = (pg == 0) ? 0 : iwps[pg - 1];
  int off = goff + prev;
  int n = iwps[pg + 1] - prev;
  int n1 = (pg == 0) ? iwps[0] : (n / 2);
  int n2 = n - n1;
  float rho_in = e[off + n1 - 1];
  float* dg = d + off;
  float* zvg = zv + off;  float* dlg = dl + off;  float* wvg = wv + off;
  float* wgg = wg + off;  float* pvfg = pvf + off; float* dvfg = dvf + off;
  int* srcxg = srcx + off; int* dsrcg = dsrc + off; int* iqg = iq + off;
  double* sdlg = sdl + off; double* spvg = spv + off;
  float* Q2g = Q2b + (size_t)off * 128;
  float* Smg = Smb + (size_t)off * 128 + off;

  for (int t = gtid; t < n1; t += Tg) zvg[t] = Qm[(off + t) * LDQ + off + n1 - 1];
  for (int t = gtid; t < n2; t += Tg) zvg[n1 + t] = Qm[(off + n1 + t) * LDQ + off + n1];
  __syncthreads();                                   // B1
  if (gtid == 0) {
    float rho = rho_in;
    if (rho < 0.f) for (int t = n1; t < n; t++) zvg[t] = -zvg[t];
    float tsc = 1.0f / sqrtf(2.0f);
    for (int t = 0; t < n; t++) zvg[t] *= tsc;
    rho = fabsf(2.0f * rho);
    {
      int i = 0, j = n1, p = 0;
      while (i < n1 && j < n) {
        if (dg[i] <= dg[j]) srcxg[p++] = i++; else srcxg[p++] = j++;
      }
      while (i < n1) srcxg[p++] = i++;
      while (j < n) srcxg[p++] = j++;
    }
    int imax = 0, jmax = 0;
    for (int t = 1; t < n; t++) if (fabsf(zvg[t]) > fabsf(zvg[imax])) imax = t;
    for (int t = 1; t < n; t++) if (fabsf(dg[t]) > fabsf(dg[jmax])) jmax = t;
    float tol = 8.0f * EPSF * fmaxf(fabsf(dg[jmax]), fabsf(zvg[imax]));
    int k = 0, nd = 0;
    if (rho * fabsf(zvg[imax]) <= tol) {
      for (int t = 0; t < n; t++) { dsrcg[nd] = srcxg[t]; dvfg[nd] = dg[srcxg[t]]; nd++; }
    } else {
      int pj = -1;
      for (int jj = 0; jj < n; jj++) {
        int nj = srcxg[jj];
        if (rho * fabsf(zvg[nj]) <= tol) {
          dsrcg[nd] = nj; dvfg[nd] = dg[nj]; nd++;
        } else if (pj < 0) {
          pj = nj;
        } else {
          float s_ = zvg[pj], c_ = zvg[nj];
          float tau_ = slapy2f(c_, s_);
          float t3 = dg[nj] - dg[pj];
          c_ /= tau_; s_ = -s_ / tau_;
          if (fabsf(t3 * c_ * s_) <= tol) {
            zvg[nj] = tau_; zvg[pj] = 0.f;
            for (int r = 0; r < n; r++) {
              float x_ = Qm[(off + pj) * LDQ + off + r];
              float y_ = Qm[(off + nj) * LDQ + off + r];
              Qm[(off + pj) * LDQ + off + r] = c_ * x_ + s_ * y_;
              Qm[(off + nj) * LDQ + off + r] = c_ * y_ - s_ * x_;
            }
            float dp = dg[pj], dn = dg[nj];
            dg[nj] = dp * s_ * s_ + dn * c_ * c_;
            dg[pj] = dp * c_ * c_ + dn * s_ * s_;
            dsrcg[nd] = pj; dvfg[nd] = dg[pj]; nd++;
            pj = nj;
          } else {
            dlg[k] = dg[pj]; wvg[k] = zvg[pj]; srcxg[k] = pj; k++;
            pj = nj;
          }
        }
      }
      if (pj >= 0) { dlg[k] = dg[pj]; wvg[k] = zvg[pj]; srcxg[k] = pj; k++; }
    }
    shi[200 + g] = k; shi[208 + g] = nd; shdf[8 + g] = rho;
    if (nd > 0) atomicAdd(defcnt, nd);
  }
  __syncthreads();                                   // B2
  int k = shi[200 + g], nd = shi[208 + g];
  float rho = shdf[8 + g];
  if (k > 1) {
    for (int t = gtid; t < k; t += Tg) {
      sdlg[t] = (double)dlg[t];
      spvg[t] = (double)rho * (double)wvg[t] * (double)wvg[t];
    }
  }
  __syncthreads();                                   // B3
  // secular roots in f64, shifted frame: lambda_j = dl_j + eta
  if (k > 1 && gtid < k) {
    int j = gtid;
    double lo = 0.0, hi;
    if (j == k - 1) {
      double sw2 = 0.0;
      for (int t = 0; t < k; t++) sw2 += spvg[t];
      hi = sw2;
      for (int g2 = 0; g2 < 8; g2++) {
        double f = 1.0;
        for (int t = 0; t < k; t++) f += spvg[t] / ((sdlg[t] - sdlg[j]) - hi);
        if (f >= 0.0) break;
        hi *= 2.0;
      }
    } else hi = sdlg[j + 1] - sdlg[j];
    double gap = hi;
    for (int it = 0; it < 110; it++) {
      double mid = 0.5 * (lo + hi);
      if (!(mid > lo && mid < hi)) break;
      double f = 1.0;
      for (int t = 0; t < k; t++) f += spvg[t] / ((sdlg[t] - sdlg[j]) - mid);
      if (f < 0.0) lo = mid; else hi = mid;
    }
    double eta = 0.5 * (lo + hi);
    if (eta <= 0.0) eta = gap * 1e-30;
    if (j < k - 1 && eta >= gap) eta = gap * (1.0 - 1e-15);
    dg[j] = (float)(sdlg[j] + eta);
    for (int t = 0; t < k; t++)
      Smg[t * 128 + j] = (float)((sdlg[t] - sdlg[j]) - eta);
  }
  __syncthreads();                                   // B4
  // Gu-Eisenstat reweighting (f32, as slaed3)
  if (k > 1 && gtid < k) {
    int i = gtid;
    float acc = Smg[i * 128 + i];
    for (int j = 0; j < k; j++) {
      if (j == i) continue;
      acc *= Smg[i * 128 + j] / (dlg[i] - dlg[j]);
    }
    wgg[i] = copysignf(sqrtf(fmaxf(-acc, 0.f)), wvg[i]);
  }
  __syncthreads();                                   // B5
  // secular vectors + positive normalization (thread j, exact order)
  if (k > 1 && gtid < k) {
    int j = gtid;
    float nrm2 = 0.f;
    for (int i = 0; i < k; i++) {
      float u = wgg[i] / Smg[i * 128 + j];
      Smg[i * 128 + j] = u;
      nrm2 += u * u;
    }
    float nrm = sqrtf(nrm2);
    for (int i = 0; i < k; i++) Smg[i * 128 + j] /= nrm;
  }
  __syncthreads();                                   // B6
  if (k > 1) {
    // gather Q2g[j][r] = sum_i Qm[off+srcxg[i]][off+r] * Smg[i][j]
    int j = gtid & 127, rg = gtid >> 7;
    int RG = Tg >> 7; if (RG < 1) RG = 1;
    if (j < k) {
      int chunk = (n + RG - 1) / RG;
      int rbeg = rg * chunk, rend = rbeg + chunk;
      if (rend > n) rend = n;
      int r0 = rbeg;
      for (; r0 + 8 <= rend; r0 += 8) {
        float a0 = 0.f, a1 = 0.f, a2 = 0.f, a3 = 0.f;
        float a4 = 0.f, a5 = 0.f, a6 = 0.f, a7 = 0.f;
        for (int i = 0; i < k; i++) {
          float s = Smg[i * 128 + j];
          const float* q = &Qm[(off + srcxg[i]) * LDQ + off + r0];
          a0 += q[0] * s; a1 += q[1] * s; a2 += q[2] * s; a3 += q[3] * s;
          a4 += q[4] * s; a5 += q[5] * s; a6 += q[6] * s; a7 += q[7] * s;
        }
        float* o = &Q2g[j * 128 + r0];
        o[0] = a0; o[1] = a1; o[2] = a2; o[3] = a3;
        o[4] = a4; o[5] = a5; o[6] = a6; o[7] = a7;
      }
      for (; r0 < rend; r0++) {
        float a = 0.f;
        for (int i = 0; i < k; i++)
          a += Qm[(off + srcxg[i]) * LDQ + off + r0] * Smg[i * 128 + j];
        Q2g[j * 128 + r0] = a;
      }
    }
  } else if (k == 1 && gtid == 0) {
    zvg[0] = dlg[0] + rho * (wvg[0] * wvg[0]);
    for (int r = 0; r < n; r++) Q2g[r] = Qm[(off + srcxg[0]) * LDQ + off + r];
  }
  __syncthreads();                                   // B7
  if (k > 1 && gtid < k) zvg[gtid] = dg[gtid];
  __syncthreads();                                   // B8
  for (int t2 = gtid; t2 < nd; t2 += Tg)
    for (int r = 0; r < n; r++) Q2g[(k + t2) * 128 + r] = Qm[(off + dsrcg[t2]) * LDQ + off + r];
  for (int j = gtid; j < n; j += Tg) pvfg[j] = (j < k) ? zvg[j] : dvfg[j - k];
  __syncthreads();                                   // B9
  // ascending physical sort: dense key mirror -> identical decisions.
  if (gtid == 0) {
    float* ks = wgg;  // dead here
    for (int i = 0; i < n; i++) { iqg[i] = i; ks[i] = pvfg[i]; }
    for (int i = 0; i < n - 1; i++) {
      int kb = i;
      float vkb = ks[i];
      for (int j = i + 1; j < n; j++) {
        float vj = ks[j];
        if (vj < vkb) { kb = j; vkb = vj; }
      }
      if (kb != i) {
        int tt = iqg[i]; iqg[i] = iqg[kb]; iqg[kb] = tt;
        float tf = ks[i]; ks[i] = ks[kb]; ks[kb] = tf;
      }
    }
  }
  __syncthreads();                                   // B10
  // permuted writeback, r-chunked (elementwise, exact)
  {
    int j = gtid & 127, rg = gtid >> 7;
    int RG = Tg >> 7; if (RG < 1) RG = 1;
    if (j < n) {
      int s2 = iqg[j];
      if (rg == 0) dg[j] = pvfg[s2];
      int chunk = (n + RG - 1) / RG;
      int rbeg = rg * chunk, rend = rbeg + chunk;
      if (rend > n) rend = n;
      for (int r = rbeg; r < rend; r++) Qm[(off + j) * LDQ + off + r] = Q2g[s2 * 128 + r];
    }
  }
  __syncthreads();                                   // B11
}

__device__ void laed0_f32(float* d, float* e, float* Qm, float* Q2, float* Sm,
                          float* zv, float* dl, float* wv, float* wg, float* pvf,
                          float* dvf, int* srcx, int* dsrc, int* iq, int* iwps,
                          float* sscr,
                          int goff, int m, int tid, int* shi, float* shdf,
                          double* sdl, double* spv, int* defcnt) {
  if (tid == 0) {
    iwps[0] = m; int sp = 1;
    while (iwps[sp - 1] > SMLSIZ) {
      for (int j = sp - 1; j >= 0; j--) { iwps[2 * j + 1] = (iwps[j] + 1) / 2; iwps[2 * j] = iwps[j] / 2; }
      sp *= 2;
    }
    for (int j = 1; j < sp; j++) iwps[j] += iwps[j - 1];
    shi[134] = sp;
    for (int i = 0; i < sp - 1; i++) {
      int bnd = goff + iwps[i];
      d[bnd - 1] -= fabsf(e[bnd - 1]);
      d[bnd] -= fabsf(e[bnd - 1]);
    }
  }
  __syncthreads();
  int subpbs = shi[134];
  // leaves: wave-parallel steqr, one leaf per wave
  {
    int lw = tid >> 6;
    if (lw < subpbs) {
      int boff = goff + (lw == 0 ? 0 : iwps[lw - 1]);
      int bm = iwps[lw] - (lw == 0 ? 0 : iwps[lw - 1]);
      steqr_f32(d + boff, e + boff, bm, Qm + boff * LDQ + boff, LDQ,
                sscr + lw * 64, sscr + lw * 64 + 32, tid & 63);
    }
  }
  __syncthreads();
  int cur = subpbs;
  while (cur > 1) {
    int nm = cur >> 1;
    for (int p0 = 0; p0 < nm; ) {
      int G = (nm - p0 >= 4) ? 4 : ((nm - p0 >= 2) ? 2 : 1);
      laed1_multi(d, e, Qm, Q2, Sm, zv, dl, wv, wg, pvf, dvf, srcx, dsrc, iq,
                  goff, iwps, p0, G, tid, shi, shdf, sdl, spv, defcnt);
      p0 += G;
    }
    if (tid == 0) for (int t = 0; 2 * t + 1 < cur; t++) iwps[t] = iwps[2 * t + 1];
    __syncthreads();
    cur >>= 1;
  }
}

// ======================= eig P1: ssytd2 tridiagonalization =======================
// Reads finalized cov (Bf), writes transformed Householder A (Af) + d/e/tau.

__global__ __launch_bounds__(THREADS) void eig_p1_kernel(const float* __restrict__ covB,
                                                         float* __restrict__ Aout,
                                                         float* __restrict__ vecs) {
  int b = blockIdx.x, tid = threadIdx.x;
  const float* Cg = covB + (size_t)b * 16384;
  float* Ag = Aout + (size_t)b * 16384;
  __shared__ float As[16384];
  __shared__ float sh_e[128], sh_tau[128], sh_pvf[128];
  __shared__ float redf[128];
  __shared__ float shdf[4];
  float* A = As; float* e = sh_e; float* tauv = sh_tau; float* pvf = sh_pvf;

  for (int idx = tid; idx < 16384; idx += THREADS) As[idx] = Cg[idx];
  if (tid < 128) { sh_e[tid] = 0.f; sh_tau[tid] = 0.f; }
  __syncthreads();

  for (int i1 = 1; i1 <= NC - 1; i1++) {
    int ii = i1 - 1;
    int mlen = NC - i1;
    float ps = 0.f;
    if (tid < 128) {
      for (int t = tid; t < mlen - 1; t += 128) {
        float v = A[ii * 128 + ii + 2 + t];
        ps += v * v;
      }
      redf[tid] = ps;
    }
    __syncthreads();                               // B1
    if (tid < 64) {
      float a = redf[tid] + redf[tid + 64];
      a += __shfl_xor(a, 32); a += __shfl_xor(a, 16); a += __shfl_xor(a, 8);
      a += __shfl_xor(a, 4);  a += __shfl_xor(a, 2);  a += __shfl_xor(a, 1);
      if (tid == 0) {
        float xnorm = sqrtf(a);
        float alpha = A[ii * 128 + ii + 1];
        float taui, ei, scl;
        if (xnorm == 0.f) { taui = 0.f; ei = alpha; scl = 0.f; }
        else {
          float beta = -copysignf(slapy2f(alpha, xnorm), alpha);
          taui = (beta - alpha) / beta;
          scl = 1.f / (alpha - beta);
          ei = beta;
        }
        e[ii] = ei; tauv[ii] = taui; shdf[2] = scl;
      }
    }
    __syncthreads();                               // B2
    float taui = tauv[ii];
    if (taui != 0.f) {
      float scl = shdf[2];
      for (int t = tid; t < mlen - 1; t += 128) A[ii * 128 + ii + 2 + t] *= scl;
      __syncthreads();                             // B3
      for (int r = tid; r < mlen; r += 128) {
        float acc = 0.f;
        int row = ii + 1 + r;
        acc += A[(ii + 1) * 128 + row];            // s=0 term, v0 == 1
        for (int s = 1; s < mlen; s++) acc += A[(ii + 1 + s) * 128 + row] * A[ii * 128 + ii + 1 + s];
        pvf[r] = taui * acc;
      }
      __syncthreads();                             // B4
      if (tid < 128) {
        float pd = 0.f;
        for (int t = tid; t < mlen; t += 128) {
          float vt = (t == 0) ? 1.f : A[ii * 128 + ii + 1 + t];
          pd += pvf[t] * vt;
        }
        redf[tid] = pd;
      }
      __syncthreads();                             // B5
      if (tid < 64) {
        float a = redf[tid] + redf[tid + 64];
        a += __shfl_xor(a, 32); a += __shfl_xor(a, 16); a += __shfl_xor(a, 8);
        a += __shfl_xor(a, 4);  a += __shfl_xor(a, 2);  a += __shfl_xor(a, 1);
        if (tid == 0) shdf[3] = -0.5f * taui * a;
      }
      __syncthreads();                             // B6
      float alpha2 = shdf[3];
      for (int t = tid; t < mlen; t += 128) {
        float vt = (t == 0) ? 1.f : A[ii * 128 + ii + 1 + t];
        pvf[t] += alpha2 * vt;
      }
      __syncthreads();                             // B7
      if ((tid & 127) < mlen) {
        int r = tid & 127, g = tid >> 7;
        int chunk = (mlen + 3) >> 2;
        int cb = g * chunk, ce = cb + chunk;
        if (ce > mlen) ce = mlen;
        float vr = (r == 0) ? 1.f : A[ii * 128 + ii + 1 + r];
        float pr = pvf[r];
        for (int c2 = cb; c2 < ce; c2++) {
          float vc = (c2 == 0) ? 1.f : A[ii * 128 + ii + 1 + c2];
          A[(ii + 1 + c2) * 128 + (ii + 1 + r)] -= vr * pvf[c2] + pr * vc;
        }
      }
      __syncthreads();                             // B8
    }
  }
  for (int idx = tid; idx < 16384; idx += THREADS) Ag[idx] = As[idx];
  if (tid < 128) {
    vecs[b * 128 + tid] = As[tid * 128 + tid];      // d = diag(A)
    vecs[2048 + b * 128 + tid] = sh_e[tid];
    vecs[4096 + b * 128 + tid] = sh_tau[tid];
  }
}

// ======================= eig P2: sstedc('I') D&C =======================

__global__ __launch_bounds__(THREADS) void eig_p2_kernel(float* __restrict__ Qw,
                                                         float* Q2w, float* Sw,
                                                         float* vecs, int* defcnt) {
  int b = blockIdx.x, tid = threadIdx.x;
  float* Qg = Qw + (size_t)b * 16384;
  float* Q2 = Q2w + (size_t)b * 16640;
  float* Sm = Sw + (size_t)b * 16384;

  __shared__ float Qs[128 * LDQ];
  __shared__ float sh_d[128], sh_e[128], sh_zv[128], sh_dl[128];
  __shared__ float sh_wv[128], sh_wg[128], sh_pvf[128], sh_dvf[128];
  __shared__ int sh_iq[128], sh_srcx[128], sh_dsrc[128];
  __shared__ int iwps[64];
  __shared__ float sscr[512];
  __shared__ float shdf[16];
  __shared__ int shi[280];
  __shared__ double sdl[128];
  __shared__ double spv[128];

  float* Qm = Qs;
  float* d = sh_d; float* e = sh_e; float* zv = sh_zv;
  float* dl = sh_dl; float* wv = sh_wv; float* wg = sh_wg; float* pvf = sh_pvf;
  float* dvf = sh_dvf;
  int* iq = sh_iq; int* srcx = sh_srcx; int* dsrc = sh_dsrc;

  if (tid < 128) {
    sh_d[tid] = vecs[b * 128 + tid];
    sh_e[tid] = vecs[2048 + b * 128 + tid];
  }
  for (int idx = tid; idx < 16384; idx += THREADS) {
    int c = idx >> 7, r = idx & 127;
    Qs[c * LDQ + r] = (c == r) ? 1.f : 0.f;
  }
  __syncthreads();
  if (tid == 0) {
    int ns = 0, start = 0;
    while (start < NC) {
      int fin = start;
      while (fin < NC - 1) {
        float tiny = EPSF * sqrtf(fabsf(d[fin])) * sqrtf(fabsf(d[fin + 1]));
        if (fabsf(e[fin]) > tiny) fin++;
        else break;
      }
      shi[2 + 2 * ns] = start; shi[3 + 2 * ns] = fin - start + 1; ns++;
      start = fin + 1;
    }
    shi[0] = ns;
  }
  __syncthreads();
  int nsplit = shi[0];
  for (int sb = 0; sb < nsplit; sb++) {
    int goff = shi[2 + 2 * sb], m = shi[3 + 2 * sb];
    if (m == 1) continue;
    if (m <= SMLSIZ) {
      if (tid < 64) steqr_f32(d + goff, e + goff, m, Qm + goff * LDQ + goff, LDQ,
                              sscr, sscr + 32, tid);
      __syncthreads();
    } else {
      if (tid == 0) {
        float mx = 0.f;
        for (int i = 0; i < m; i++) mx = fmaxf(mx, fabsf(d[goff + i]));
        for (int i = 0; i < m - 1; i++) mx = fmaxf(mx, fabsf(e[goff + i]));
        shdf[0] = mx;
      }
      __syncthreads();
      float onrm = shdf[0];
      if (onrm != 0.f) {
        float mul = 1.f / onrm;
        for (int t = tid; t < m; t += 128) d[goff + t] *= mul;
        for (int t = tid; t < m - 1; t += 128) e[goff + t] *= mul;
        __syncthreads();
        laed0_f32(d, e, Qm, Q2, Sm, zv, dl, wv, wg, pvf, dvf, srcx, dsrc, iq,
                  iwps, sscr, goff, m, tid, shi, shdf, sdl, spv, defcnt);
        for (int t = tid; t < m; t += 128) d[goff + t] *= onrm;
        __syncthreads();
      }
    }
  }
  if (tid == 0) {
    for (int i = 0; i < NC; i++) shi[140 + i] = i;
    for (int ii2 = 2; ii2 <= NC; ii2++) {
      int i = ii2 - 1, kk2 = i;
      float p = d[i - 1];
      for (int j = ii2; j <= NC; j++) if (d[j - 1] < p) { kk2 = j; p = d[j - 1]; }
      if (kk2 != i) {
        d[kk2 - 1] = d[i - 1]; d[i - 1] = p;
        int tmp = shi[140 + i - 1]; shi[140 + i - 1] = shi[140 + kk2 - 1]; shi[140 + kk2 - 1] = tmp;
      }
    }
  }
  __syncthreads();
  {
    int j = tid & 127, g = tid >> 7;
    int rbeg = g * 32, rend = rbeg + 32;
    int src = shi[140 + j];
    for (int r = rbeg; r < rend; r++) Q2[j * 128 + r] = Qm[src * LDQ + r];
  }
  __syncthreads();
  {
    int j = tid & 127, g = tid >> 7;
    int rbeg = g * 32, rend = rbeg + 32;
    for (int r = rbeg; r < rend; r++) Qm[j * LDQ + r] = Q2[j * 128 + r];
  }
  __syncthreads();
  for (int idx = tid; idx < 16384; idx += THREADS) {
    int c = idx >> 7, r = idx & 127;
    Qg[idx] = Qs[c * LDQ + r];
  }
  if (tid < 128) vecs[b * 128 + tid] = d[tid];
}

// ======================= eig P3: sormtr + top-64 extract =======================

__global__ __launch_bounds__(THREADS) void eig_p3_kernel(const float* __restrict__ Ain,
                                                         const float* __restrict__ vecs,
                                                         float* __restrict__ Qw,
                                                         float* __restrict__ Vw) {
  int b = blockIdx.x, tid = threadIdx.x;
  const float* Ag = Ain + (size_t)b * 16384;
  float* Qg = Qw + (size_t)b * 16384;
  __shared__ float As[16384];
  __shared__ float Qs[128 * LDQ];
  __shared__ float sh_tau[128];
  float* A = As; float* Qm = Qs; float* tauv = sh_tau;

  for (int idx = tid; idx < 16384; idx += THREADS) As[idx] = Ag[idx];
  for (int idx = tid; idx < 16384; idx += THREADS) {
    int c = idx >> 7, r = idx & 127;
    Qs[c * LDQ + r] = Qg[idx];
  }
  if (tid < 128) sh_tau[tid] = vecs[4096 + b * 128 + tid];
  __syncthreads();

  for (int j1 = NC - 1; j1 >= 1; j1--) {
    int jj = j1 - 1;
    float tj = tauv[jj];
    if (tj != 0.f) {
      if (tid < NC) {
        int col = tid;
        float s = Qm[col * LDQ + jj + 1];
        for (int r = jj + 2; r < NC; r++) s += A[jj * 128 + r] * Qm[col * LDQ + r];
        s *= tj;
        Qm[col * LDQ + jj + 1] -= s;
        for (int r = jj + 2; r < NC; r++) Qm[col * LDQ + r] -= s * A[jj * 128 + r];
      }
    }
  }
  __syncthreads();

  for (int idx = tid; idx < NC * KTOP; idx += THREADS) {
    int c2 = idx / KTOP, kk = idx % KTOP;
    Vw[(size_t)b * (NC * KTOP) + idx] = Qm[(127 - kk) * LDQ + c2];
  }
  for (int idx = tid; idx < 16384; idx += THREADS) {
    int c = idx >> 7, r = idx & 127;
    Qg[idx] = Qs[c * LDQ + r];
  }
}

// ======================= diagnostics =======================

__global__ void zeroi_kernel(int* p) { p[0] = 0; p[1] = 0; }

__global__ __launch_bounds__(128) void diag_kernel(const float* __restrict__ covB,
                                                   const float* __restrict__ Qw,
                                                   const float* __restrict__ vecs,
                                                   const float* __restrict__ Vw, int* dcode) {
  int b = blockIdx.x, tid = threadIdx.x;
  const float* C = covB + (size_t)b * 16384;
  const float* Qm = Qw + (size_t)b * 16384;
  const float* d = vecs + b * 128;
  int flags = 0;
  double rmax = 0.0;
  for (int k = 64; k < 128; k++) {
    double lam = (double)d[k];
    double acc = 0.0;
    for (int j = 0; j < 128; j++) acc += (double)C[j * 128 + tid] * (double)Qm[k * 128 + j];
    acc -= lam * (double)Qm[k * 128 + tid];
    rmax = fmax(rmax, fabs(acc));
  }
  if (rmax > 1e-3) flags |= 1;
  double omax = 0.0;
  for (int p = tid; p < 64 * 64; p += 128) {
    int i = 64 + p / 64, j = 64 + p % 64;
    if (j < i) continue;
    double s = 0.0;
    for (int r = 0; r < 128; r++) s += (double)Qm[i * 128 + r] * (double)Qm[j * 128 + r];
    if (i == j) s -= 1.0;
    omax = fmax(omax, fabs(s));
  }
  if (omax > 1e-3) flags |= 2;
  if (tid < 127 && d[tid + 1] < d[tid] - 1e-5f) flags |= 4;
  for (int idx = tid; idx < 8192; idx += 128) {
    int c2 = idx / 64, kk = idx % 64;
    if (Vw[(size_t)b * 8192 + idx] != Qm[(127 - kk) * 128 + c2]) flags |= 8;
  }
  if (tid == 0) {
    for (int k = 64; k < 128; k++) if (!(d[k] > 0.2f && d[k] < 5.0f)) flags |= 16;
    float s = 0.f;
    for (int c = 0; c < 128; c++) { float v = Vw[(size_t)b * 8192 + c * 64]; s += v * v; }
    if (fabsf(s - 1.f) > 1e-2f) flags |= 32;
  }
  if (flags) atomicOr(dcode, flags);
}

__global__ void emit_kernel(const int* dcode, float* out) {
  int f = dcode[0];
  if (f) {
    int code = 1000;
    if (f & 1) code += 400;
    if (f & 2) code += 200;
    if (f & 4) code += 100;
    if (f & 8) code += 40;
    if (f & 16) code += 20;
    if (f & 32) code += 10;
    int nd = dcode[1]; if (nd > 9) nd = 9;
    code += nd;
    out[0] = (float)code;
  }
}

// ======================= numpy-f32-mirror mean / cov =======================

__global__ __launch_bounds__(128) void mean_np_kernel(const float* __restrict__ x,
                                                      float* __restrict__ mean32) {
  int b = blockIdx.x, c = threadIdx.x;
  const float* xb = x + (size_t)b * 2097152;
  float s = 0.0f;
#pragma unroll 16
  for (int n = 0; n < 16384; n++) s = __fadd_rn(s, xb[n * 128 + c]);
  mean32[b * 128 + c] = s / 16384.0f;
}

// Upper tile-pairs only (tj >= ti); lower mirrored in covfin (bit-exact by
// commutativity + same n-order). LDS stride 66: banks (4k+n)%32 -> <=2-way
// (free), float2-aligned for even rows AND odd rows (66*odd + even n ≡ 0 mod 2).
__global__ __launch_bounds__(256) void covnp_kernel(const float* __restrict__ x,
                                                    const float* __restrict__ mean32,
                                                    float* __restrict__ S) {
  int b = blockIdx.x;
  int p = blockIdx.y;
  int ti4, tj4;
  if (p < 4) { ti4 = 0; tj4 = p; }
  else if (p < 7) { ti4 = 1; tj4 = p - 3; }
  else if (p < 9) { ti4 = 2; tj4 = p - 5; }
  else { ti4 = 3; tj4 = 3; }
  int ti = ti4 * 32, tj = tj4 * 32;
  __shared__ float XI[32 * 66], XJ[32 * 66];
  int tid = threadIdx.x;
  int ci = 2 * (tid & 15), dj = 2 * (tid >> 4);
  float a00 = 0.f, a01 = 0.f, a10 = 0.f, a11 = 0.f;
  const float* xb = x + (size_t)b * 2097152;
  const float* mb = mean32 + b * 128;
  for (int n0 = 0; n0 < 16384; n0 += 64) {
    __syncthreads();
    for (int l = tid; l < 2048; l += 256) {
      int n = l >> 5, cc = l & 31;
      XI[cc * 66 + n] = __fsub_rn(xb[(n0 + n) * 128 + ti + cc], mb[ti + cc]);
      XJ[cc * 66 + n] = __fsub_rn(xb[(n0 + n) * 128 + tj + cc], mb[tj + cc]);
    }
    __syncthreads();
    const float2* pi0 = (const float2*)&XI[ci * 66];
    const float2* pi1 = (const float2*)&XI[(ci + 1) * 66];
    const float2* pj0 = (const float2*)&XJ[dj * 66];
    const float2* pj1 = (const float2*)&XJ[(dj + 1) * 66];
    for (int n2 = 0; n2 < 32; n2++) {
      float2 xi0 = pi0[n2], xi1 = pi1[n2], xj0 = pj0[n2], xj1 = pj1[n2];
      a00 = __fadd_rn(a00, __fmul_rn(xi0.x, xj0.x));
      a01 = __fadd_rn(a01, __fmul_rn(xi0.x, xj1.x));
      a10 = __fadd_rn(a10, __fmul_rn(xi1.x, xj0.x));
      a11 = __fadd_rn(a11, __fmul_rn(xi1.x, xj1.x));
      a00 = __fadd_rn(a00, __fmul_rn(xi0.y, xj0.y));
      a01 = __fadd_rn(a01, __fmul_rn(xi0.y, xj1.y));
      a10 = __fadd_rn(a10, __fmul_rn(xi1.y, xj0.y));
      a11 = __fadd_rn(a11, __fmul_rn(xi1.y, xj1.y));
    }
  }
  float* Sb = S + (size_t)b * 16384;
  int C = ti + ci, D = tj + dj;
  Sb[C * 128 + D] = a00;
  Sb[C * 128 + D + 1] = a01;
  Sb[(C + 1) * 128 + D] = a10;
  Sb[(C + 1) * 128 + D + 1] = a11;
}

// covfin: reads raw sums (A, upper tiles valid), writes finalized cov to B only
// (race-free); lower tiles mirrored from upper (bit-exact).
__global__ void covfin_kernel(const float* __restrict__ A, float* __restrict__ B) {
  int i = blockIdx.x * 256 + threadIdx.x;
  if (i < 262144) {
    int w = i & 16383;
    int base = i - w;
    int r = w >> 7, c = w & 127;
    int src = ((r >> 5) > (c >> 5)) ? (base + c * 128 + r) : i;
    B[i] = A[src] / 16383.0f;
  }
}

// ======================= projection =======================

__global__ __launch_bounds__(256) void proj_kernel(const float* __restrict__ x, const float* __restrict__ V,
                                                   const float* __restrict__ mean32, float* __restrict__ out) {
  __shared__ float Vs[128 * 64];
  __shared__ float Xs[64 * 128];
  __shared__ float ms[128];
  int b = blockIdx.x, t = blockIdx.y, tid = threadIdx.x;
  const float* xb = x + (size_t)b * 2097152 + (size_t)t * 64 * 128;
  const float* vb = V + (size_t)b * 8192;
  if (tid < 128) ms[tid] = mean32[b * 128 + tid];
  __syncthreads();
  for (int i = tid; i < 2048; i += 256) ((float4*)Vs)[i] = ((const float4*)vb)[i];
  for (int i = tid; i < 2048; i += 256) {
    float4 xv = ((const float4*)xb)[i];
    int cv = (i & 31) * 4;
    xv.x -= ms[cv]; xv.y -= ms[cv + 1]; xv.z -= ms[cv + 2]; xv.w -= ms[cv + 3];
    ((float4*)Xs)[i] = xv;
  }
  __syncthreads();
  int kk = tid & 63, w = tid >> 6;
  float acc[16];
#pragma unroll
  for (int r = 0; r < 16; r++) acc[r] = 0.f;
  for (int c4 = 0; c4 < 32; c4++) {
    float v0 = Vs[(c4 * 4 + 0) * 64 + kk];
    float v1 = Vs[(c4 * 4 + 1) * 64 + kk];
    float v2 = Vs[(c4 * 4 + 2) * 64 + kk];
    float v3 = Vs[(c4 * 4 + 3) * 64 + kk];
#pragma unroll
    for (int r = 0; r < 16; r++) {
      const float4 xv = ((const float4*)Xs)[(w * 16 + r) * 32 + c4];
      acc[r] += xv.x * v0 + xv.y * v1 + xv.z * v2 + xv.w * v3;
    }
  }
  float* ob = out + (size_t)b * 1048576 + (size_t)t * 4096;
#pragma unroll
  for (int r = 0; r < 16; r++) ob[(w * 16 + r) * 64 + kk] = acc[r];
}

// ======================= launch =======================

extern "C" void kernel_launch(void* const* d_in, const int* in_sizes, int n_in,
                              void* d_out, int out_size, void* d_ws, size_t ws_size,
                              hipStream_t stream) {
  (void)in_sizes; (void)n_in; (void)out_size; (void)ws_size;
  const float* x = (const float*)d_in[0];
  float* out = (float*)d_out;
  float* T = out + TBASEF;
  float* Af   = T + F_A;
  float* Bf   = T + F_B;
  float* Qf   = T + F_Q;
  float* Q2f  = T + F_Q2;
  float* Smf  = T + F_SM;
  float* vecsf = T + F_VECS;
  float* Vw = (float*)d_ws;
  float* mean32 = Vw + 131072;
  int* dcode = (int*)(mean32 + 2048);

  zeroi_kernel<<<dim3(1), dim3(1), 0, stream>>>(dcode);
  mean_np_kernel<<<dim3(16), dim3(128), 0, stream>>>(x, mean32);
  covnp_kernel<<<dim3(16, 10), dim3(256), 0, stream>>>(x, mean32, Af);
  covfin_kernel<<<dim3(1024), dim3(256), 0, stream>>>(Af, Bf);
  eig_p1_kernel<<<dim3(16), dim3(THREADS), 0, stream>>>(Bf, Af, vecsf);
  eig_p2_kernel<<<dim3(16), dim3(THREADS), 0, stream>>>(Qf, Q2f, Smf, vecsf, dcode + 1);
  eig_p3_kernel<<<dim3(16), dim3(THREADS), 0, stream>>>(Af, vecsf, Qf, Vw);
  diag_kernel<<<dim3(16), dim3(128), 0, stream>>>(Bf, Qf, vecsf, Vw, dcode);
  proj_kernel<<<dim3(16, 256), dim3(256), 0, stream>>>(x, Vw, mean32, out);
  emit_kernel<<<dim3(1), dim3(1), 0, stream>>>(dcode, out);
}

// Round 5
// 4776.490 us; speedup vs baseline: 4.0454x; 1.1612x over previous
//
#include <hip/hip_runtime.h>

#define NC 128
#define KTOP 64
#define SMLSIZ 25
#define EPSF 5.9604645e-8f
#define SAFMINF 1.17549435e-38f
#define LDQ 129   // LDS leading dim for Qm: breaks 64-way bank conflicts on column-per-lane access
#define THREADS 512

// out-tail scratch (floats). out = 16,777,216 floats; scratch in top ~5.4MB,
// dead before proj overwrites out.
#define TBASEF 15400960
#define F_A    0         // 262144 f (covnp raw sums -> transformed Householder A)
#define F_B    262144    // 262144 f (finalized cov: eig input + diag)
#define F_Q    524288    // 262144 f (eigvec handoff P2->P3 + diag)
#define F_Q2   786432    // 266240 f (global scratch in merges, sliced by off*128)
#define F_SM   1052672   // 262144 f (secular matrix, TRANSPOSED + off-sliced)
#define F_VECS 1314816   // 18432 f (d / e / tau regions)

// ======================= f32 LAPACK helpers =======================

__device__ __forceinline__ float slapy2f(float x, float y) {
  float xa = fabsf(x), ya = fabsf(y);
  float w = fmaxf(xa, ya), z = fminf(xa, ya);
  if (z == 0.f) return w;
  float r = z / w;
  return w * sqrtf(1.f + r * r);
}

// LAPACK >=3.10 slartg convention (c >= 0, r carries sign of f)
__device__ __forceinline__ void slartgf(float f, float g, float* c, float* s, float* r) {
  if (g == 0.f) { *c = 1.f; *s = 0.f; *r = f; }
  else if (f == 0.f) { *c = 0.f; *s = (g >= 0.f) ? 1.f : -1.f; *r = fabsf(g); }
  else {
    float d_ = sqrtf(f * f + g * g);
    *c = fabsf(f) / d_;
    *r = (f >= 0.f) ? d_ : -d_;
    *s = g / (*r);
  }
}

__device__ void slaev2f(float a, float b, float c,
                        float* rt1, float* rt2, float* cs1, float* sn1) {
  float sm = a + c, df = a - c, adf = fabsf(df), tb = b + b, ab = fabsf(tb);
  float acmx, acmn;
  if (fabsf(a) > fabsf(c)) { acmx = a; acmn = c; } else { acmx = c; acmn = a; }
  float rt;
  if (adf > ab) { float t = ab / adf; rt = adf * sqrtf(1.f + t * t); }
  else if (adf < ab) { float t = adf / ab; rt = ab * sqrtf(1.f + t * t); }
  else rt = ab * sqrtf(2.f);
  int sgn1;
  if (sm < 0.f) { *rt1 = 0.5f * (sm - rt); sgn1 = -1; *rt2 = (acmx / (*rt1)) * acmn - (b / (*rt1)) * b; }
  else if (sm > 0.f) { *rt1 = 0.5f * (sm + rt); sgn1 = 1; *rt2 = (acmx / (*rt1)) * acmn - (b / (*rt1)) * b; }
  else { *rt1 = 0.5f * rt; *rt2 = -0.5f * rt; sgn1 = 1; }
  float cs; int sgn2;
  if (df >= 0.f) { cs = df + rt; sgn2 = 1; } else { cs = df - rt; sgn2 = -1; }
  float acs = fabsf(cs);
  if (acs > ab) {
    float ct = -tb / cs;
    *sn1 = 1.f / sqrtf(1.f + ct * ct);
    *cs1 = ct * (*sn1);
  } else {
    if (ab == 0.f) { *cs1 = 1.f; *sn1 = 0.f; }
    else { float tn = -cs / tb; *cs1 = 1.f / sqrtf(1.f + tn * tn); *sn1 = tn * (*cs1); }
  }
  if (sgn1 == sgn2) { float tn = *cs1; *cs1 = -(*sn1); *sn1 = tn; }
}

// Faithful serial ssteqr('I'), WAVE-PARALLEL + REGISTER-RESIDENT d/e/cw/sw:
// lane l holds d[l], e[l]; scalar chain computed redundantly in uniform flow
// using __shfl broadcasts (wave-uniform index -> v_readlane, ~cycles instead
// of ~120-cy LDS round trips). Arithmetic order identical -> bit-exact.
// n <= 25 < 64 lanes. Z rows in LDS, lane-strided (parallel).
#define SDD(i) __shfl(dr, (i))
#define SEE(i) __shfl(er, (i))
__device__ void steqr_reg(float* d, float* e, int n, float* zb, int ldz, int lane) {
  const float eps = EPSF;
  const float eps2 = eps * eps;
  const float safmin = SAFMINF;
  for (int j = 0; j < n; j++)
    for (int i = lane; i < n; i += 64) zb[j * ldz + i] = (i == j) ? 1.f : 0.f;
  if (n <= 1) return;
  float dr = (lane < n) ? d[lane] : 0.f;
  float er = (lane < n - 1) ? e[lane] : 0.f;
  float cwr = 0.f, swr = 0.f;
  int nmaxit = n * 30, jtot = 0;
  int l1 = 1;
  while (true) {
    if (l1 > n) break;
    if (l1 > 1) er = (lane == l1 - 2) ? 0.f : er;
    int m;
    {
      int mm_;
      for (mm_ = l1; mm_ <= n - 1; mm_++) {
        float tst = fabsf(SEE(mm_ - 1));
        if (tst == 0.f) break;
        if (tst <= (sqrtf(fabsf(SDD(mm_ - 1))) * sqrtf(fabsf(SDD(mm_)))) * eps) {
          er = (lane == mm_ - 1) ? 0.f : er;
          break;
        }
      }
      m = mm_;
    }
    int l = l1, lsv = l, lend = m, lendsv = lend;
    l1 = m + 1;
    if (lend == l) continue;
    float anorm = 0.f;
    for (int i = l; i <= lend; i++) anorm = fmaxf(anorm, fabsf(SDD(i - 1)));
    for (int i = l; i <= lend - 1; i++) anorm = fmaxf(anorm, fabsf(SEE(i - 1)));
    if (anorm == 0.f) continue;
    if (fabsf(SDD(lend - 1)) < fabsf(SDD(l - 1))) { lend = lsv; l = lendsv; }
    if (lend > l) {
      // ---- QL ----
      while (true) {
        int m2;
        {
          int i;
          for (i = l; i <= lend - 1; i++) {
            float tst = fabsf(SEE(i - 1)); tst = tst * tst;
            if (tst <= (eps2 * fabsf(SDD(i - 1))) * fabsf(SDD(i)) + safmin) break;
          }
          m2 = i;
        }
        if (m2 < lend) er = (lane == m2 - 1) ? 0.f : er;
        float p = SDD(l - 1);
        if (m2 == l) { dr = (lane == l - 1) ? p : dr; l++; if (l <= lend) continue; else break; }
        if (m2 == l + 1) {
          float rt1, rt2, c_, s_;
          slaev2f(SDD(l - 1), SEE(l - 1), SDD(l), &rt1, &rt2, &c_, &s_);
          for (int i = lane; i < n; i += 64) {
            float t1 = zb[l * ldz + i];
            float t0 = zb[(l - 1) * ldz + i];
            zb[l * ldz + i] = c_ * t1 - s_ * t0;
            zb[(l - 1) * ldz + i] = s_ * t1 + c_ * t0;
          }
          dr = (lane == l - 1) ? rt1 : dr;
          dr = (lane == l) ? rt2 : dr;
          er = (lane == l - 1) ? 0.f : er;
          l += 2; if (l <= lend) continue; else break;
        }
        if (jtot == nmaxit) break;
        jtot++;
        float g = (SDD(l) - p) / (2.f * SEE(l - 1));
        float r = slapy2f(g, 1.f);
        g = SDD(m2 - 1) - p + SEE(l - 1) / (g + copysignf(r, g));
        float s_ = 1.f, c_ = 1.f; p = 0.f;
        for (int i = m2 - 1; i >= l; i--) {
          float ee = SEE(i - 1);
          float f = s_ * ee, b2 = c_ * ee;
          float cc, ss, rr;
          slartgf(g, f, &cc, &ss, &rr);
          c_ = cc; s_ = ss;
          if (i != m2 - 1) er = (lane == i) ? rr : er;
          g = SDD(i) - p;
          rr = (SDD(i - 1) - g) * s_ + 2.f * c_ * b2;
          p = s_ * rr;
          dr = (lane == i) ? (g + p) : dr;
          g = c_ * rr - b2;
          cwr = (lane == (i - l)) ? c_ : cwr;
          swr = (lane == (i - l)) ? (-s_) : swr;
        }
        int mm2 = m2 - l + 1;
        for (int jj = mm2 - 2; jj >= 0; jj--) {
          float ct_ = __shfl(cwr, jj), st_ = __shfl(swr, jj);
          int colj = l - 1 + jj;
          for (int i = lane; i < n; i += 64) {
            float t1 = zb[(colj + 1) * ldz + i];
            float t0 = zb[colj * ldz + i];
            zb[(colj + 1) * ldz + i] = ct_ * t1 - st_ * t0;
            zb[colj * ldz + i] = st_ * t1 + ct_ * t0;
          }
        }
        {
          float nv = SDD(l - 1) - p;
          dr = (lane == l - 1) ? nv : dr;
          er = (lane == l - 1) ? g : er;
        }
      }
    } else {
      // ---- QR ----
      while (true) {
        int m2;
        {
          int i;
          for (i = l; i >= lend + 1; i--) {
            float tst = fabsf(SEE(i - 2)); tst = tst * tst;
            if (tst <= (eps2 * fabsf(SDD(i - 1))) * fabsf(SDD(i - 2)) + safmin) break;
          }
          m2 = i;
        }
        if (m2 > lend) er = (lane == m2 - 2) ? 0.f : er;
        float p = SDD(l - 1);
        if (m2 == l) { dr = (lane == l - 1) ? p : dr; l--; if (l >= lend) continue; else break; }
        if (m2 == l - 1) {
          float rt1, rt2, c_, s_;
          slaev2f(SDD(l - 2), SEE(l - 2), SDD(l - 1), &rt1, &rt2, &c_, &s_);
          for (int i = lane; i < n; i += 64) {
            float t1 = zb[(l - 1) * ldz + i];
            float t0 = zb[(l - 2) * ldz + i];
            zb[(l - 1) * ldz + i] = c_ * t1 - s_ * t0;
            zb[(l - 2) * ldz + i] = s_ * t1 + c_ * t0;
          }
          dr = (lane == l - 2) ? rt1 : dr;
          dr = (lane == l - 1) ? rt2 : dr;
          er = (lane == l - 2) ? 0.f : er;
          l -= 2; if (l >= lend) continue; else break;
        }
        if (jtot == nmaxit) break;
        jtot++;
        float g = (SDD(l - 2) - p) / (2.f * SEE(l - 2));
        float r = slapy2f(g, 1.f);
        g = SDD(m2 - 1) - p + SEE(l - 2) / (g + copysignf(r, g));
        float s_ = 1.f, c_ = 1.f; p = 0.f;
        for (int i = m2; i <= l - 1; i++) {
          float ee = SEE(i - 1);
          float f = s_ * ee, b2 = c_ * ee;
          float cc, ss, rr;
          slartgf(g, f, &cc, &ss, &rr);
          c_ = cc; s_ = ss;
          if (i != m2) er = (lane == i - 2) ? rr : er;
          g = SDD(i - 1) - p;
          rr = (SDD(i) - g) * s_ + 2.f * c_ * b2;
          p = s_ * rr;
          dr = (lane == i - 1) ? (g + p) : dr;
          g = c_ * rr - b2;
          cwr = (lane == (i - m2)) ? c_ : cwr;
          swr = (lane == (i - m2)) ? s_ : swr;
        }
        int mm2 = l - m2 + 1;
        for (int jj = 0; jj <= mm2 - 2; jj++) {
          float ct_ = __shfl(cwr, jj), st_ = __shfl(swr, jj);
          int colj = m2 - 1 + jj;
          for (int i = lane; i < n; i += 64) {
            float t1 = zb[(colj + 1) * ldz + i];
            float t0 = zb[colj * ldz + i];
            zb[(colj + 1) * ldz + i] = ct_ * t1 - st_ * t0;
            zb[colj * ldz + i] = st_ * t1 + ct_ * t0;
          }
        }
        {
          float nv = SDD(l - 1) - p;
          dr = (lane == l - 1) ? nv : dr;
          er = (lane == l - 2) ? g : er;
        }
      }
    }
  }
  for (int ii = 2; ii <= n; ii++) {
    int i = ii - 1, k = i;
    float p = SDD(i - 1);
    for (int j = ii; j <= n; j++) {
      float dj = SDD(j - 1);
      if (dj < p) { k = j; p = dj; }
    }
    if (k != i) {
      float old = SDD(i - 1);
      dr = (lane == k - 1) ? old : dr;
      dr = (lane == i - 1) ? p : dr;
      for (int r = lane; r < n; r += 64) {
        float t5 = zb[(i - 1) * ldz + r];
        zb[(i - 1) * ldz + r] = zb[(k - 1) * ldz + r];
        zb[(k - 1) * ldz + r] = t5;
      }
    }
  }
  if (lane < n) d[lane] = dr;
  if (lane < n - 1) e[lane] = er;
}

// ======================= f32 D&C merge, MULTI-GROUP (slaed1/2/3 semantics) ===

__device__ void laed1_multi(float* d, float* e, float* Qm, float* Q2b, float* Smb,
                            float* zv, float* dl, float* wv, float* wg, float* pvf,
                            float* dvf, int* srcx, int* dsrc, int* iq,
                            int goff, const int* iwps, int p0, int G,
                            int tid, int* shi, float* shdf,
                            double* sdl, double* spv, int* defcnt) {
  int Tg = THREADS / G;
  int g = tid / Tg, gtid = tid - g * Tg;
  int pg = 2 * (p0 + g);
  int prev = (pg == 0) ? 0 : iwps[pg - 1];
  int off = goff + prev;
  int n = iwps[pg + 1] - prev;
  int n1 = (pg == 0) ? iwps[0] : (n / 2);
  int n2 = n - n1;
  float rho_in = e[off + n1 - 1];
  float* dg = d + off;
  float* zvg = zv + off;  float* dlg = dl + off;  float* wvg = wv + off;
  float* wgg = wg + off;  float* pvfg = pvf + off; float* dvfg = dvf + off;
  int* srcxg = srcx + off; int* dsrcg = dsrc + off; int* iqg = iq + off;
  double* sdlg = sdl + off; double* spvg = spv + off;
  float* Q2g = Q2b + (size_t)off * 128;
  float* Smg = Smb + (size_t)off * 128 + off;

  for (int t = gtid; t < n1; t += Tg) zvg[t] = Qm[(off + t) * LDQ + off + n1 - 1];
  for (int t = gtid; t < n2; t += Tg) zvg[n1 + t] = Qm[(off + n1 + t) * LDQ + off + n1];
  __syncthreads();                                   // B1
  if (gtid == 0) {
    float rho = rho_in;
    if (rho < 0.f) for (int t = n1; t < n; t++) zvg[t] = -zvg[t];
    float tsc = 1.0f / sqrtf(2.0f);
    for (int t = 0; t < n; t++) zvg[t] *= tsc;
    rho = fabsf(2.0f * rho);
    {
      int i = 0, j = n1, p = 0;
      while (i < n1 && j < n) {
        if (dg[i] <= dg[j]) srcxg[p++] = i++; else srcxg[p++] = j++;
      }
      while (i < n1) srcxg[p++] = i++;
      while (j < n) srcxg[p++] = j++;
    }
    int imax = 0, jmax = 0;
    for (int t = 1; t < n; t++) if (fabsf(zvg[t]) > fabsf(zvg[imax])) imax = t;
    for (int t = 1; t < n; t++) if (fabsf(dg[t]) > fabsf(dg[jmax])) jmax = t;
    float tol = 8.0f * EPSF * fmaxf(fabsf(dg[jmax]), fabsf(zvg[imax]));
    int k = 0, nd = 0;
    if (rho * fabsf(zvg[imax]) <= tol) {
      for (int t = 0; t < n; t++) { dsrcg[nd] = srcxg[t]; dvfg[nd] = dg[srcxg[t]]; nd++; }
    } else {
      int pj = -1;
      for (int jj = 0; jj < n; jj++) {
        int nj = srcxg[jj];
        if (rho * fabsf(zvg[nj]) <= tol) {
          dsrcg[nd] = nj; dvfg[nd] = dg[nj]; nd++;
        } else if (pj < 0) {
          pj = nj;
        } else {
          float s_ = zvg[pj], c_ = zvg[nj];
          float tau_ = slapy2f(c_, s_);
          float t3 = dg[nj] - dg[pj];
          c_ /= tau_; s_ = -s_ / tau_;
          if (fabsf(t3 * c_ * s_) <= tol) {
            zvg[nj] = tau_; zvg[pj] = 0.f;
            for (int r = 0; r < n; r++) {
              float x_ = Qm[(off + pj) * LDQ + off + r];
              float y_ = Qm[(off + nj) * LDQ + off + r];
              Qm[(off + pj) * LDQ + off + r] = c_ * x_ + s_ * y_;
              Qm[(off + nj) * LDQ + off + r] = c_ * y_ - s_ * x_;
            }
            float dp = dg[pj], dn = dg[nj];
            dg[nj] = dp * s_ * s_ + dn * c_ * c_;
            dg[pj] = dp * c_ * c_ + dn * s_ * s_;
            dsrcg[nd] = pj; dvfg[nd] = dg[pj]; nd++;
            pj = nj;
          } else {
            dlg[k] = dg[pj]; wvg[k] = zvg[pj]; srcxg[k] = pj; k++;
            pj = nj;
          }
        }
      }
      if (pj >= 0) { dlg[k] = dg[pj]; wvg[k] = zvg[pj]; srcxg[k] = pj; k++; }
    }
    shi[200 + g] = k; shi[208 + g] = nd; shdf[8 + g] = rho;
    if (nd > 0) atomicAdd(defcnt, nd);
  }
  __syncthreads();                                   // B2
  int k = shi[200 + g], nd = shi[208 + g];
  float rho = shdf[8 + g];
  if (k > 1) {
    for (int t = gtid; t < k; t += Tg) {
      sdlg[t] = (double)dlg[t];
      spvg[t] = (double)rho * (double)wvg[t] * (double)wvg[t];
    }
  }
  __syncthreads();                                   // B3
  // secular roots in f64, shifted frame: lambda_j = dl_j + eta.
  // f(x) = 1 + sum spv/(dsh - x) is strictly increasing on (lo,hi):
  // bracket-safeguarded NEWTON (~6-10 iters vs ~53 fixed bisection steps);
  // derivative is free (fp += u*inv reuses the same divide). Root converges
  // to f64 ulp either way -> f32-cast Sm entries essentially identical.
  if (k > 1 && gtid < k) {
    int j = gtid;
    double lo = 0.0, hi;
    if (j == k - 1) {
      double sw2 = 0.0;
      for (int t = 0; t < k; t++) sw2 += spvg[t];
      hi = sw2;
      for (int g2 = 0; g2 < 8; g2++) {
        double f = 1.0;
        for (int t = 0; t < k; t++) f += spvg[t] / ((sdlg[t] - sdlg[j]) - hi);
        if (f >= 0.0) break;
        hi *= 2.0;
      }
    } else hi = sdlg[j + 1] - sdlg[j];
    double gap = hi;
    double x = 0.5 * (lo + hi);
    for (int it = 0; it < 60; it++) {
      double f = 1.0, fp = 0.0;
      for (int t = 0; t < k; t++) {
        double inv = 1.0 / ((sdlg[t] - sdlg[j]) - x);
        double u = spvg[t] * inv;
        f += u; fp += u * inv;
      }
      if (f < 0.0) lo = x; else hi = x;
      double xn = x - f / fp;
      if (!(xn > lo && xn < hi)) xn = 0.5 * (lo + hi);
      if (xn == x) break;
      x = xn;
    }
    double eta = x;
    if (eta <= 0.0) eta = gap * 1e-30;
    if (j < k - 1 && eta >= gap) eta = gap * (1.0 - 1e-15);
    dg[j] = (float)(sdlg[j] + eta);
    for (int t = 0; t < k; t++)
      Smg[t * 128 + j] = (float)((sdlg[t] - sdlg[j]) - eta);
  }
  __syncthreads();                                   // B4
  // Gu-Eisenstat reweighting (f32, as slaed3)
  if (k > 1 && gtid < k) {
    int i = gtid;
    float acc = Smg[i * 128 + i];
    for (int j = 0; j < k; j++) {
      if (j == i) continue;
      acc *= Smg[i * 128 + j] / (dlg[i] - dlg[j]);
    }
    wgg[i] = copysignf(sqrtf(fmaxf(-acc, 0.f)), wvg[i]);
  }
  __syncthreads();                                   // B5
  // secular vectors + positive normalization (thread j, exact order)
  if (k > 1 && gtid < k) {
    int j = gtid;
    float nrm2 = 0.f;
    for (int i = 0; i < k; i++) {
      float u = wgg[i] / Smg[i * 128 + j];
      Smg[i * 128 + j] = u;
      nrm2 += u * u;
    }
    float nrm = sqrtf(nrm2);
    for (int i = 0; i < k; i++) Smg[i * 128 + j] /= nrm;
  }
  __syncthreads();                                   // B6
  if (k > 1) {
    // gather Q2g[j][r] = sum_i Qm[off+srcxg[i]][off+r] * Smg[i][j]
    int j = gtid & 127, rg = gtid >> 7;
    int RG = Tg >> 7; if (RG < 1) RG = 1;
    if (j < k) {
      int chunk = (n + RG - 1) / RG;
      int rbeg = rg * chunk, rend = rbeg + chunk;
      if (rend > n) rend = n;
      int r0 = rbeg;
      for (; r0 + 8 <= rend; r0 += 8) {
        float a0 = 0.f, a1 = 0.f, a2 = 0.f, a3 = 0.f;
        float a4 = 0.f, a5 = 0.f, a6 = 0.f, a7 = 0.f;
        for (int i = 0; i < k; i++) {
          float s = Smg[i * 128 + j];
          const float* q = &Qm[(off + srcxg[i]) * LDQ + off + r0];
          a0 += q[0] * s; a1 += q[1] * s; a2 += q[2] * s; a3 += q[3] * s;
          a4 += q[4] * s; a5 += q[5] * s; a6 += q[6] * s; a7 += q[7] * s;
        }
        float* o = &Q2g[j * 128 + r0];
        o[0] = a0; o[1] = a1; o[2] = a2; o[3] = a3;
        o[4] = a4; o[5] = a5; o[6] = a6; o[7] = a7;
      }
      for (; r0 < rend; r0++) {
        float a = 0.f;
        for (int i = 0; i < k; i++)
          a += Qm[(off + srcxg[i]) * LDQ + off + r0] * Smg[i * 128 + j];
        Q2g[j * 128 + r0] = a;
      }
    }
  } else if (k == 1 && gtid == 0) {
    zvg[0] = dlg[0] + rho * (wvg[0] * wvg[0]);
    for (int r = 0; r < n; r++) Q2g[r] = Qm[(off + srcxg[0]) * LDQ + off + r];
  }
  __syncthreads();                                   // B7
  if (k > 1 && gtid < k) zvg[gtid] = dg[gtid];
  __syncthreads();                                   // B8
  for (int t2 = gtid; t2 < nd; t2 += Tg)
    for (int r = 0; r < n; r++) Q2g[(k + t2) * 128 + r] = Qm[(off + dsrcg[t2]) * LDQ + off + r];
  for (int j = gtid; j < n; j += Tg) pvfg[j] = (j < k) ? zvg[j] : dvfg[j - k];
  __syncthreads();                                   // B9
  // ascending sort: parallel STABLE RANK (ties by original index). For
  // distinct keys (the generic case) identical permutation to the serial
  // selection sort; fully pipelined O(n) scan per thread, no serial chain.
  for (int j = gtid; j < n; j += Tg) {
    float kj = pvfg[j];
    int r = 0;
    for (int i = 0; i < n; i++) {
      float ki = pvfg[i];
      if (ki < kj || (ki == kj && i < j)) r++;
    }
    iqg[r] = j;
  }
  __syncthreads();                                   // B10
  // permuted writeback, r-chunked (elementwise, exact)
  {
    int j = gtid & 127, rg = gtid >> 7;
    int RG = Tg >> 7; if (RG < 1) RG = 1;
    if (j < n) {
      int s2 = iqg[j];
      if (rg == 0) dg[j] = pvfg[s2];
      int chunk = (n + RG - 1) / RG;
      int rbeg = rg * chunk, rend = rbeg + chunk;
      if (rend > n) rend = n;
      for (int r = rbeg; r < rend; r++) Qm[(off + j) * LDQ + off + r] = Q2g[s2 * 128 + r];
    }
  }
  __syncthreads();                                   // B11
}

__device__ void laed0_f32(float* d, float* e, float* Qm, float* Q2, float* Sm,
                          float* zv, float* dl, float* wv, float* wg, float* pvf,
                          float* dvf, int* srcx, int* dsrc, int* iq, int* iwps,
                          int goff, int m, int tid, int* shi, float* shdf,
                          double* sdl, double* spv, int* defcnt) {
  if (tid == 0) {
    iwps[0] = m; int sp = 1;
    while (iwps[sp - 1] > SMLSIZ) {
      for (int j = sp - 1; j >= 0; j--) { iwps[2 * j + 1] = (iwps[j] + 1) / 2; iwps[2 * j] = iwps[j] / 2; }
      sp *= 2;
    }
    for (int j = 1; j < sp; j++) iwps[j] += iwps[j - 1];
    shi[134] = sp;
    for (int i = 0; i < sp - 1; i++) {
      int bnd = goff + iwps[i];
      d[bnd - 1] -= fabsf(e[bnd - 1]);
      d[bnd] -= fabsf(e[bnd - 1]);
    }
  }
  __syncthreads();
  int subpbs = shi[134];
  // leaves: wave-parallel register steqr, one leaf per wave
  {
    int lw = tid >> 6;
    if (lw < subpbs) {
      int boff = goff + (lw == 0 ? 0 : iwps[lw - 1]);
      int bm = iwps[lw] - (lw == 0 ? 0 : iwps[lw - 1]);
      steqr_reg(d + boff, e + boff, bm, Qm + boff * LDQ + boff, LDQ, tid & 63);
    }
  }
  __syncthreads();
  int cur = subpbs;
  while (cur > 1) {
    int nm = cur >> 1;
    for (int p0 = 0; p0 < nm; ) {
      int G = (nm - p0 >= 4) ? 4 : ((nm - p0 >= 2) ? 2 : 1);
      laed1_multi(d, e, Qm, Q2, Sm, zv, dl, wv, wg, pvf, dvf, srcx, dsrc, iq,
                  goff, iwps, p0, G, tid, shi, shdf, sdl, spv, defcnt);
      p0 += G;
    }
    if (tid == 0) for (int t = 0; 2 * t + 1 < cur; t++) iwps[t] = iwps[2 * t + 1];
    __syncthreads();
    cur >>= 1;
  }
}

// ======================= eig P1: ssytd2 tridiagonalization =======================
// Reads finalized cov (Bf), writes transformed Householder A (Af) + d/e/tau.

__global__ __launch_bounds__(THREADS) void eig_p1_kernel(const float* __restrict__ covB,
                                                         float* __restrict__ Aout,
                                                         float* __restrict__ vecs) {
  int b = blockIdx.x, tid = threadIdx.x;
  const float* Cg = covB + (size_t)b * 16384;
  float* Ag = Aout + (size_t)b * 16384;
  __shared__ float As[16384];
  __shared__ float sh_e[128], sh_tau[128], sh_pvf[128];
  __shared__ float redf[128];
  __shared__ float shdf[4];
  float* A = As; float* e = sh_e; float* tauv = sh_tau; float* pvf = sh_pvf;

  for (int idx = tid; idx < 16384; idx += THREADS) As[idx] = Cg[idx];
  if (tid < 128) { sh_e[tid] = 0.f; sh_tau[tid] = 0.f; }
  __syncthreads();

  for (int i1 = 1; i1 <= NC - 1; i1++) {
    int ii = i1 - 1;
    int mlen = NC - i1;
    float ps = 0.f;
    if (tid < 128) {
      for (int t = tid; t < mlen - 1; t += 128) {
        float v = A[ii * 128 + ii + 2 + t];
        ps += v * v;
      }
      redf[tid] = ps;
    }
    __syncthreads();                               // B1
    if (tid < 64) {
      float a = redf[tid] + redf[tid + 64];
      a += __shfl_xor(a, 32); a += __shfl_xor(a, 16); a += __shfl_xor(a, 8);
      a += __shfl_xor(a, 4);  a += __shfl_xor(a, 2);  a += __shfl_xor(a, 1);
      if (tid == 0) {
        float xnorm = sqrtf(a);
        float alpha = A[ii * 128 + ii + 1];
        float taui, ei, scl;
        if (xnorm == 0.f) { taui = 0.f; ei = alpha; scl = 0.f; }
        else {
          float beta = -copysignf(slapy2f(alpha, xnorm), alpha);
          taui = (beta - alpha) / beta;
          scl = 1.f / (alpha - beta);
          ei = beta;
        }
        e[ii] = ei; tauv[ii] = taui; shdf[2] = scl;
      }
    }
    __syncthreads();                               // B2
    float taui = tauv[ii];
    if (taui != 0.f) {
      float scl = shdf[2];
      for (int t = tid; t < mlen - 1; t += 128) A[ii * 128 + ii + 2 + t] *= scl;
      __syncthreads();                             // B3
      for (int r = tid; r < mlen; r += 128) {
        float acc = 0.f;
        int row = ii + 1 + r;
        acc += A[(ii + 1) * 128 + row];            // s=0 term, v0 == 1
        for (int s = 1; s < mlen; s++) acc += A[(ii + 1 + s) * 128 + row] * A[ii * 128 + ii + 1 + s];
        pvf[r] = taui * acc;
      }
      __syncthreads();                             // B4
      if (tid < 128) {
        float pd = 0.f;
        for (int t = tid; t < mlen; t += 128) {
          float vt = (t == 0) ? 1.f : A[ii * 128 + ii + 1 + t];
          pd += pvf[t] * vt;
        }
        redf[tid] = pd;
      }
      __syncthreads();                             // B5
      if (tid < 64) {
        float a = redf[tid] + redf[tid + 64];
        a += __shfl_xor(a, 32); a += __shfl_xor(a, 16); a += __shfl_xor(a, 8);
        a += __shfl_xor(a, 4);  a += __shfl_xor(a, 2);  a += __shfl_xor(a, 1);
        if (tid == 0) shdf[3] = -0.5f * taui * a;
      }
      __syncthreads();                             // B6
      float alpha2 = shdf[3];
      for (int t = tid; t < mlen; t += 128) {
        float vt = (t == 0) ? 1.f : A[ii * 128 + ii + 1 + t];
        pvf[t] += alpha2 * vt;
      }
      __syncthreads();                             // B7
      if ((tid & 127) < mlen) {
        int r = tid & 127, g = tid >> 7;
        int chunk = (mlen + 3) >> 2;
        int cb = g * chunk, ce = cb + chunk;
        if (ce > mlen) ce = mlen;
        float vr = (r == 0) ? 1.f : A[ii * 128 + ii + 1 + r];
        float pr = pvf[r];
        for (int c2 = cb; c2 < ce; c2++) {
          float vc = (c2 == 0) ? 1.f : A[ii * 128 + ii + 1 + c2];
          A[(ii + 1 + c2) * 128 + (ii + 1 + r)] -= vr * pvf[c2] + pr * vc;
        }
      }
      __syncthreads();                             // B8
    }
  }
  for (int idx = tid; idx < 16384; idx += THREADS) Ag[idx] = As[idx];
  if (tid < 128) {
    vecs[b * 128 + tid] = As[tid * 128 + tid];      // d = diag(A)
    vecs[2048 + b * 128 + tid] = sh_e[tid];
    vecs[4096 + b * 128 + tid] = sh_tau[tid];
  }
}

// ======================= eig P2: sstedc('I') D&C =======================

__global__ __launch_bounds__(THREADS) void eig_p2_kernel(float* __restrict__ Qw,
                                                         float* Q2w, float* Sw,
                                                         float* vecs, int* defcnt) {
  int b = blockIdx.x, tid = threadIdx.x;
  float* Qg = Qw + (size_t)b * 16384;
  float* Q2 = Q2w + (size_t)b * 16640;
  float* Sm = Sw + (size_t)b * 16384;

  __shared__ float Qs[128 * LDQ];
  __shared__ float sh_d[128], sh_e[128], sh_zv[128], sh_dl[128];
  __shared__ float sh_wv[128], sh_wg[128], sh_pvf[128], sh_dvf[128];
  __shared__ int sh_iq[128], sh_srcx[128], sh_dsrc[128];
  __shared__ int iwps[64];
  __shared__ float shdf[16];
  __shared__ int shi[280];
  __shared__ double sdl[128];
  __shared__ double spv[128];

  float* Qm = Qs;
  float* d = sh_d; float* e = sh_e; float* zv = sh_zv;
  float* dl = sh_dl; float* wv = sh_wv; float* wg = sh_wg; float* pvf = sh_pvf;
  float* dvf = sh_dvf;
  int* iq = sh_iq; int* srcx = sh_srcx; int* dsrc = sh_dsrc;

  if (tid < 128) {
    sh_d[tid] = vecs[b * 128 + tid];
    sh_e[tid] = vecs[2048 + b * 128 + tid];
  }
  for (int idx = tid; idx < 16384; idx += THREADS) {
    int c = idx >> 7, r = idx & 127;
    Qs[c * LDQ + r] = (c == r) ? 1.f : 0.f;
  }
  __syncthreads();
  if (tid == 0) {
    int ns = 0, start = 0;
    while (start < NC) {
      int fin = start;
      while (fin < NC - 1) {
        float tiny = EPSF * sqrtf(fabsf(d[fin])) * sqrtf(fabsf(d[fin + 1]));
        if (fabsf(e[fin]) > tiny) fin++;
        else break;
      }
      shi[2 + 2 * ns] = start; shi[3 + 2 * ns] = fin - start + 1; ns++;
      start = fin + 1;
    }
    shi[0] = ns;
  }
  __syncthreads();
  int nsplit = shi[0];
  for (int sb = 0; sb < nsplit; sb++) {
    int goff = shi[2 + 2 * sb], m = shi[3 + 2 * sb];
    if (m == 1) continue;
    if (m <= SMLSIZ) {
      if (tid < 64) steqr_reg(d + goff, e + goff, m, Qm + goff * LDQ + goff, LDQ, tid);
      __syncthreads();
    } else {
      if (tid == 0) {
        float mx = 0.f;
        for (int i = 0; i < m; i++) mx = fmaxf(mx, fabsf(d[goff + i]));
        for (int i = 0; i < m - 1; i++) mx = fmaxf(mx, fabsf(e[goff + i]));
        shdf[0] = mx;
      }
      __syncthreads();
      float onrm = shdf[0];
      if (onrm != 0.f) {
        float mul = 1.f / onrm;
        for (int t = tid; t < m; t += 128) d[goff + t] *= mul;
        for (int t = tid; t < m - 1; t += 128) e[goff + t] *= mul;
        __syncthreads();
        laed0_f32(d, e, Qm, Q2, Sm, zv, dl, wv, wg, pvf, dvf, srcx, dsrc, iq,
                  iwps, goff, m, tid, shi, shdf, sdl, spv, defcnt);
        for (int t = tid; t < m; t += 128) d[goff + t] *= onrm;
        __syncthreads();
      }
    }
  }
  // final eigen d-sort: parallel stable rank (ties by original column index)
  if (tid < 128) {
    float kj = d[tid];
    int r = 0;
    for (int i = 0; i < 128; i++) {
      float ki = d[i];
      if (ki < kj || (ki == kj && i < tid)) r++;
    }
    shi[140 + r] = tid;
    zv[r] = kj;
  }
  __syncthreads();
  if (tid < 128) d[tid] = zv[tid];
  __syncthreads();
  {
    int j = tid & 127, g = tid >> 7;
    int rbeg = g * 32, rend = rbeg + 32;
    int src = shi[140 + j];
    for (int r = rbeg; r < rend; r++) Q2[j * 128 + r] = Qm[src * LDQ + r];
  }
  __syncthreads();
  {
    int j = tid & 127, g = tid >> 7;
    int rbeg = g * 32, rend = rbeg + 32;
    for (int r = rbeg; r < rend; r++) Qm[j * LDQ + r] = Q2[j * 128 + r];
  }
  __syncthreads();
  for (int idx = tid; idx < 16384; idx += THREADS) {
    int c = idx >> 7, r = idx & 127;
    Qg[idx] = Qs[c * LDQ + r];
  }
  if (tid < 128) vecs[b * 128 + tid] = d[tid];
}

// ======================= eig P3: sormtr + top-64 extract =======================

__global__ __launch_bounds__(THREADS) void eig_p3_kernel(const float* __restrict__ Ain,
                                                         const float* __restrict__ vecs,
                                                         float* __restrict__ Qw,
                                                         float* __restrict__ Vw) {
  int b = blockIdx.x, tid = threadIdx.x;
  const float* Ag = Ain + (size_t)b * 16384;
  float* Qg = Qw + (size_t)b * 16384;
  __shared__ float As[16384];
  __shared__ float Qs[128 * LDQ];
  __shared__ float sh_tau[128];
  float* A = As; float* Qm = Qs; float* tauv = sh_tau;

  for (int idx = tid; idx < 16384; idx += THREADS) As[idx] = Ag[idx];
  for (int idx = tid; idx < 16384; idx += THREADS) {
    int c = idx >> 7, r = idx & 127;
    Qs[c * LDQ + r] = Qg[idx];
  }
  if (tid < 128) sh_tau[tid] = vecs[4096 + b * 128 + tid];
  __syncthreads();

  for (int j1 = NC - 1; j1 >= 1; j1--) {
    int jj = j1 - 1;
    float tj = tauv[jj];
    if (tj != 0.f) {
      if (tid < NC) {
        int col = tid;
        float s = Qm[col * LDQ + jj + 1];
        for (int r = jj + 2; r < NC; r++) s += A[jj * 128 + r] * Qm[col * LDQ + r];
        s *= tj;
        Qm[col * LDQ + jj + 1] -= s;
        for (int r = jj + 2; r < NC; r++) Qm[col * LDQ + r] -= s * A[jj * 128 + r];
      }
    }
  }
  __syncthreads();

  for (int idx = tid; idx < NC * KTOP; idx += THREADS) {
    int c2 = idx / KTOP, kk = idx % KTOP;
    Vw[(size_t)b * (NC * KTOP) + idx] = Qm[(127 - kk) * LDQ + c2];
  }
  for (int idx = tid; idx < 16384; idx += THREADS) {
    int c = idx >> 7, r = idx & 127;
    Qg[idx] = Qs[c * LDQ + r];
  }
}

// ======================= diagnostics =======================

__global__ void zeroi_kernel(int* p) { p[0] = 0; p[1] = 0; }

__global__ __launch_bounds__(128) void diag_kernel(const float* __restrict__ covB,
                                                   const float* __restrict__ Qw,
                                                   const float* __restrict__ vecs,
                                                   const float* __restrict__ Vw, int* dcode) {
  int b = blockIdx.x, tid = threadIdx.x;
  const float* C = covB + (size_t)b * 16384;
  const float* Qm = Qw + (size_t)b * 16384;
  const float* d = vecs + b * 128;
  int flags = 0;
  double rmax = 0.0;
  for (int k = 64; k < 128; k++) {
    double lam = (double)d[k];
    double acc = 0.0;
    for (int j = 0; j < 128; j++) acc += (double)C[j * 128 + tid] * (double)Qm[k * 128 + j];
    acc -= lam * (double)Qm[k * 128 + tid];
    rmax = fmax(rmax, fabs(acc));
  }
  if (rmax > 1e-3) flags |= 1;
  double omax = 0.0;
  for (int p = tid; p < 64 * 64; p += 128) {
    int i = 64 + p / 64, j = 64 + p % 64;
    if (j < i) continue;
    double s = 0.0;
    for (int r = 0; r < 128; r++) s += (double)Qm[i * 128 + r] * (double)Qm[j * 128 + r];
    if (i == j) s -= 1.0;
    omax = fmax(omax, fabs(s));
  }
  if (omax > 1e-3) flags |= 2;
  if (tid < 127 && d[tid + 1] < d[tid] - 1e-5f) flags |= 4;
  for (int idx = tid; idx < 8192; idx += 128) {
    int c2 = idx / 64, kk = idx % 64;
    if (Vw[(size_t)b * 8192 + idx] != Qm[(127 - kk) * 128 + c2]) flags |= 8;
  }
  if (tid == 0) {
    for (int k = 64; k < 128; k++) if (!(d[k] > 0.2f && d[k] < 5.0f)) flags |= 16;
    float s = 0.f;
    for (int c = 0; c < 128; c++) { float v = Vw[(size_t)b * 8192 + c * 64]; s += v * v; }
    if (fabsf(s - 1.f) > 1e-2f) flags |= 32;
  }
  if (flags) atomicOr(dcode, flags);
}

__global__ void emit_kernel(const int* dcode, float* out) {
  int f = dcode[0];
  if (f) {
    int code = 1000;
    if (f & 1) code += 400;
    if (f & 2) code += 200;
    if (f & 4) code += 100;
    if (f & 8) code += 40;
    if (f & 16) code += 20;
    if (f & 32) code += 10;
    int nd = dcode[1]; if (nd > 9) nd = 9;
    code += nd;
    out[0] = (float)code;
  }
}

// ======================= numpy-f32-mirror mean / cov =======================

__global__ __launch_bounds__(128) void mean_np_kernel(const float* __restrict__ x,
                                                      float* __restrict__ mean32) {
  int b = blockIdx.x, c = threadIdx.x;
  const float* xb = x + (size_t)b * 2097152;
  float s = 0.0f;
#pragma unroll 16
  for (int n = 0; n < 16384; n++) s = __fadd_rn(s, xb[n * 128 + c]);
  mean32[b * 128 + c] = s / 16384.0f;
}

// Upper tile-pairs only (tj >= ti); lower mirrored in covfin (bit-exact by
// commutativity + same n-order). LDS stride 66: banks (4k+n)%32 -> <=2-way
// (free), float2-aligned for even rows AND odd rows.
__global__ __launch_bounds__(256) void covnp_kernel(const float* __restrict__ x,
                                                    const float* __restrict__ mean32,
                                                    float* __restrict__ S) {
  int b = blockIdx.x;
  int p = blockIdx.y;
  int ti4, tj4;
  if (p < 4) { ti4 = 0; tj4 = p; }
  else if (p < 7) { ti4 = 1; tj4 = p - 3; }
  else if (p < 9) { ti4 = 2; tj4 = p - 5; }
  else { ti4 = 3; tj4 = 3; }
  int ti = ti4 * 32, tj = tj4 * 32;
  __shared__ float XI[32 * 66], XJ[32 * 66];
  int tid = threadIdx.x;
  int ci = 2 * (tid & 15), dj = 2 * (tid >> 4);
  float a00 = 0.f, a01 = 0.f, a10 = 0.f, a11 = 0.f;
  const float* xb = x + (size_t)b * 2097152;
  const float* mb = mean32 + b * 128;
  for (int n0 = 0; n0 < 16384; n0 += 64) {
    __syncthreads();
    for (int l = tid; l < 2048; l += 256) {
      int n = l >> 5, cc = l & 31;
      XI[cc * 66 + n] = __fsub_rn(xb[(n0 + n) * 128 + ti + cc], mb[ti + cc]);
      XJ[cc * 66 + n] = __fsub_rn(xb[(n0 + n) * 128 + tj + cc], mb[tj + cc]);
    }
    __syncthreads();
    const float2* pi0 = (const float2*)&XI[ci * 66];
    const float2* pi1 = (const float2*)&XI[(ci + 1) * 66];
    const float2* pj0 = (const float2*)&XJ[dj * 66];
    const float2* pj1 = (const float2*)&XJ[(dj + 1) * 66];
    for (int n2 = 0; n2 < 32; n2++) {
      float2 xi0 = pi0[n2], xi1 = pi1[n2], xj0 = pj0[n2], xj1 = pj1[n2];
      a00 = __fadd_rn(a00, __fmul_rn(xi0.x, xj0.x));
      a01 = __fadd_rn(a01, __fmul_rn(xi0.x, xj1.x));
      a10 = __fadd_rn(a10, __fmul_rn(xi1.x, xj0.x));
      a11 = __fadd_rn(a11, __fmul_rn(xi1.x, xj1.x));
      a00 = __fadd_rn(a00, __fmul_rn(xi0.y, xj0.y));
      a01 = __fadd_rn(a01, __fmul_rn(xi0.y, xj1.y));
      a10 = __fadd_rn(a10, __fmul_rn(xi1.y, xj0.y));
      a11 = __fadd_rn(a11, __fmul_rn(xi1.y, xj1.y));
    }
  }
  float* Sb = S + (size_t)b * 16384;
  int C = ti + ci, D = tj + dj;
  Sb[C * 128 + D] = a00;
  Sb[C * 128 + D + 1] = a01;
  Sb[(C + 1) * 128 + D] = a10;
  Sb[(C + 1) * 128 + D + 1] = a11;
}

// covfin: reads raw sums (A, upper tiles valid), writes finalized cov to B only
// (race-free); lower tiles mirrored from upper (bit-exact).
__global__ void covfin_kernel(const float* __restrict__ A, float* __restrict__ B) {
  int i = blockIdx.x * 256 + threadIdx.x;
  if (i < 262144) {
    int w = i & 16383;
    int base = i - w;
    int r = w >> 7, c = w & 127;
    int src = ((r >> 5) > (c >> 5)) ? (base + c * 128 + r) : i;
    B[i] = A[src] / 16383.0f;
  }
}

// ======================= projection =======================

__global__ __launch_bounds__(256) void proj_kernel(const float* __restrict__ x, const float* __restrict__ V,
                                                   const float* __restrict__ mean32, float* __restrict__ out) {
  __shared__ float Vs[128 * 64];
  __shared__ float Xs[64 * 128];
  __shared__ float ms[128];
  int b = blockIdx.x, t = blockIdx.y, tid = threadIdx.x;
  const float* xb = x + (size_t)b * 2097152 + (size_t)t * 64 * 128;
  const float* vb = V + (size_t)b * 8192;
  if (tid < 128) ms[tid] = mean32[b * 128 + tid];
  __syncthreads();
  for (int i = tid; i < 2048; i += 256) ((float4*)Vs)[i] = ((const float4*)vb)[i];
  for (int i = tid; i < 2048; i += 256) {
    float4 xv = ((const float4*)xb)[i];
    int cv = (i & 31) * 4;
    xv.x -= ms[cv]; xv.y -= ms[cv + 1]; xv.z -= ms[cv + 2]; xv.w -= ms[cv + 3];
    ((float4*)Xs)[i] = xv;
  }
  __syncthreads();
  int kk = tid & 63, w = tid >> 6;
  float acc[16];
#pragma unroll
  for (int r = 0; r < 16; r++) acc[r] = 0.f;
  for (int c4 = 0; c4 < 32; c4++) {
    float v0 = Vs[(c4 * 4 + 0) * 64 + kk];
    float v1 = Vs[(c4 * 4 + 1) * 64 + kk];
    float v2 = Vs[(c4 * 4 + 2) * 64 + kk];
    float v3 = Vs[(c4 * 4 + 3) * 64 + kk];
#pragma unroll
    for (int r = 0; r < 16; r++) {
      const float4 xv = ((const float4*)Xs)[(w * 16 + r) * 32 + c4];
      acc[r] += xv.x * v0 + xv.y * v1 + xv.z * v2 + xv.w * v3;
    }
  }
  float* ob = out + (size_t)b * 1048576 + (size_t)t * 4096;
#pragma unroll
  for (int r = 0; r < 16; r++) ob[(w * 16 + r) * 64 + kk] = acc[r];
}

// ======================= launch =======================

extern "C" void kernel_launch(void* const* d_in, const int* in_sizes, int n_in,
                              void* d_out, int out_size, void* d_ws, size_t ws_size,
                              hipStream_t stream) {
  (void)in_sizes; (void)n_in; (void)out_size; (void)ws_size;
  const float* x = (const float*)d_in[0];
  float* out = (float*)d_out;
  float* T = out + TBASEF;
  float* Af   = T + F_A;
  float* Bf   = T + F_B;
  float* Qf   = T + F_Q;
  float* Q2f  = T + F_Q2;
  float* Smf  = T + F_SM;
  float* vecsf = T + F_VECS;
  float* Vw = (float*)d_ws;
  float* mean32 = Vw + 131072;
  int* dcode = (int*)(mean32 + 2048);

  zeroi_kernel<<<dim3(1), dim3(1), 0, stream>>>(dcode);
  mean_np_kernel<<<dim3(16), dim3(128), 0, stream>>>(x, mean32);
  covnp_kernel<<<dim3(16, 10), dim3(256), 0, stream>>>(x, mean32, Af);
  covfin_kernel<<<dim3(1024), dim3(256), 0, stream>>>(Af, Bf);
  eig_p1_kernel<<<dim3(16), dim3(THREADS), 0, stream>>>(Bf, Af, vecsf);
  eig_p2_kernel<<<dim3(16), dim3(THREADS), 0, stream>>>(Qf, Q2f, Smf, vecsf, dcode + 1);
  eig_p3_kernel<<<dim3(16), dim3(THREADS), 0, stream>>>(Af, vecsf, Qf, Vw);
  diag_kernel<<<dim3(16), dim3(128), 0, stream>>>(Bf, Qf, vecsf, Vw, dcode);
  proj_kernel<<<dim3(16, 256), dim3(256), 0, stream>>>(x, Vw, mean32, out);
  emit_kernel<<<dim3(1), dim3(1), 0, stream>>>(dcode, out);
}

// Round 7
// 4437.128 us; speedup vs baseline: 4.3548x; 1.0765x over previous
//
#include <hip/hip_runtime.h>

#define NC 128
#define KTOP 64
#define SMLSIZ 25
#define EPSF 5.9604645e-8f
#define SAFMINF 1.17549435e-38f
#define LDQ 129    // LDS leading dim for Qm: breaks 64-way bank conflicts
#define LDS_SM 129 // LDS leading dim for Sm: conflict-free (129%32==1)
#define THREADS 512

// out-tail scratch (floats). out = 16,777,216 floats; scratch in top ~5.4MB,
// dead before proj overwrites out.
#define TBASEF 15400960
#define F_A    0         // 262144 f (covnp raw sums -> transformed Householder A)
#define F_B    262144    // 262144 f (finalized cov: eig input + diag)
#define F_Q    524288    // 262144 f (eigvec handoff p2a->p2b->p2c->p3 + diag)
#define F_Q2   786432    // 266240 f (global scratch in merges, sliced by off*128)
#define F_VECS 1314816   // 18432 f: d@0, e@2048, tau@4096, meta(int)@6144+b*320, onrm@11264+b*128

// ======================= f32 LAPACK helpers =======================

__device__ __forceinline__ float slapy2f(float x, float y) {
  float xa = fabsf(x), ya = fabsf(y);
  float w = fmaxf(xa, ya), z = fminf(xa, ya);
  if (z == 0.f) return w;
  float r = z / w;
  return w * sqrtf(1.f + r * r);
}

// LAPACK >=3.10 slartg convention (c >= 0, r carries sign of f)
__device__ __forceinline__ void slartgf(float f, float g, float* c, float* s, float* r) {
  if (g == 0.f) { *c = 1.f; *s = 0.f; *r = f; }
  else if (f == 0.f) { *c = 0.f; *s = (g >= 0.f) ? 1.f : -1.f; *r = fabsf(g); }
  else {
    float d_ = sqrtf(f * f + g * g);
    *c = fabsf(f) / d_;
    *r = (f >= 0.f) ? d_ : -d_;
    *s = g / (*r);
  }
}

__device__ void slaev2f(float a, float b, float c,
                        float* rt1, float* rt2, float* cs1, float* sn1) {
  float sm = a + c, df = a - c, adf = fabsf(df), tb = b + b, ab = fabsf(tb);
  float acmx, acmn;
  if (fabsf(a) > fabsf(c)) { acmx = a; acmn = c; } else { acmx = c; acmn = a; }
  float rt;
  if (adf > ab) { float t = ab / adf; rt = adf * sqrtf(1.f + t * t); }
  else if (adf < ab) { float t = adf / ab; rt = ab * sqrtf(1.f + t * t); }
  else rt = ab * sqrtf(2.f);
  int sgn1;
  if (sm < 0.f) { *rt1 = 0.5f * (sm - rt); sgn1 = -1; *rt2 = (acmx / (*rt1)) * acmn - (b / (*rt1)) * b; }
  else if (sm > 0.f) { *rt1 = 0.5f * (sm + rt); sgn1 = 1; *rt2 = (acmx / (*rt1)) * acmn - (b / (*rt1)) * b; }
  else { *rt1 = 0.5f * rt; *rt2 = -0.5f * rt; sgn1 = 1; }
  float cs; int sgn2;
  if (df >= 0.f) { cs = df + rt; sgn2 = 1; } else { cs = df - rt; sgn2 = -1; }
  float acs = fabsf(cs);
  if (acs > ab) {
    float ct = -tb / cs;
    *sn1 = 1.f / sqrtf(1.f + ct * ct);
    *cs1 = ct * (*sn1);
  } else {
    if (ab == 0.f) { *cs1 = 1.f; *sn1 = 0.f; }
    else { float tn = -cs / tb; *cs1 = 1.f / sqrtf(1.f + tn * tn); *sn1 = tn * (*cs1); }
  }
  if (sgn1 == sgn2) { float tn = *cs1; *cs1 = -(*sn1); *sn1 = tn; }
}

// Faithful serial ssteqr('I'), WAVE-PARALLEL + REGISTER-RESIDENT d/e/cw/sw.
// All shfl reads execute with the full wave active (uniform control flow).
#define SDD(i) __shfl(dr, (i))
#define SEE(i) __shfl(er, (i))
__device__ void steqr_reg(float* d, float* e, int n, float* zb, int ldz, int lane) {
  const float eps = EPSF;
  const float eps2 = eps * eps;
  const float safmin = SAFMINF;
  for (int j = 0; j < n; j++)
    for (int i = lane; i < n; i += 64) zb[j * ldz + i] = (i == j) ? 1.f : 0.f;
  if (n <= 1) return;
  float dr = (lane < n) ? d[lane] : 0.f;
  float er = (lane < n - 1) ? e[lane] : 0.f;
  float cwr = 0.f, swr = 0.f;
  int nmaxit = n * 30, jtot = 0;
  int l1 = 1;
  while (true) {
    if (l1 > n) break;
    if (l1 > 1) er = (lane == l1 - 2) ? 0.f : er;
    int m;
    {
      int mm_;
      for (mm_ = l1; mm_ <= n - 1; mm_++) {
        float tst = fabsf(SEE(mm_ - 1));
        if (tst == 0.f) break;
        if (tst <= (sqrtf(fabsf(SDD(mm_ - 1))) * sqrtf(fabsf(SDD(mm_)))) * eps) {
          er = (lane == mm_ - 1) ? 0.f : er;
          break;
        }
      }
      m = mm_;
    }
    int l = l1, lsv = l, lend = m, lendsv = lend;
    l1 = m + 1;
    if (lend == l) continue;
    float anorm = 0.f;
    for (int i = l; i <= lend; i++) anorm = fmaxf(anorm, fabsf(SDD(i - 1)));
    for (int i = l; i <= lend - 1; i++) anorm = fmaxf(anorm, fabsf(SEE(i - 1)));
    if (anorm == 0.f) continue;
    if (fabsf(SDD(lend - 1)) < fabsf(SDD(l - 1))) { lend = lsv; l = lendsv; }
    if (lend > l) {
      // ---- QL ----
      while (true) {
        int m2;
        {
          int i;
          for (i = l; i <= lend - 1; i++) {
            float tst = fabsf(SEE(i - 1)); tst = tst * tst;
            if (tst <= (eps2 * fabsf(SDD(i - 1))) * fabsf(SDD(i)) + safmin) break;
          }
          m2 = i;
        }
        if (m2 < lend) er = (lane == m2 - 1) ? 0.f : er;
        float p = SDD(l - 1);
        if (m2 == l) { dr = (lane == l - 1) ? p : dr; l++; if (l <= lend) continue; else break; }
        if (m2 == l + 1) {
          float rt1, rt2, c_, s_;
          slaev2f(SDD(l - 1), SEE(l - 1), SDD(l), &rt1, &rt2, &c_, &s_);
          for (int i = lane; i < n; i += 64) {
            float t1 = zb[l * ldz + i];
            float t0 = zb[(l - 1) * ldz + i];
            zb[l * ldz + i] = c_ * t1 - s_ * t0;
            zb[(l - 1) * ldz + i] = s_ * t1 + c_ * t0;
          }
          dr = (lane == l - 1) ? rt1 : dr;
          dr = (lane == l) ? rt2 : dr;
          er = (lane == l - 1) ? 0.f : er;
          l += 2; if (l <= lend) continue; else break;
        }
        if (jtot == nmaxit) break;
        jtot++;
        float g = (SDD(l) - p) / (2.f * SEE(l - 1));
        float r = slapy2f(g, 1.f);
        g = SDD(m2 - 1) - p + SEE(l - 1) / (g + copysignf(r, g));
        float s_ = 1.f, c_ = 1.f; p = 0.f;
        for (int i = m2 - 1; i >= l; i--) {
          float ee = SEE(i - 1);
          float f = s_ * ee, b2 = c_ * ee;
          float cc, ss, rr;
          slartgf(g, f, &cc, &ss, &rr);
          c_ = cc; s_ = ss;
          if (i != m2 - 1) er = (lane == i) ? rr : er;
          g = SDD(i) - p;
          rr = (SDD(i - 1) - g) * s_ + 2.f * c_ * b2;
          p = s_ * rr;
          dr = (lane == i) ? (g + p) : dr;
          g = c_ * rr - b2;
          cwr = (lane == (i - l)) ? c_ : cwr;
          swr = (lane == (i - l)) ? (-s_) : swr;
        }
        int mm2 = m2 - l + 1;
        for (int jj = mm2 - 2; jj >= 0; jj--) {
          float ct_ = __shfl(cwr, jj), st_ = __shfl(swr, jj);
          int colj = l - 1 + jj;
          for (int i = lane; i < n; i += 64) {
            float t1 = zb[(colj + 1) * ldz + i];
            float t0 = zb[colj * ldz + i];
            zb[(colj + 1) * ldz + i] = ct_ * t1 - st_ * t0;
            zb[colj * ldz + i] = st_ * t1 + ct_ * t0;
          }
        }
        {
          float nv = SDD(l - 1) - p;
          dr = (lane == l - 1) ? nv : dr;
          er = (lane == l - 1) ? g : er;
        }
      }
    } else {
      // ---- QR ----
      while (true) {
        int m2;
        {
          int i;
          for (i = l; i >= lend + 1; i--) {
            float tst = fabsf(SEE(i - 2)); tst = tst * tst;
            if (tst <= (eps2 * fabsf(SDD(i - 1))) * fabsf(SDD(i - 2)) + safmin) break;
          }
          m2 = i;
        }
        if (m2 > lend) er = (lane == m2 - 2) ? 0.f : er;
        float p = SDD(l - 1);
        if (m2 == l) { dr = (lane == l - 1) ? p : dr; l--; if (l >= lend) continue; else break; }
        if (m2 == l - 1) {
          float rt1, rt2, c_, s_;
          slaev2f(SDD(l - 2), SEE(l - 2), SDD(l - 1), &rt1, &rt2, &c_, &s_);
          for (int i = lane; i < n; i += 64) {
            float t1 = zb[(l - 1) * ldz + i];
            float t0 = zb[(l - 2) * ldz + i];
            zb[(l - 1) * ldz + i] = c_ * t1 - s_ * t0;
            zb[(l - 2) * ldz + i] = s_ * t1 + c_ * t0;
          }
          dr = (lane == l - 2) ? rt1 : dr;
          dr = (lane == l - 1) ? rt2 : dr;
          er = (lane == l - 2) ? 0.f : er;
          l -= 2; if (l >= lend) continue; else break;
        }
        if (jtot == nmaxit) break;
        jtot++;
        float g = (SDD(l - 2) - p) / (2.f * SEE(l - 2));
        float r = slapy2f(g, 1.f);
        g = SDD(m2 - 1) - p + SEE(l - 2) / (g + copysignf(r, g));
        float s_ = 1.f, c_ = 1.f; p = 0.f;
        for (int i = m2; i <= l - 1; i++) {
          float ee = SEE(i - 1);
          float f = s_ * ee, b2 = c_ * ee;
          float cc, ss, rr;
          slartgf(g, f, &cc, &ss, &rr);
          c_ = cc; s_ = ss;
          if (i != m2) er = (lane == i - 2) ? rr : er;
          g = SDD(i - 1) - p;
          rr = (SDD(i) - g) * s_ + 2.f * c_ * b2;
          p = s_ * rr;
          dr = (lane == i - 1) ? (g + p) : dr;
          g = c_ * rr - b2;
          cwr = (lane == (i - m2)) ? c_ : cwr;
          swr = (lane == (i - m2)) ? s_ : swr;
        }
        int mm2 = l - m2 + 1;
        for (int jj = 0; jj <= mm2 - 2; jj++) {
          float ct_ = __shfl(cwr, jj), st_ = __shfl(swr, jj);
          int colj = m2 - 1 + jj;
          for (int i = lane; i < n; i += 64) {
            float t1 = zb[(colj + 1) * ldz + i];
            float t0 = zb[colj * ldz + i];
            zb[(colj + 1) * ldz + i] = ct_ * t1 - st_ * t0;
            zb[colj * ldz + i] = st_ * t1 + ct_ * t0;
          }
        }
        {
          float nv = SDD(l - 1) - p;
          dr = (lane == l - 1) ? nv : dr;
          er = (lane == l - 2) ? g : er;
        }
      }
    }
  }
  for (int ii = 2; ii <= n; ii++) {
    int i = ii - 1, k = i;
    float p = SDD(i - 1);
    for (int j = ii; j <= n; j++) {
      float dj = SDD(j - 1);
      if (dj < p) { k = j; p = dj; }
    }
    if (k != i) {
      float old = SDD(i - 1);
      dr = (lane == k - 1) ? old : dr;
      dr = (lane == i - 1) ? p : dr;
      for (int r = lane; r < n; r += 64) {
        float t5 = zb[(i - 1) * ldz + r];
        zb[(i - 1) * ldz + r] = zb[(k - 1) * ldz + r];
        zb[(k - 1) * ldz + r] = t5;
      }
    }
  }
  if (lane < n) d[lane] = dr;
  if (lane < n - 1) e[lane] = er;
}

// ======================= f32 D&C merge, MULTI-GROUP (slaed1/2/3 semantics) ===
// Round-5-verified serial slaed2 (gtid==0); Sm now in LDS (stride LDS_SM).

__device__ void laed1_multi(float* d, float* e, float* Qm, float* Q2b, float* Smb,
                            float* zv, float* dl, float* wv, float* wg, float* pvf,
                            float* dvf, int* srcx, int* dsrc, int* iq,
                            int goff, const int* iwps, int p0, int G,
                            int tid, int* shi, float* shdf,
                            double* sdl, double* spv, int* defcnt) {
  int Tg = THREADS / G;
  int g = tid / Tg, gtid = tid - g * Tg;
  int pg = 2 * (p0 + g);
  int prev = (pg == 0) ? 0 : iwps[pg - 1];
  int off = goff + prev;
  int n = iwps[pg + 1] - prev;
  int n1 = (pg == 0) ? iwps[0] : (n / 2);
  int n2 = n - n1;
  float rho_in = e[off + n1 - 1];
  float* dg = d + off;
  float* zvg = zv + off;  float* dlg = dl + off;  float* wvg = wv + off;
  float* wgg = wg + off;  float* pvfg = pvf + off; float* dvfg = dvf + off;
  int* srcxg = srcx + off; int* dsrcg = dsrc + off; int* iqg = iq + off;
  double* sdlg = sdl + off; double* spvg = spv + off;
  float* Q2g = Q2b + (size_t)off * 128;
  float* Smg = Smb + (size_t)off * LDS_SM + off;

  for (int t = gtid; t < n1; t += Tg) zvg[t] = Qm[(off + t) * LDQ + off + n1 - 1];
  for (int t = gtid; t < n2; t += Tg) zvg[n1 + t] = Qm[(off + n1 + t) * LDQ + off + n1];
  __syncthreads();                                   // B1
  if (gtid == 0) {
    float rho = rho_in;
    if (rho < 0.f) for (int t = n1; t < n; t++) zvg[t] = -zvg[t];
    float tsc = 1.0f / sqrtf(2.0f);
    for (int t = 0; t < n; t++) zvg[t] *= tsc;
    rho = fabsf(2.0f * rho);
    {
      int i = 0, j = n1, p = 0;
      while (i < n1 && j < n) {
        if (dg[i] <= dg[j]) srcxg[p++] = i++; else srcxg[p++] = j++;
      }
      while (i < n1) srcxg[p++] = i++;
      while (j < n) srcxg[p++] = j++;
    }
    int imax = 0, jmax = 0;
    for (int t = 1; t < n; t++) if (fabsf(zvg[t]) > fabsf(zvg[imax])) imax = t;
    for (int t = 1; t < n; t++) if (fabsf(dg[t]) > fabsf(dg[jmax])) jmax = t;
    float tol = 8.0f * EPSF * fmaxf(fabsf(dg[jmax]), fabsf(zvg[imax]));
    int k = 0, nd = 0;
    if (rho * fabsf(zvg[imax]) <= tol) {
      for (int t = 0; t < n; t++) { dsrcg[nd] = srcxg[t]; dvfg[nd] = dg[srcxg[t]]; nd++; }
    } else {
      int pj = -1;
      for (int jj = 0; jj < n; jj++) {
        int nj = srcxg[jj];
        if (rho * fabsf(zvg[nj]) <= tol) {
          dsrcg[nd] = nj; dvfg[nd] = dg[nj]; nd++;
        } else if (pj < 0) {
          pj = nj;
        } else {
          float s_ = zvg[pj], c_ = zvg[nj];
          float tau_ = slapy2f(c_, s_);
          float t3 = dg[nj] - dg[pj];
          c_ /= tau_; s_ = -s_ / tau_;
          if (fabsf(t3 * c_ * s_) <= tol) {
            zvg[nj] = tau_; zvg[pj] = 0.f;
            for (int r = 0; r < n; r++) {
              float x_ = Qm[(off + pj) * LDQ + off + r];
              float y_ = Qm[(off + nj) * LDQ + off + r];
              Qm[(off + pj) * LDQ + off + r] = c_ * x_ + s_ * y_;
              Qm[(off + nj) * LDQ + off + r] = c_ * y_ - s_ * x_;
            }
            float dp = dg[pj], dn = dg[nj];
            dg[nj] = dp * s_ * s_ + dn * c_ * c_;
            dg[pj] = dp * c_ * c_ + dn * s_ * s_;
            dsrcg[nd] = pj; dvfg[nd] = dg[pj]; nd++;
            pj = nj;
          } else {
            dlg[k] = dg[pj]; wvg[k] = zvg[pj]; srcxg[k] = pj; k++;
            pj = nj;
          }
        }
      }
      if (pj >= 0) { dlg[k] = dg[pj]; wvg[k] = zvg[pj]; srcxg[k] = pj; k++; }
    }
    shi[200 + g] = k; shi[208 + g] = nd; shdf[8 + g] = rho;
    if (nd > 0) atomicAdd(defcnt, nd);
  }
  __syncthreads();                                   // B2
  int k = shi[200 + g], nd = shi[208 + g];
  float rho = shdf[8 + g];
  if (k > 1) {
    for (int t = gtid; t < k; t += Tg) {
      sdlg[t] = (double)dlg[t];
      spvg[t] = (double)rho * (double)wvg[t] * (double)wvg[t];
    }
  }
  __syncthreads();                                   // B3
  // secular roots in f64: bracket-safeguarded Newton (monotone f)
  if (k > 1 && gtid < k) {
    int j = gtid;
    double lo = 0.0, hi;
    if (j == k - 1) {
      double sw2 = 0.0;
      for (int t = 0; t < k; t++) sw2 += spvg[t];
      hi = sw2;
      for (int g2 = 0; g2 < 8; g2++) {
        double f = 1.0;
        for (int t = 0; t < k; t++) f += spvg[t] / ((sdlg[t] - sdlg[j]) - hi);
        if (f >= 0.0) break;
        hi *= 2.0;
      }
    } else hi = sdlg[j + 1] - sdlg[j];
    double gap = hi;
    double x = 0.5 * (lo + hi);
    for (int it = 0; it < 60; it++) {
      double f = 1.0, fp = 0.0;
      for (int t = 0; t < k; t++) {
        double inv = 1.0 / ((sdlg[t] - sdlg[j]) - x);
        double u = spvg[t] * inv;
        f += u; fp += u * inv;
      }
      if (f < 0.0) lo = x; else hi = x;
      double xn = x - f / fp;
      if (!(xn > lo && xn < hi)) xn = 0.5 * (lo + hi);
      if (xn == x) break;
      x = xn;
    }
    double eta = x;
    if (eta <= 0.0) eta = gap * 1e-30;
    if (j < k - 1 && eta >= gap) eta = gap * (1.0 - 1e-15);
    dg[j] = (float)(sdlg[j] + eta);
    for (int t = 0; t < k; t++)
      Smg[t * LDS_SM + j] = (float)((sdlg[t] - sdlg[j]) - eta);
  }
  __syncthreads();                                   // B4
  // Gu-Eisenstat reweighting (f32, as slaed3)
  if (k > 1 && gtid < k) {
    int i = gtid;
    float acc = Smg[i * LDS_SM + i];
    for (int j = 0; j < k; j++) {
      if (j == i) continue;
      acc *= Smg[i * LDS_SM + j] / (dlg[i] - dlg[j]);
    }
    wgg[i] = copysignf(sqrtf(fmaxf(-acc, 0.f)), wvg[i]);
  }
  __syncthreads();                                   // B5
  // secular vectors + positive normalization (thread j, exact order)
  if (k > 1 && gtid < k) {
    int j = gtid;
    float nrm2 = 0.f;
    for (int i = 0; i < k; i++) {
      float u = wgg[i] / Smg[i * LDS_SM + j];
      Smg[i * LDS_SM + j] = u;
      nrm2 += u * u;
    }
    float nrm = sqrtf(nrm2);
    for (int i = 0; i < k; i++) Smg[i * LDS_SM + j] /= nrm;
  }
  __syncthreads();                                   // B6
  if (k > 1) {
    // gather Q2g[j][r] = sum_i Qm[off+srcxg[i]][off+r] * Smg[i][j]
    int j = gtid & 127, rg = gtid >> 7;
    int RG = Tg >> 7; if (RG < 1) RG = 1;
    if (j < k) {
      int chunk = (n + RG - 1) / RG;
      int rbeg = rg * chunk, rend = rbeg + chunk;
      if (rend > n) rend = n;
      int r0 = rbeg;
      for (; r0 + 8 <= rend; r0 += 8) {
        float a0 = 0.f, a1 = 0.f, a2 = 0.f, a3 = 0.f;
        float a4 = 0.f, a5 = 0.f, a6 = 0.f, a7 = 0.f;
        for (int i = 0; i < k; i++) {
          float s = Smg[i * LDS_SM + j];
          const float* q = &Qm[(off + srcxg[i]) * LDQ + off + r0];
          a0 += q[0] * s; a1 += q[1] * s; a2 += q[2] * s; a3 += q[3] * s;
          a4 += q[4] * s; a5 += q[5] * s; a6 += q[6] * s; a7 += q[7] * s;
        }
        float* o = &Q2g[j * 128 + r0];
        o[0] = a0; o[1] = a1; o[2] = a2; o[3] = a3;
        o[4] = a4; o[5] = a5; o[6] = a6; o[7] = a7;
      }
      for (; r0 < rend; r0++) {
        float a = 0.f;
        for (int i = 0; i < k; i++)
          a += Qm[(off + srcxg[i]) * LDQ + off + r0] * Smg[i * LDS_SM + j];
        Q2g[j * 128 + r0] = a;
      }
    }
  } else if (k == 1 && gtid == 0) {
    zvg[0] = dlg[0] + rho * (wvg[0] * wvg[0]);
    for (int r = 0; r < n; r++) Q2g[r] = Qm[(off + srcxg[0]) * LDQ + off + r];
  }
  __syncthreads();                                   // B7
  if (k > 1 && gtid < k) zvg[gtid] = dg[gtid];
  __syncthreads();                                   // B8
  for (int t2 = gtid; t2 < nd; t2 += Tg)
    for (int r = 0; r < n; r++) Q2g[(k + t2) * 128 + r] = Qm[(off + dsrcg[t2]) * LDQ + off + r];
  for (int j = gtid; j < n; j += Tg) pvfg[j] = (j < k) ? zvg[j] : dvfg[j - k];
  __syncthreads();                                   // B9
  // ascending sort: parallel stable rank (ties by original index)
  for (int j = gtid; j < n; j += Tg) {
    float kj = pvfg[j];
    int r = 0;
    for (int i = 0; i < n; i++) {
      float ki = pvfg[i];
      if (ki < kj || (ki == kj && i < j)) r++;
    }
    iqg[r] = j;
  }
  __syncthreads();                                   // B10
  {
    int j = gtid & 127, rg = gtid >> 7;
    int RG = Tg >> 7; if (RG < 1) RG = 1;
    if (j < n) {
      int s2 = iqg[j];
      if (rg == 0) dg[j] = pvfg[s2];
      int chunk = (n + RG - 1) / RG;
      int rbeg = rg * chunk, rend = rbeg + chunk;
      if (rend > n) rend = n;
      for (int r = rbeg; r < rend; r++) Qm[(off + j) * LDQ + off + r] = Q2g[s2 * 128 + r];
    }
  }
  __syncthreads();                                   // B11
}

// ======================= eig P1: ssytd2 tridiagonalization =======================

__global__ __launch_bounds__(THREADS) void eig_p1_kernel(const float* __restrict__ covB,
                                                         float* __restrict__ Aout,
                                                         float* __restrict__ vecs) {
  int b = blockIdx.x, tid = threadIdx.x;
  const float* Cg = covB + (size_t)b * 16384;
  float* Ag = Aout + (size_t)b * 16384;
  __shared__ float As[16384];
  __shared__ float sh_e[128], sh_tau[128], sh_pvf[128];
  __shared__ float redf[128];
  __shared__ float shdf[4];
  float* A = As; float* e = sh_e; float* tauv = sh_tau; float* pvf = sh_pvf;

  for (int idx = tid; idx < 16384; idx += THREADS) As[idx] = Cg[idx];
  if (tid < 128) { sh_e[tid] = 0.f; sh_tau[tid] = 0.f; }
  __syncthreads();

  for (int i1 = 1; i1 <= NC - 1; i1++) {
    int ii = i1 - 1;
    int mlen = NC - i1;
    float ps = 0.f;
    if (tid < 128) {
      for (int t = tid; t < mlen - 1; t += 128) {
        float v = A[ii * 128 + ii + 2 + t];
        ps += v * v;
      }
      redf[tid] = ps;
    }
    __syncthreads();                               // B1
    if (tid < 64) {
      float a = redf[tid] + redf[tid + 64];
      a += __shfl_xor(a, 32); a += __shfl_xor(a, 16); a += __shfl_xor(a, 8);
      a += __shfl_xor(a, 4);  a += __shfl_xor(a, 2);  a += __shfl_xor(a, 1);
      if (tid == 0) {
        float xnorm = sqrtf(a);
        float alpha = A[ii * 128 + ii + 1];
        float taui, ei, scl;
        if (xnorm == 0.f) { taui = 0.f; ei = alpha; scl = 0.f; }
        else {
          float beta = -copysignf(slapy2f(alpha, xnorm), alpha);
          taui = (beta - alpha) / beta;
          scl = 1.f / (alpha - beta);
          ei = beta;
        }
        e[ii] = ei; tauv[ii] = taui; shdf[2] = scl;
      }
    }
    __syncthreads();                               // B2
    float taui = tauv[ii];
    if (taui != 0.f) {
      float scl = shdf[2];
      for (int t = tid; t < mlen - 1; t += 128) A[ii * 128 + ii + 2 + t] *= scl;
      __syncthreads();                             // B3
      for (int r = tid; r < mlen; r += 128) {
        float acc = 0.f;
        int row = ii + 1 + r;
        acc += A[(ii + 1) * 128 + row];            // s=0 term, v0 == 1
        for (int s = 1; s < mlen; s++) acc += A[(ii + 1 + s) * 128 + row] * A[ii * 128 + ii + 1 + s];
        pvf[r] = taui * acc;
      }
      __syncthreads();                             // B4
      if (tid < 128) {
        float pd = 0.f;
        for (int t = tid; t < mlen; t += 128) {
          float vt = (t == 0) ? 1.f : A[ii * 128 + ii + 1 + t];
          pd += pvf[t] * vt;
        }
        redf[tid] = pd;
      }
      __syncthreads();                             // B5
      if (tid < 64) {
        float a = redf[tid] + redf[tid + 64];
        a += __shfl_xor(a, 32); a += __shfl_xor(a, 16); a += __shfl_xor(a, 8);
        a += __shfl_xor(a, 4);  a += __shfl_xor(a, 2);  a += __shfl_xor(a, 1);
        if (tid == 0) shdf[3] = -0.5f * taui * a;
      }
      __syncthreads();                             // B6
      float alpha2 = shdf[3];
      for (int t = tid; t < mlen; t += 128) {
        float vt = (t == 0) ? 1.f : A[ii * 128 + ii + 1 + t];
        pvf[t] += alpha2 * vt;
      }
      __syncthreads();                             // B7
      if ((tid & 127) < mlen) {
        int r = tid & 127, g = tid >> 7;
        int chunk = (mlen + 3) >> 2;
        int cb = g * chunk, ce = cb + chunk;
        if (ce > mlen) ce = mlen;
        float vr = (r == 0) ? 1.f : A[ii * 128 + ii + 1 + r];
        float pr = pvf[r];
        for (int c2 = cb; c2 < ce; c2++) {
          float vc = (c2 == 0) ? 1.f : A[ii * 128 + ii + 1 + c2];
          A[(ii + 1 + c2) * 128 + (ii + 1 + r)] -= vr * pvf[c2] + pr * vc;
        }
      }
      __syncthreads();                             // B8
    }
  }
  for (int idx = tid; idx < 16384; idx += THREADS) Ag[idx] = As[idx];
  if (tid < 128) {
    vecs[b * 128 + tid] = As[tid * 128 + tid];      // d = diag(A)
    vecs[2048 + b * 128 + tid] = sh_e[tid];
    vecs[4096 + b * 128 + tid] = sh_tau[tid];
  }
}

// ======================= eig P2a: split detect + scale + tear + leaves =======================

__global__ __launch_bounds__(THREADS) void eig_p2a_kernel(float* __restrict__ Qw,
                                                          float* __restrict__ vecs) {
  int b = blockIdx.x, tid = threadIdx.x;
  float* Qg = Qw + (size_t)b * 16384;
  __shared__ float Qs[128 * LDQ];
  __shared__ float sh_d[128], sh_e[128];
  __shared__ int iwps[64];
  __shared__ float shdf[16];
  __shared__ int shi[280];
  float* Qm = Qs; float* d = sh_d; float* e = sh_e;
  int* meta = (int*)(vecs + 6144) + b * 320;
  float* onrmv = vecs + 11264 + b * 128;

  if (tid < 128) { sh_d[tid] = vecs[b * 128 + tid]; sh_e[tid] = vecs[2048 + b * 128 + tid]; }
  for (int idx = tid; idx < 16384; idx += THREADS) {
    int c = idx >> 7, r = idx & 127;
    Qs[c * LDQ + r] = (c == r) ? 1.f : 0.f;
  }
  __syncthreads();
  if (tid == 0) {
    int ns = 0, start = 0;
    while (start < NC) {
      int fin = start;
      while (fin < NC - 1) {
        float tiny = EPSF * sqrtf(fabsf(d[fin])) * sqrtf(fabsf(d[fin + 1]));
        if (fabsf(e[fin]) > tiny) fin++;
        else break;
      }
      shi[2 + 2 * ns] = start; shi[3 + 2 * ns] = fin - start + 1; ns++;
      start = fin + 1;
    }
    shi[0] = ns;
    meta[0] = ns;
    for (int s = 0; s < ns; s++) { meta[1 + 2 * s] = shi[2 + 2 * s]; meta[2 + 2 * s] = shi[3 + 2 * s]; }
  }
  __syncthreads();
  int nsplit = shi[0];
  for (int sb = 0; sb < nsplit; sb++) {
    int goff = shi[2 + 2 * sb], m = shi[3 + 2 * sb];
    if (m == 1) { if (tid == 0) onrmv[sb] = 0.f; continue; }
    if (m <= SMLSIZ) {
      if (tid == 0) onrmv[sb] = 0.f;
      if (tid < 64) steqr_reg(d + goff, e + goff, m, Qm + goff * LDQ + goff, LDQ, tid);
      __syncthreads();
    } else {
      if (tid == 0) {
        float mx = 0.f;
        for (int i = 0; i < m; i++) mx = fmaxf(mx, fabsf(d[goff + i]));
        for (int i = 0; i < m - 1; i++) mx = fmaxf(mx, fabsf(e[goff + i]));
        shdf[0] = mx;
        onrmv[sb] = mx;
      }
      __syncthreads();
      float onrm = shdf[0];
      if (onrm != 0.f) {
        float mul = 1.f / onrm;
        for (int t = tid; t < m; t += 128) d[goff + t] *= mul;
        for (int t = tid; t < m - 1; t += 128) e[goff + t] *= mul;
        __syncthreads();
        if (tid == 0) {
          iwps[0] = m; int sp = 1;
          while (iwps[sp - 1] > SMLSIZ) {
            for (int j = sp - 1; j >= 0; j--) { iwps[2 * j + 1] = (iwps[j] + 1) / 2; iwps[2 * j] = iwps[j] / 2; }
            sp *= 2;
          }
          for (int j = 1; j < sp; j++) iwps[j] += iwps[j - 1];
          shi[134] = sp;
          for (int i = 0; i < sp - 1; i++) {
            int bnd = goff + iwps[i];
            d[bnd - 1] -= fabsf(e[bnd - 1]);
            d[bnd] -= fabsf(e[bnd - 1]);
          }
        }
        __syncthreads();
        int subpbs = shi[134];
        {
          int lw = tid >> 6;
          if (lw < subpbs) {
            int boff = goff + (lw == 0 ? 0 : iwps[lw - 1]);
            int bm = iwps[lw] - (lw == 0 ? 0 : iwps[lw - 1]);
            steqr_reg(d + boff, e + boff, bm, Qm + boff * LDQ + boff, LDQ, tid & 63);
          }
        }
        __syncthreads();
      }
    }
  }
  if (tid < 128) { vecs[b * 128 + tid] = sh_d[tid]; vecs[2048 + b * 128 + tid] = sh_e[tid]; }
  for (int idx = tid; idx < 16384; idx += THREADS) {
    int c = idx >> 7, r = idx & 127;
    Qg[idx] = Qs[c * LDQ + r];
  }
}

// ======================= eig P2b: merge levels until 2 remain =======================

__global__ __launch_bounds__(THREADS) void eig_p2b_kernel(float* __restrict__ Qw,
                                                          float* Q2w, float* vecs, int* defcnt) {
  int b = blockIdx.x, tid = threadIdx.x;
  float* Qg = Qw + (size_t)b * 16384;
  float* Q2 = Q2w + (size_t)b * 16640;
  __shared__ float Qs[128 * LDQ];
  __shared__ float Sms[128 * LDS_SM];
  __shared__ float sh_d[128], sh_e[128], sh_zv[128], sh_dl[128];
  __shared__ float sh_wv[128], sh_wg[128], sh_pvf[128], sh_dvf[128];
  __shared__ int sh_iq[128], sh_srcx[128], sh_dsrc[128];
  __shared__ int iwps[64];
  __shared__ float shdf[16];
  __shared__ int shi[280];
  __shared__ double sdl[128];
  __shared__ double spv[128];
  float* Qm = Qs;
  int* meta = (int*)(vecs + 6144) + b * 320;
  float* onrmv = vecs + 11264 + b * 128;

  if (tid < 128) { sh_d[tid] = vecs[b * 128 + tid]; sh_e[tid] = vecs[2048 + b * 128 + tid]; }
  for (int idx = tid; idx < 16384; idx += THREADS) {
    int c = idx >> 7, r = idx & 127;
    Qs[c * LDQ + r] = Qg[idx];
  }
  __syncthreads();
  int nsplit = meta[0];
  for (int sb = 0; sb < nsplit; sb++) {
    int goff = meta[1 + 2 * sb], m = meta[2 + 2 * sb];
    float onrm = onrmv[sb];
    if (onrm == 0.f || m <= SMLSIZ) continue;
    if (tid == 0) {
      iwps[0] = m; int sp = 1;
      while (iwps[sp - 1] > SMLSIZ) {
        for (int j = sp - 1; j >= 0; j--) { iwps[2 * j + 1] = (iwps[j] + 1) / 2; iwps[2 * j] = iwps[j] / 2; }
        sp *= 2;
      }
      for (int j = 1; j < sp; j++) iwps[j] += iwps[j - 1];
      shi[134] = sp;
    }
    __syncthreads();
    int cur = shi[134];
    while (cur > 2) {
      int nm = cur >> 1;
      for (int p0 = 0; p0 < nm; ) {
        int G = (nm - p0 >= 4) ? 4 : ((nm - p0 >= 2) ? 2 : 1);
        laed1_multi(sh_d, sh_e, Qm, Q2, Sms, sh_zv, sh_dl, sh_wv, sh_wg, sh_pvf, sh_dvf,
                    sh_srcx, sh_dsrc, sh_iq, goff, iwps, p0, G, tid, shi, shdf, sdl, spv, defcnt);
        p0 += G;
      }
      if (tid == 0) for (int t = 0; 2 * t + 1 < cur; t++) iwps[t] = iwps[2 * t + 1];
      __syncthreads();
      cur >>= 1;
    }
  }
  if (tid < 128) vecs[b * 128 + tid] = sh_d[tid];
  for (int idx = tid; idx < 16384; idx += THREADS) {
    int c = idx >> 7, r = idx & 127;
    Qg[idx] = Qs[c * LDQ + r];
  }
}

// ======================= eig P2c: final merge + unscale + global sort =======================

__global__ __launch_bounds__(THREADS) void eig_p2c_kernel(float* __restrict__ Qw,
                                                          float* Q2w, float* vecs, int* defcnt) {
  int b = blockIdx.x, tid = threadIdx.x;
  float* Qg = Qw + (size_t)b * 16384;
  float* Q2 = Q2w + (size_t)b * 16640;
  __shared__ float Qs[128 * LDQ];
  __shared__ float Sms[128 * LDS_SM];
  __shared__ float sh_d[128], sh_e[128], sh_zv[128], sh_dl[128];
  __shared__ float sh_wv[128], sh_wg[128], sh_pvf[128], sh_dvf[128];
  __shared__ int sh_iq[128], sh_srcx[128], sh_dsrc[128];
  __shared__ int iwps[64];
  __shared__ float shdf[16];
  __shared__ int shi[280];
  __shared__ double sdl[128];
  __shared__ double spv[128];
  float* Qm = Qs; float* d = sh_d; float* zv = sh_zv;
  int* meta = (int*)(vecs + 6144) + b * 320;
  float* onrmv = vecs + 11264 + b * 128;

  if (tid < 128) { sh_d[tid] = vecs[b * 128 + tid]; sh_e[tid] = vecs[2048 + b * 128 + tid]; }
  for (int idx = tid; idx < 16384; idx += THREADS) {
    int c = idx >> 7, r = idx & 127;
    Qs[c * LDQ + r] = Qg[idx];
  }
  __syncthreads();
  int nsplit = meta[0];
  for (int sb = 0; sb < nsplit; sb++) {
    int goff = meta[1 + 2 * sb], m = meta[2 + 2 * sb];
    float onrm = onrmv[sb];
    if (onrm == 0.f || m <= SMLSIZ) continue;
    if (tid == 0) {
      iwps[0] = m; int sp = 1;
      while (iwps[sp - 1] > SMLSIZ) {
        for (int j = sp - 1; j >= 0; j--) { iwps[2 * j + 1] = (iwps[j] + 1) / 2; iwps[2 * j] = iwps[j] / 2; }
        sp *= 2;
      }
      for (int j = 1; j < sp; j++) iwps[j] += iwps[j - 1];
      shi[134] = sp;
    }
    __syncthreads();
    int cur = shi[134];
    while (cur > 2) {              // replay p2b's collapses (no merging)
      if (tid == 0) for (int t = 0; 2 * t + 1 < cur; t++) iwps[t] = iwps[2 * t + 1];
      __syncthreads();
      cur >>= 1;
    }
    // final merge (cur == 2)
    laed1_multi(sh_d, sh_e, Qm, Q2, Sms, sh_zv, sh_dl, sh_wv, sh_wg, sh_pvf, sh_dvf,
                sh_srcx, sh_dsrc, sh_iq, goff, iwps, 0, 1, tid, shi, shdf, sdl, spv, defcnt);
    for (int t = tid; t < m; t += 128) d[goff + t] *= onrm;
    __syncthreads();
  }
  // final eigen d-sort: parallel stable rank (ties by original column index)
  if (tid < 128) {
    float kj = d[tid];
    int r = 0;
    for (int i = 0; i < 128; i++) {
      float ki = d[i];
      if (ki < kj || (ki == kj && i < tid)) r++;
    }
    shi[140 + r] = tid;
    zv[r] = kj;
  }
  __syncthreads();
  if (tid < 128) d[tid] = zv[tid];
  __syncthreads();
  {
    int j = tid & 127, g = tid >> 7;
    int rbeg = g * 32, rend = rbeg + 32;
    int src = shi[140 + j];
    for (int r = rbeg; r < rend; r++) Q2[j * 128 + r] = Qm[src * LDQ + r];
  }
  __syncthreads();
  {
    int j = tid & 127, g = tid >> 7;
    int rbeg = g * 32, rend = rbeg + 32;
    for (int r = rbeg; r < rend; r++) Qm[j * LDQ + r] = Q2[j * 128 + r];
  }
  __syncthreads();
  for (int idx = tid; idx < 16384; idx += THREADS) {
    int c = idx >> 7, r = idx & 127;
    Qg[idx] = Qs[c * LDQ + r];
  }
  if (tid < 128) vecs[b * 128 + tid] = d[tid];
}

// ======================= eig P3: sormtr + top-64 extract =======================

__global__ __launch_bounds__(THREADS) void eig_p3_kernel(const float* __restrict__ Ain,
                                                         const float* __restrict__ vecs,
                                                         float* __restrict__ Qw,
                                                         float* __restrict__ Vw) {
  int b = blockIdx.x, tid = threadIdx.x;
  const float* Ag = Ain + (size_t)b * 16384;
  float* Qg = Qw + (size_t)b * 16384;
  __shared__ float As[16384];
  __shared__ float Qs[128 * LDQ];
  __shared__ float sh_tau[128];
  float* A = As; float* Qm = Qs; float* tauv = sh_tau;

  for (int idx = tid; idx < 16384; idx += THREADS) As[idx] = Ag[idx];
  for (int idx = tid; idx < 16384; idx += THREADS) {
    int c = idx >> 7, r = idx & 127;
    Qs[c * LDQ + r] = Qg[idx];
  }
  if (tid < 128) sh_tau[tid] = vecs[4096 + b * 128 + tid];
  __syncthreads();

  for (int j1 = NC - 1; j1 >= 1; j1--) {
    int jj = j1 - 1;
    float tj = tauv[jj];
    if (tj != 0.f) {
      if (tid < NC) {
        int col = tid;
        float s = Qm[col * LDQ + jj + 1];
        for (int r = jj + 2; r < NC; r++) s += A[jj * 128 + r] * Qm[col * LDQ + r];
        s *= tj;
        Qm[col * LDQ + jj + 1] -= s;
        for (int r = jj + 2; r < NC; r++) Qm[col * LDQ + r] -= s * A[jj * 128 + r];
      }
    }
  }
  __syncthreads();

  for (int idx = tid; idx < NC * KTOP; idx += THREADS) {
    int c2 = idx / KTOP, kk = idx % KTOP;
    Vw[(size_t)b * (NC * KTOP) + idx] = Qm[(127 - kk) * LDQ + c2];
  }
  for (int idx = tid; idx < 16384; idx += THREADS) {
    int c = idx >> 7, r = idx & 127;
    Qg[idx] = Qs[c * LDQ + r];
  }
}

// ======================= diagnostics =======================

__global__ void zeroi_kernel(int* p) { p[0] = 0; p[1] = 0; }

__global__ __launch_bounds__(128) void diag_kernel(const float* __restrict__ covB,
                                                   const float* __restrict__ Qw,
                                                   const float* __restrict__ vecs,
                                                   const float* __restrict__ Vw, int* dcode) {
  int b = blockIdx.x, tid = threadIdx.x;
  const float* C = covB + (size_t)b * 16384;
  const float* Qm = Qw + (size_t)b * 16384;
  const float* d = vecs + b * 128;
  int flags = 0;
  double rmax = 0.0;
  for (int k = 64; k < 128; k++) {
    double lam = (double)d[k];
    double acc = 0.0;
    for (int j = 0; j < 128; j++) acc += (double)C[j * 128 + tid] * (double)Qm[k * 128 + j];
    acc -= lam * (double)Qm[k * 128 + tid];
    rmax = fmax(rmax, fabs(acc));
  }
  if (rmax > 1e-3) flags |= 1;
  double omax = 0.0;
  for (int p = tid; p < 64 * 64; p += 128) {
    int i = 64 + p / 64, j = 64 + p % 64;
    if (j < i) continue;
    double s = 0.0;
    for (int r = 0; r < 128; r++) s += (double)Qm[i * 128 + r] * (double)Qm[j * 128 + r];
    if (i == j) s -= 1.0;
    omax = fmax(omax, fabs(s));
  }
  if (omax > 1e-3) flags |= 2;
  if (tid < 127 && d[tid + 1] < d[tid] - 1e-5f) flags |= 4;
  for (int idx = tid; idx < 8192; idx += 128) {
    int c2 = idx / 64, kk = idx % 64;
    if (Vw[(size_t)b * 8192 + idx] != Qm[(127 - kk) * 128 + c2]) flags |= 8;
  }
  if (tid == 0) {
    for (int k = 64; k < 128; k++) if (!(d[k] > 0.2f && d[k] < 5.0f)) flags |= 16;
    float s = 0.f;
    for (int c = 0; c < 128; c++) { float v = Vw[(size_t)b * 8192 + c * 64]; s += v * v; }
    if (fabsf(s - 1.f) > 1e-2f) flags |= 32;
  }
  if (flags) atomicOr(dcode, flags);
}

__global__ void emit_kernel(const int* dcode, float* out) {
  int f = dcode[0];
  if (f) {
    int code = 1000;
    if (f & 1) code += 400;
    if (f & 2) code += 200;
    if (f & 4) code += 100;
    if (f & 8) code += 40;
    if (f & 16) code += 20;
    if (f & 32) code += 10;
    int nd = dcode[1]; if (nd > 9) nd = 9;
    code += nd;
    out[0] = (float)code;
  }
}

// ======================= numpy-f32-mirror mean / cov =======================

__global__ __launch_bounds__(128) void mean_np_kernel(const float* __restrict__ x,
                                                      float* __restrict__ mean32) {
  int b = blockIdx.x, c = threadIdx.x;
  const float* xb = x + (size_t)b * 2097152;
  float s = 0.0f;
#pragma unroll 64
  for (int n = 0; n < 16384; n++) s = __fadd_rn(s, xb[n * 128 + c]);
  mean32[b * 128 + c] = s / 16384.0f;
}

__global__ __launch_bounds__(256) void covnp_kernel(const float* __restrict__ x,
                                                    const float* __restrict__ mean32,
                                                    float* __restrict__ S) {
  int b = blockIdx.x;
  int p = blockIdx.y;
  int ti4, tj4;
  if (p < 4) { ti4 = 0; tj4 = p; }
  else if (p < 7) { ti4 = 1; tj4 = p - 3; }
  else if (p < 9) { ti4 = 2; tj4 = p - 5; }
  else { ti4 = 3; tj4 = 3; }
  int ti = ti4 * 32, tj = tj4 * 32;
  __shared__ float XI[32 * 66], XJ[32 * 66];
  int tid = threadIdx.x;
  int ci = 2 * (tid & 15), dj = 2 * (tid >> 4);
  float a00 = 0.f, a01 = 0.f, a10 = 0.f, a11 = 0.f;
  const float* xb = x + (size_t)b * 2097152;
  const float* mb = mean32 + b * 128;
  for (int n0 = 0; n0 < 16384; n0 += 64) {
    __syncthreads();
    for (int l = tid; l < 2048; l += 256) {
      int n = l >> 5, cc = l & 31;
      XI[cc * 66 + n] = __fsub_rn(xb[(n0 + n) * 128 + ti + cc], mb[ti + cc]);
      XJ[cc * 66 + n] = __fsub_rn(xb[(n0 + n) * 128 + tj + cc], mb[tj + cc]);
    }
    __syncthreads();
    const float2* pi0 = (const float2*)&XI[ci * 66];
    const float2* pi1 = (const float2*)&XI[(ci + 1) * 66];
    const float2* pj0 = (const float2*)&XJ[dj * 66];
    const float2* pj1 = (const float2*)&XJ[(dj + 1) * 66];
    for (int n2 = 0; n2 < 32; n2++) {
      float2 xi0 = pi0[n2], xi1 = pi1[n2], xj0 = pj0[n2], xj1 = pj1[n2];
      a00 = __fadd_rn(a00, __fmul_rn(xi0.x, xj0.x));
      a01 = __fadd_rn(a01, __fmul_rn(xi0.x, xj1.x));
      a10 = __fadd_rn(a10, __fmul_rn(xi1.x, xj0.x));
      a11 = __fadd_rn(a11, __fmul_rn(xi1.x, xj1.x));
      a00 = __fadd_rn(a00, __fmul_rn(xi0.y, xj0.y));
      a01 = __fadd_rn(a01, __fmul_rn(xi0.y, xj1.y));
      a10 = __fadd_rn(a10, __fmul_rn(xi1.y, xj0.y));
      a11 = __fadd_rn(a11, __fmul_rn(xi1.y, xj1.y));
    }
  }
  float* Sb = S + (size_t)b * 16384;
  int C = ti + ci, D = tj + dj;
  Sb[C * 128 + D] = a00;
  Sb[C * 128 + D + 1] = a01;
  Sb[(C + 1) * 128 + D] = a10;
  Sb[(C + 1) * 128 + D + 1] = a11;
}

__global__ void covfin_kernel(const float* __restrict__ A, float* __restrict__ B) {
  int i = blockIdx.x * 256 + threadIdx.x;
  if (i < 262144) {
    int w = i & 16383;
    int base = i - w;
    int r = w >> 7, c = w & 127;
    int src = ((r >> 5) > (c >> 5)) ? (base + c * 128 + r) : i;
    B[i] = A[src] / 16383.0f;
  }
}

// ======================= projection =======================

__global__ __launch_bounds__(256) void proj_kernel(const float* __restrict__ x, const float* __restrict__ V,
                                                   const float* __restrict__ mean32, float* __restrict__ out) {
  __shared__ float Vs[128 * 64];
  __shared__ float Xs[64 * 128];
  __shared__ float ms[128];
  int b = blockIdx.x, t = blockIdx.y, tid = threadIdx.x;
  const float* xb = x + (size_t)b * 2097152 + (size_t)t * 64 * 128;
  const float* vb = V + (size_t)b * 8192;
  if (tid < 128) ms[tid] = mean32[b * 128 + tid];
  __syncthreads();
  for (int i = tid; i < 2048; i += 256) ((float4*)Vs)[i] = ((const float4*)vb)[i];
  for (int i = tid; i < 2048; i += 256) {
    float4 xv = ((const float4*)xb)[i];
    int cv = (i & 31) * 4;
    xv.x -= ms[cv]; xv.y -= ms[cv + 1]; xv.z -= ms[cv + 2]; xv.w -= ms[cv + 3];
    ((float4*)Xs)[i] = xv;
  }
  __syncthreads();
  int kk = tid & 63, w = tid >> 6;
  float acc[16];
#pragma unroll
  for (int r = 0; r < 16; r++) acc[r] = 0.f;
  for (int c4 = 0; c4 < 32; c4++) {
    float v0 = Vs[(c4 * 4 + 0) * 64 + kk];
    float v1 = Vs[(c4 * 4 + 1) * 64 + kk];
    float v2 = Vs[(c4 * 4 + 2) * 64 + kk];
    float v3 = Vs[(c4 * 4 + 3) * 64 + kk];
#pragma unroll
    for (int r = 0; r < 16; r++) {
      const float4 xv = ((const float4*)Xs)[(w * 16 + r) * 32 + c4];
      acc[r] += xv.x * v0 + xv.y * v1 + xv.z * v2 + xv.w * v3;
    }
  }
  float* ob = out + (size_t)b * 1048576 + (size_t)t * 4096;
#pragma unroll
  for (int r = 0; r < 16; r++) ob[(w * 16 + r) * 64 + kk] = acc[r];
}

// ======================= launch =======================

extern "C" void kernel_launch(void* const* d_in, const int* in_sizes, int n_in,
                              void* d_out, int out_size, void* d_ws, size_t ws_size,
                              hipStream_t stream) {
  (void)in_sizes; (void)n_in; (void)out_size; (void)ws_size;
  const float* x = (const float*)d_in[0];
  float* out = (float*)d_out;
  float* T = out + TBASEF;
  float* Af   = T + F_A;
  float* Bf   = T + F_B;
  float* Qf   = T + F_Q;
  float* Q2f  = T + F_Q2;
  float* vecsf = T + F_VECS;
  float* Vw = (float*)d_ws;
  float* mean32 = Vw + 131072;
  int* dcode = (int*)(mean32 + 2048);

  zeroi_kernel<<<dim3(1), dim3(1), 0, stream>>>(dcode);
  mean_np_kernel<<<dim3(16), dim3(128), 0, stream>>>(x, mean32);
  covnp_kernel<<<dim3(16, 10), dim3(256), 0, stream>>>(x, mean32, Af);
  covfin_kernel<<<dim3(1024), dim3(256), 0, stream>>>(Af, Bf);
  eig_p1_kernel<<<dim3(16), dim3(THREADS), 0, stream>>>(Bf, Af, vecsf);
  eig_p2a_kernel<<<dim3(16), dim3(THREADS), 0, stream>>>(Qf, vecsf);
  eig_p2b_kernel<<<dim3(16), dim3(THREADS), 0, stream>>>(Qf, Q2f, vecsf, dcode + 1);
  eig_p2c_kernel<<<dim3(16), dim3(THREADS), 0, stream>>>(Qf, Q2f, vecsf, dcode + 1);
  eig_p3_kernel<<<dim3(16), dim3(THREADS), 0, stream>>>(Af, vecsf, Qf, Vw);
  diag_kernel<<<dim3(16), dim3(128), 0, stream>>>(Bf, Qf, vecsf, Vw, dcode);
  proj_kernel<<<dim3(16, 256), dim3(256), 0, stream>>>(x, Vw, mean32, out);
  emit_kernel<<<dim3(1), dim3(1), 0, stream>>>(dcode, out);
}